// Round 13
// baseline (1627.954 us; speedup 1.0000x reference)
//
#include <hip/hip_runtime.h>
#include <hip/hip_bf16.h>

typedef unsigned short u16;
typedef __attribute__((ext_vector_type(8))) short bf16x8;
typedef __attribute__((ext_vector_type(4))) float f32x4;

__device__ __constant__ float kInvSqrtD = 0.04419417382415922f; // 1/sqrt(512)

__device__ __forceinline__ u16 f2bf(float f) {
  union { float f; unsigned u; } a; a.f = f;
  unsigned r = a.u + 0x7FFFu + ((a.u >> 16) & 1u);
  return (u16)(r >> 16);
}
__device__ __forceinline__ float bf2f(u16 u) {
  union { unsigned u; float f; } a; a.u = ((unsigned)u) << 16;
  return a.f;
}

// ---------------------------------------------------------------------------
// Block reductions (blockDim.x == 256)
// ---------------------------------------------------------------------------
__device__ __forceinline__ float blockReduceMax(float v, float* red) {
  int tid = threadIdx.x;
  red[tid] = v; __syncthreads();
  #pragma unroll
  for (int w = 128; w > 0; w >>= 1) {
    if (tid < w) red[tid] = fmaxf(red[tid], red[tid + w]);
    __syncthreads();
  }
  float r = red[0];
  __syncthreads();
  return r;
}
__device__ __forceinline__ float blockReduceSum(float v, float* red) {
  int tid = threadIdx.x;
  red[tid] = v; __syncthreads();
  #pragma unroll
  for (int w = 128; w > 0; w >>= 1) {
    if (tid < w) red[tid] = red[tid] + red[tid + w];
    __syncthreads();
  }
  float r = red[0];
  __syncthreads();
  return r;
}

__device__ __forceinline__ float4 blockReduceF4(float4 v, float4* red) {
  int tid = threadIdx.x;
  red[tid] = v; __syncthreads();
  #pragma unroll
  for (int w = 128; w > 0; w >>= 1) {
    if (tid < w) {
      float4 a = red[tid], b = red[tid + w];
      a.x += b.x; a.y += b.y; a.z += b.z; a.w += b.w;
      red[tid] = a;
    }
    __syncthreads();
  }
  float4 r = red[0];
  __syncthreads();
  return r;
}

#define GLDS16(gp, lp)                                                         \
  __builtin_amdgcn_global_load_lds(                                            \
      (const __attribute__((address_space(1))) void*)(gp),                     \
      (__attribute__((address_space(3))) void*)(lp), 16, 0, 0)

// 2-D rectangular XCD partition (bijective); fallback: 1-D chunks
__device__ __forceinline__ void xcd_map(int gx, int gy, int& bx, int& by) {
  const int nwg = gx * gy;
  const int orig = blockIdx.y * gx + blockIdx.x;
  if ((nwg & 7) == 0) {
    int bestfx = 0, bestcost = 1 << 30;
    #pragma unroll
    for (int fx = 1; fx <= 8; fx <<= 1) {
      int fy = 8 / fx;
      if ((gx % fx) == 0 && (gy % fy) == 0) {
        int cost = gx / fx + gy / fy;
        if (cost < bestcost) { bestcost = cost; bestfx = fx; }
      }
    }
    if (bestfx > 0) {
      const int fx = bestfx, fy = 8 / bestfx;
      const int rw = gx / fx, rh = gy / fy;
      const int xcd = orig & 7, lid = orig >> 3;
      bx = (xcd % fx) * rw + lid % rw;
      by = (xcd / fx) * rh + lid / rw;
      return;
    }
    const int q = nwg >> 3;
    const int xcd = orig & 7, lid = orig >> 3;
    const int wgid = xcd * q + lid;
    bx = wgid % gx; by = wgid / gx;
    return;
  }
  const int q = nwg >> 3, r = nwg & 7;
  const int xcd = orig & 7, lid = orig >> 3;
  const int wgid = (xcd < r ? xcd * (q + 1) : r * (q + 1) + (xcd - r) * q) + lid;
  bx = wgid % gx; by = wgid / gx;
}

// ---------------------------------------------------------------------------
// Shared epilogue for the 128x128 8-wave kernels: split-K merge via LDS,
// LDS tile staging, coalesced writeout. smem must hold >= 67584 bytes.
// ---------------------------------------------------------------------------
template<int OUTM, bool ACCUM, bool RELU, bool RANK1, bool BIAS>
__device__ __forceinline__ void epilogue128(
    u16* smem, f32x4 (&acc)[4][4],
    int z, int row0, int col0, int tid, int lane, int w, int wr, int wc,
    const float* bias, int sBias,
    float* Cf, u16* Cb, int ldc, long long sC,
    const float* r1row, int sR1r, const float* r1col, int sR1c)
{
  // cross-group merge: group 1 dumps acc to LDS, group 0 adds
  float* dump = (float*)smem;
  if (w >= 4) {
    float* reg = dump + ((w - 4) << 12);
    #pragma unroll
    for (int f = 0; f < 16; ++f) {
      int mi = f >> 2, ni = f & 3;
      *(f32x4*)(reg + (lane << 6) + (((f + lane) & 15) << 2)) = acc[mi][ni];
    }
  }
  asm volatile("s_waitcnt lgkmcnt(0)" ::: "memory");
  __builtin_amdgcn_s_barrier();
  asm volatile("" ::: "memory");
  if (w < 4) {
    float* reg = dump + (w << 12);
    #pragma unroll
    for (int f = 0; f < 16; ++f) {
      int mi = f >> 2, ni = f & 3;
      acc[mi][ni] += *(const f32x4*)(reg + (lane << 6) + (((f + lane) & 15) << 2));
    }
  }
  asm volatile("s_waitcnt lgkmcnt(0)" ::: "memory");
  __builtin_amdgcn_s_barrier();
  asm volatile("" ::: "memory");

  // tile store (group 0 only) into LDS [128][132] fp32
  float* tile = (float*)smem;
  if (w < 4) {
    const int cn  = lane & 15;
    const int rm4 = (lane >> 4) << 2;
    #pragma unroll
    for (int mi = 0; mi < 4; ++mi) {
      #pragma unroll
      for (int ni = 0; ni < 4; ++ni) {
        const int rl = wr + mi * 16 + rm4;
        const int cl = wc + ni * 16 + cn;
        if (OUTM == 2) {
          *(f32x4*)&tile[cl * 132 + rl] = acc[mi][ni];
        } else {
          #pragma unroll
          for (int j = 0; j < 4; ++j) tile[(rl + j) * 132 + cl] = acc[mi][ni][j];
        }
      }
    }
  }
  asm volatile("s_waitcnt lgkmcnt(0)" ::: "memory");
  __builtin_amdgcn_s_barrier();
  asm volatile("" ::: "memory");

  // coalesced writeout: all 512 threads, 8 passes of 16 rows
  #pragma unroll
  for (int p = 0; p < 8; ++p) {
    const int rr = p * 16 + (tid >> 5);
    const int c4 = (tid & 31) << 2;
    f32x4 v = *(const f32x4*)&tile[rr * 132 + c4];
    if (OUTM == 2) {
      const int cc = col0 + rr;
      float badd = BIAS ? bias[(long long)z * sBias + cc] : 0.f;
      u16* pp = Cb + (long long)z * sC + (long long)cc * ldc + row0 + c4;
      ushort4 o;
      o.x = f2bf(v[0] + badd); o.y = f2bf(v[1] + badd);
      o.z = f2bf(v[2] + badd); o.w = f2bf(v[3] + badd);
      *(ushort4*)pp = o;
    } else {
      const int R = row0 + rr;
      const long long idx = (long long)z * sC + (long long)R * ldc + col0 + c4;
      float val[4] = {v[0], v[1], v[2], v[3]};
      if (BIAS) {
        float4 b4 = *(const float4*)&bias[(long long)z * sBias + col0 + c4];
        val[0] += b4.x; val[1] += b4.y; val[2] += b4.z; val[3] += b4.w;
      }
      if (RANK1) {
        float rr1 = r1row[(long long)z * sR1r + R];
        float4 c4v = *(const float4*)&r1col[(long long)z * sR1c + col0 + c4];
        val[0] += rr1 * c4v.x; val[1] += rr1 * c4v.y;
        val[2] += rr1 * c4v.z; val[3] += rr1 * c4v.w;
      }
      if (OUTM == 0) {
        if (ACCUM) {
          float4 old = *(const float4*)&Cf[idx];
          val[0] += old.x; val[1] += old.y; val[2] += old.z; val[3] += old.w;
        }
        if (RELU) {
          val[0] = fmaxf(val[0], 0.f); val[1] = fmaxf(val[1], 0.f);
          val[2] = fmaxf(val[2], 0.f); val[3] = fmaxf(val[3], 0.f);
        }
        float4 o4; o4.x = val[0]; o4.y = val[1]; o4.z = val[2]; o4.w = val[3];
        *(float4*)&Cf[idx] = o4;
      } else {
        ushort4 o;
        o.x = f2bf(val[0]); o.y = f2bf(val[1]);
        o.z = f2bf(val[2]); o.w = f2bf(val[3]);
        *(ushort4*)&Cb[idx] = o;
      }
    }
  }
}

// ---------------------------------------------------------------------------
// 128x128 8-wave split-K MFMA GEMM, ring-4 (~68 KB LDS -> 2 blocks/CU).
// Ledger: prologue stages pairs 0,1; per pair p: vmcnt(4) [pair p landed,
// p+1 in flight] -> barrier -> reads -> lgkm0+barrier [all reads done] ->
// stage pair p+2 (into pair-p slots) -> MFMA.
// OUTM: 0 = fp32 [M,N], 1 = bf16 [M,N], 2 = bf16 [N,M] (transposed store).
// ---------------------------------------------------------------------------
template<int OUTM, bool ACCUM, bool RELU, bool RANK1, bool BIAS>
__global__ __launch_bounds__(512, 4) void mgemm8d_k(
    const u16* __restrict__ A, int lda, long long sA,
    const u16* __restrict__ B, int ldb, long long sB,
    const float* __restrict__ bias, int sBias,
    float* __restrict__ Cf, u16* __restrict__ Cb, int ldc, long long sC,
    int K,
    const float* __restrict__ r1row, int sR1r,
    const float* __restrict__ r1col, int sR1c)
{
  __shared__ u16 smem[33792];   // max(ring-4 64KB, epilogue tile 67.5KB)
  const int z = blockIdx.z;
  const u16* Ag = A + (long long)z * sA;
  const u16* Bg = B + (long long)z * sB;

  int bx, by;
  xcd_map(gridDim.x, gridDim.y, bx, by);

  const int row0 = by << 7;
  const int col0 = bx << 7;
  const int tid  = threadIdx.x;
  const int lane = tid & 63;
  const int w    = tid >> 6;
  const int g    = w >> 2;
  const int s4   = w & 3;
  const int wr   = (s4 >> 1) << 6;
  const int wc   = (s4 & 1) << 6;

  const int srow = tid >> 2;
  const int ssw  = (tid & 3) ^ ((srow >> 1) & 3);
  const long long aoff = (long long)(row0 + srow) * lda + ssw * 8;
  const long long boff = (long long)(col0 + srow) * ldb + ssw * 8;

  const int frow = lane & 15;
  const int fsw  = (lane >> 4) ^ ((frow >> 1) & 3);
  const int fAoff = ((wr + frow) << 5) + (fsw << 3);
  const int fBoff = ((wc + frow) << 5) + (fsw << 3);

#define STAGE4(tt) do {                                                        \
    u16* _sb = smem + (((tt) & 3) << 13);                                      \
    const long long _k = (long long)(tt) << 5;                                 \
    GLDS16(Ag + aoff + _k, _sb + (tid << 3));                                  \
    GLDS16(Bg + boff + _k, _sb + 4096 + (tid << 3));                           \
  } while (0)

  f32x4 acc[4][4];
  #pragma unroll
  for (int mi = 0; mi < 4; ++mi)
    #pragma unroll
    for (int ni = 0; ni < 4; ++ni) {
      acc[mi][ni][0] = 0.f; acc[mi][ni][1] = 0.f;
      acc[mi][ni][2] = 0.f; acc[mi][ni][3] = 0.f;
    }

  const int NT = K >> 5;
  const int NP = NT >> 1;   // >= 2 for all our shapes
  STAGE4(0); STAGE4(1); STAGE4(2); STAGE4(3);   // pairs 0,1 (8 loads)

  for (int p = 0; p < NP; ++p) {
    if (p + 1 < NP) asm volatile("s_waitcnt vmcnt(4)" ::: "memory");
    else            asm volatile("s_waitcnt vmcnt(0)" ::: "memory");
    __builtin_amdgcn_s_barrier();
    asm volatile("" ::: "memory");

    const u16* base = smem + (((2 * p + g) & 3) << 13);
    bf16x8 af[4], bfr[4];
    #pragma unroll
    for (int mi = 0; mi < 4; ++mi) af[mi]  = *(const bf16x8*)(base + fAoff + mi * 512);
    #pragma unroll
    for (int ni = 0; ni < 4; ++ni) bfr[ni] = *(const bf16x8*)(base + 4096 + fBoff + ni * 512);
    asm volatile("s_waitcnt lgkmcnt(0)" ::: "memory");
    __builtin_amdgcn_s_barrier();
    asm volatile("" ::: "memory");

    if (p + 2 < NP) { STAGE4(2 * p + 4); STAGE4(2 * p + 5); }

    __builtin_amdgcn_s_setprio(1);
    #pragma unroll
    for (int mi = 0; mi < 4; ++mi)
      #pragma unroll
      for (int ni = 0; ni < 4; ++ni)
        acc[mi][ni] = __builtin_amdgcn_mfma_f32_16x16x32_bf16(
            af[mi], bfr[ni], acc[mi][ni], 0, 0, 0);
    __builtin_amdgcn_s_setprio(0);
  }
#undef STAGE4

  epilogue128<OUTM, ACCUM, RELU, RANK1, BIAS>(
      smem, acc, z, row0, col0, tid, lane, w, wr, wc,
      bias, sBias, Cf, Cb, ldc, sC, r1row, sR1r, r1col, sR1c);
}

// ---------------------------------------------------------------------------
// 256x256 MFMA GEMM, 8 waves each owning 128x64, 2-slot double buffer
// (64 KB LDS -> 2 blocks/CU). Same ledger as mgemm8d at tile granularity:
// vmcnt(4) [tile t landed, t+1 in flight] -> barrier -> reads -> lgkm0 +
// barrier -> stage t+2 (into slot of t) -> MFMA. Direct epilogue.
// ---------------------------------------------------------------------------
template<bool BIAS>
__global__ __launch_bounds__(512, 4) void mgemm256d_k(
    const u16* __restrict__ A, int lda, long long sA,
    const u16* __restrict__ B, int ldb, long long sB,
    const float* __restrict__ bias, int sBias,
    u16* __restrict__ Cb, int ldc, long long sC,
    int K)
{
  __shared__ u16 smem[2 * 16384];   // 2 slots x 32KB = 64 KB
  const int z = blockIdx.z;
  const u16* Ag = A + (long long)z * sA;
  const u16* Bg = B + (long long)z * sB;

  int bx, by;
  xcd_map(gridDim.x, gridDim.y, bx, by);

  const int row0r = by << 8;
  const int col0 = bx << 8;
  const int tid  = threadIdx.x;
  const int lane = tid & 63;
  const int w    = tid >> 6;
  const int wrow = w >> 2;
  const int wcol = w & 3;

  const int srow = tid >> 2;
  const int ssw  = (tid & 3) ^ ((srow >> 1) & 3);
  const long long aoff0 = (long long)(row0r + srow)       * lda + ssw * 8;
  const long long aoff1 = (long long)(row0r + srow + 128) * lda + ssw * 8;
  const long long boff0 = (long long)(col0 + srow)        * ldb + ssw * 8;
  const long long boff1 = (long long)(col0 + srow + 128)  * ldb + ssw * 8;

  const int frow = lane & 15;
  const int fsw  = (lane >> 4) ^ ((frow >> 1) & 3);
  const int fAoff = ((wrow * 128 + frow) << 5) + (fsw << 3);   // + mi*512
  const int fBoff = ((wcol * 64  + frow) << 5) + (fsw << 3);   // + ni*512

#define STG256(tt) do {                                                        \
    u16* _sb = smem + (((tt) & 1) << 14);                                      \
    const long long _k = (long long)(tt) << 5;                                 \
    GLDS16(Ag + aoff0 + _k, _sb + (tid << 3));                                 \
    GLDS16(Ag + aoff1 + _k, _sb + 4096 + (tid << 3));                          \
    GLDS16(Bg + boff0 + _k, _sb + 8192 + (tid << 3));                          \
    GLDS16(Bg + boff1 + _k, _sb + 12288 + (tid << 3));                         \
  } while (0)

  f32x4 acc[8][4];
  #pragma unroll
  for (int mi = 0; mi < 8; ++mi)
    #pragma unroll
    for (int ni = 0; ni < 4; ++ni) {
      acc[mi][ni][0] = 0.f; acc[mi][ni][1] = 0.f;
      acc[mi][ni][2] = 0.f; acc[mi][ni][3] = 0.f;
    }

  const int NT = K >> 5;   // >= 16 for our shapes
  STG256(0); STG256(1);    // 8 loads in flight

  for (int t = 0; t < NT; ++t) {
    if (t + 1 < NT) asm volatile("s_waitcnt vmcnt(4)" ::: "memory");
    else            asm volatile("s_waitcnt vmcnt(0)" ::: "memory");
    __builtin_amdgcn_s_barrier();
    asm volatile("" ::: "memory");

    const u16* base = smem + ((t & 1) << 14);
    bf16x8 af[8], bfr[4];
    #pragma unroll
    for (int mi = 0; mi < 8; ++mi) af[mi]  = *(const bf16x8*)(base + fAoff + mi * 512);
    #pragma unroll
    for (int ni = 0; ni < 4; ++ni) bfr[ni] = *(const bf16x8*)(base + 8192 + fBoff + ni * 512);
    asm volatile("s_waitcnt lgkmcnt(0)" ::: "memory");
    __builtin_amdgcn_s_barrier();
    asm volatile("" ::: "memory");

    if (t + 2 < NT) STG256(t + 2);

    __builtin_amdgcn_s_setprio(1);
    #pragma unroll
    for (int mi = 0; mi < 8; ++mi)
      #pragma unroll
      for (int ni = 0; ni < 4; ++ni)
        acc[mi][ni] = __builtin_amdgcn_mfma_f32_16x16x32_bf16(
            af[mi], bfr[ni], acc[mi][ni], 0, 0, 0);
    __builtin_amdgcn_s_setprio(0);
  }
#undef STG256

  // direct epilogue: each wave owns its 128x64 output
  const int cn  = lane & 15;
  const int rm4 = (lane >> 4) << 2;
  #pragma unroll
  for (int mi = 0; mi < 8; ++mi) {
    #pragma unroll
    for (int ni = 0; ni < 4; ++ni) {
      const int rb = row0r + wrow * 128 + mi * 16 + rm4;
      const int cc = col0 + wcol * 64 + ni * 16 + cn;
      float badd = BIAS ? bias[(long long)z * sBias + cc] : 0.f;
      f32x4 v = acc[mi][ni];
      #pragma unroll
      for (int j = 0; j < 4; ++j)
        Cb[(long long)z * sC + (long long)(rb + j) * ldc + cc] = f2bf(v[j] + badd);
    }
  }
}

// out = relu(p0+p1+p2+p3), partials stride 1M floats, n4 = n/4 float4s
__global__ __launch_bounds__(256) void reduce4relu_k(
    const float* __restrict__ p, float* __restrict__ out, int n4)
{
  int i = blockIdx.x * 256 + threadIdx.x;
  if (i < n4) {
    float4 a = ((const float4*)p)[i];
    float4 b = ((const float4*)(p + (1ll << 20)))[i];
    float4 c = ((const float4*)(p + (2ll << 20)))[i];
    float4 d = ((const float4*)(p + (3ll << 20)))[i];
    float4 o;
    o.x = fmaxf(a.x + b.x + c.x + d.x, 0.f);
    o.y = fmaxf(a.y + b.y + c.y + d.y, 0.f);
    o.z = fmaxf(a.z + b.z + c.z + d.z, 0.f);
    o.w = fmaxf(a.w + b.w + c.w + d.w, 0.f);
    ((float4*)out)[i] = o;
  }
}

// ---------------------------------------------------------------------------
__global__ __launch_bounds__(256) void xpose_k(
    const float* __restrict__ in, float* __restrict__ out, int R, int Cc)
{
  __shared__ float tile[32][33];
  int c0 = blockIdx.x * 32, r0 = blockIdx.y * 32;
  int tx = threadIdx.x & 31, ty = threadIdx.x >> 5;
  #pragma unroll
  for (int rr = ty; rr < 32; rr += 8)
    tile[rr][tx] = in[(long long)(r0 + rr) * Cc + c0 + tx];
  __syncthreads();
  #pragma unroll
  for (int cc = ty; cc < 32; cc += 8)
    out[(long long)(c0 + cc) * R + r0 + tx] = tile[tx][cc];
}

__global__ __launch_bounds__(256) void tcvt_k(
    const float* __restrict__ in, u16* __restrict__ out, int R, int Cc)
{
  __shared__ float tile[32][33];
  int c0 = blockIdx.x * 32, r0 = blockIdx.y * 32;
  int tx = threadIdx.x & 31, ty = threadIdx.x >> 5;
  #pragma unroll
  for (int rr = ty; rr < 32; rr += 8)
    tile[rr][tx] = in[(long long)(r0 + rr) * Cc + c0 + tx];
  __syncthreads();
  #pragma unroll
  for (int cc = ty; cc < 32; cc += 8)
    out[(long long)(c0 + cc) * R + r0 + tx] = f2bf(tile[tx][cc]);
}

__global__ __launch_bounds__(256) void tcvt_aff_k(
    const float* __restrict__ in, u16* __restrict__ out, int R, int Cc,
    const float* __restrict__ A2, const float* __restrict__ C2)
{
  __shared__ float tile[32][33];
  int c0 = blockIdx.x * 32, r0 = blockIdx.y * 32;
  int tx = threadIdx.x & 31, ty = threadIdx.x >> 5;
  #pragma unroll
  for (int rr = ty; rr < 32; rr += 8)
    tile[rr][tx] = in[(long long)(r0 + rr) * Cc + c0 + tx];
  __syncthreads();
  #pragma unroll
  for (int cc = ty; cc < 32; cc += 8) {
    float v = A2[c0 + cc] * tile[tx][cc] + C2[c0 + cc];
    out[(long long)(c0 + cc) * R + r0 + tx] = f2bf(v);
  }
}

__global__ __launch_bounds__(256) void cvt_k(
    const float* __restrict__ in, u16* __restrict__ out)
{
  int i = blockIdx.x * 256 + threadIdx.x;
  float4 v = ((const float4*)in)[i];
  ushort4 o;
  o.x = f2bf(v.x); o.y = f2bf(v.y); o.z = f2bf(v.z); o.w = f2bf(v.w);
  ((ushort4*)out)[i] = o;
}

__global__ __launch_bounds__(256) void pack2_k(
    const float* __restrict__ a, const float* __restrict__ b,
    float* __restrict__ out, int n)
{
  int i = blockIdx.x * 256 + threadIdx.x;
  if (i < n) { out[i] = a[i]; out[n + i] = b[i]; }
}

// ---------------------------------------------------------------------------
__global__ __launch_bounds__(64) void qe_k(const u16* __restrict__ Q1,
                                           const float* __restrict__ We1,
                                           float* __restrict__ qe)
{
  int h = blockIdx.x >> 10;
  int i = blockIdx.x & 1023;
  const u16* q = Q1 + (long long)i * 4096 + h * 512;
  const float* wv = We1 + h * 512;
  int l = threadIdx.x;
  float s = 0.f;
  #pragma unroll
  for (int r = 0; r < 8; ++r) s += bf2f(q[l + r * 64]) * wv[l + r * 64];
  #pragma unroll
  for (int off = 32; off > 0; off >>= 1) s += __shfl_down(s, off);
  if (l == 0) qe[blockIdx.x] = s;
}

// ---------------------------------------------------------------------------
__global__ __launch_bounds__(256) void softmax1b_k(
    u16* __restrict__ S, const float* __restrict__ xT,
    const float* __restrict__ qe, float* __restrict__ ae)
{
  int i = blockIdx.x, h = blockIdx.y;
  u16* s = S + ((long long)h * 1024 + i) * 1024;
  const float* e = xT + (long long)i * 1024;
  float q = qe[h * 1024 + i];
  int tid = threadIdx.x;
  __shared__ float red[256];

  ushort4 sv = ((const ushort4*)s)[tid];
  float4  evv = ((const float4*)e)[tid];
  float ev[4] = {evv.x, evv.y, evv.z, evv.w};
  float t[4];
  t[0] = (bf2f(sv.x) + q * ev[0]) * kInvSqrtD;
  t[1] = (bf2f(sv.y) + q * ev[1]) * kInvSqrtD;
  t[2] = (bf2f(sv.z) + q * ev[2]) * kInvSqrtD;
  t[3] = (bf2f(sv.w) + q * ev[3]) * kInvSqrtD;
  float m = fmaxf(fmaxf(t[0], t[1]), fmaxf(t[2], t[3]));
  m = blockReduceMax(m, red);
  float sum = 0.f;
  #pragma unroll
  for (int r = 0; r < 4; ++r) { t[r] = __expf(t[r] - m); sum += t[r]; }
  sum = blockReduceSum(sum, red);
  float invl = 1.f / sum;
  float aes = 0.f;
  ushort4 o;
  o.x = f2bf(t[0] * invl); o.y = f2bf(t[1] * invl);
  o.z = f2bf(t[2] * invl); o.w = f2bf(t[3] * invl);
  #pragma unroll
  for (int r = 0; r < 4; ++r) aes += (t[r] * invl) * ev[r];
  ((ushort4*)s)[tid] = o;
  aes = blockReduceSum(aes, red);
  if (tid == 0) ae[h * 1024 + i] = aes;
}

__global__ __launch_bounds__(256) void softmax2b_k(u16* __restrict__ S)
{
  u16* s = S + ((long long)blockIdx.y * 2048 + blockIdx.x) * 4096;
  int tid = threadIdx.x;
  __shared__ float red[256];
  float t[16];
  float m = -1e30f;
  #pragma unroll
  for (int r = 0; r < 4; ++r) {
    ushort4 sv = ((const ushort4*)s)[tid + r * 256];
    t[r*4+0] = bf2f(sv.x) * kInvSqrtD; t[r*4+1] = bf2f(sv.y) * kInvSqrtD;
    t[r*4+2] = bf2f(sv.z) * kInvSqrtD; t[r*4+3] = bf2f(sv.w) * kInvSqrtD;
    m = fmaxf(m, fmaxf(fmaxf(t[r*4], t[r*4+1]), fmaxf(t[r*4+2], t[r*4+3])));
  }
  m = blockReduceMax(m, red);
  float sum = 0.f;
  #pragma unroll
  for (int r = 0; r < 16; ++r) { t[r] = __expf(t[r] - m); sum += t[r]; }
  sum = blockReduceSum(sum, red);
  float invl = 1.f / sum;
  #pragma unroll
  for (int r = 0; r < 4; ++r) {
    ushort4 o;
    o.x = f2bf(t[r*4+0] * invl); o.y = f2bf(t[r*4+1] * invl);
    o.z = f2bf(t[r*4+2] * invl); o.w = f2bf(t[r*4+3] * invl);
    ((ushort4*)s)[tid + r * 256] = o;
  }
}

// ---------------------------------------------------------------------------
__global__ __launch_bounds__(256) void colpart4_k(const float* __restrict__ h,
    int N, int F, int nchunk, float* __restrict__ ps, float* __restrict__ pss)
{
  const int f4 = blockIdx.x * 256 + threadIdx.x;
  const int chunk = blockIdx.y;
  const int rows = N / nchunk;
  const int rbeg = chunk * rows;
  const int F4 = F >> 2;
  const float4* h4 = (const float4*)h;
  float4 s = {0.f, 0.f, 0.f, 0.f}, ss = {0.f, 0.f, 0.f, 0.f};
  #pragma unroll 8
  for (int i = 0; i < rows; ++i) {
    float4 v = h4[(long long)(rbeg + i) * F4 + f4];
    s.x += v.x; s.y += v.y; s.z += v.z; s.w += v.w;
    ss.x += v.x * v.x; ss.y += v.y * v.y;
    ss.z += v.z * v.z; ss.w += v.w * v.w;
  }
  ((float4*)(ps  + (long long)chunk * F))[f4] = s;
  ((float4*)(pss + (long long)chunk * F))[f4] = ss;
}

// Parallel finisher: one block per float4-column; 256 threads split chunks.
template<int MODE>
__global__ __launch_bounds__(256) void colfin2_k(
    const float* __restrict__ ps, const float* __restrict__ pss,
    int F, int nchunk, float Nf,
    const float* __restrict__ ms, const float* __restrict__ g,
    const float* __restrict__ beta,
    float* __restrict__ outA, float* __restrict__ outC)
{
  __shared__ float4 red4[256];
  const int f4 = blockIdx.x;
  const int tid = threadIdx.x;
  float4 s = {0.f, 0.f, 0.f, 0.f}, ss = {0.f, 0.f, 0.f, 0.f};
  for (int c = tid; c < nchunk; c += 256) {
    float4 v = ((const float4*)(ps  + (long long)c * F))[f4];
    float4 u = ((const float4*)(pss + (long long)c * F))[f4];
    s.x += v.x; s.y += v.y; s.z += v.z; s.w += v.w;
    ss.x += u.x; ss.y += u.y; ss.z += u.z; ss.w += u.w;
  }
  s  = blockReduceF4(s, red4);
  ss = blockReduceF4(ss, red4);
  if (tid < 4) {
    const int f = f4 * 4 + tid;
    float sv  = (tid == 0) ? s.x  : (tid == 1) ? s.y  : (tid == 2) ? s.z  : s.w;
    float ssv = (tid == 0) ? ss.x : (tid == 1) ? ss.y : (tid == 2) ? ss.z : ss.w;
    float Ninv = 1.f / Nf;
    float mean = sv * Ninv;
    float mm = ms[f] * mean;
    float var = ssv * Ninv - 2.f * mm * mean + mm * mm;
    float is = rsqrtf(var + 1e-5f);
    float a = g[f] * is;
    float c = beta[f] - a * mm;
    if (MODE == 1) {
      float sy2 = a * a * ssv + 2.f * a * c * sv + Nf * c * c;
      float cinv = rsqrtf(sy2);
      a *= cinv; c *= cinv;
    }
    outA[f] = a;
    outC[f] = c;
  }
}

__global__ __launch_bounds__(256) void rowl2gn_k(
    float* __restrict__ h, u16* __restrict__ hb,
    const float* __restrict__ a, const float* __restrict__ c)
{
  int i = blockIdx.x;
  float* row = h + (long long)i * 4096;
  u16* rb = hb + (long long)i * 4096;
  int tid = threadIdx.x;
  __shared__ float red[256];
  float t[16];
  float ss = 0.f;
  #pragma unroll
  for (int r = 0; r < 4; ++r) {
    int j = tid + r * 256;
    float4 hv = ((const float4*)row)[j];
    float4 av = ((const float4*)a)[j];
    float4 cv = ((const float4*)c)[j];
    t[r*4+0] = av.x * hv.x + cv.x;
    t[r*4+1] = av.y * hv.y + cv.y;
    t[r*4+2] = av.z * hv.z + cv.z;
    t[r*4+3] = av.w * hv.w + cv.w;
    ss += t[r*4+0]*t[r*4+0] + t[r*4+1]*t[r*4+1]
        + t[r*4+2]*t[r*4+2] + t[r*4+3]*t[r*4+3];
  }
  ss = blockReduceSum(ss, red);
  float inv = rsqrtf(ss);
  #pragma unroll
  for (int r = 0; r < 4; ++r) {
    int j = tid + r * 256;
    float4 o4;
    o4.x = t[r*4+0] * inv; o4.y = t[r*4+1] * inv;
    o4.z = t[r*4+2] * inv; o4.w = t[r*4+3] * inv;
    ((float4*)row)[j] = o4;
    ushort4 ob;
    ob.x = f2bf(o4.x); ob.y = f2bf(o4.y); ob.z = f2bf(o4.z); ob.w = f2bf(o4.w);
    ((ushort4*)rb)[j] = ob;
  }
}

// ---------------------------------------------------------------------------
extern "C" void kernel_launch(void* const* d_in, const int* in_sizes, int n_in,
                              void* d_out, int out_size, void* d_ws, size_t ws_size,
                              hipStream_t stream)
{
  (void)in_sizes; (void)n_in; (void)out_size; (void)ws_size;

  const float* x      = (const float*)d_in[0];
  const float* Wq1    = (const float*)d_in[1];
  const float* bq1    = (const float*)d_in[2];
  const float* Wk1    = (const float*)d_in[3];
  const float* bk1    = (const float*)d_in[4];
  const float* Wv1    = (const float*)d_in[5];
  const float* bv1    = (const float*)d_in[6];
  const float* We1    = (const float*)d_in[7];
  const float* Wskip1 = (const float*)d_in[8];
  const float* bskip1 = (const float*)d_in[9];
  const float* g1     = (const float*)d_in[10];
  const float* bb1    = (const float*)d_in[11];
  const float* ms1    = (const float*)d_in[12];
  const float* Wq2    = (const float*)d_in[13];
  const float* bq2    = (const float*)d_in[14];
  const float* Wk2    = (const float*)d_in[15];
  const float* bk2    = (const float*)d_in[16];
  const float* Wv2    = (const float*)d_in[17];
  const float* bv2    = (const float*)d_in[18];
  const float* Wskip2 = (const float*)d_in[19];
  const float* bskip2 = (const float*)d_in[20];
  const float* g2     = (const float*)d_in[21];
  const float* bb2    = (const float*)d_in[22];
  const float* ms2    = (const float*)d_in[23];

  // ---- workspace arena (~209 MB) ----
  char* base = (char*)d_ws;
  float* lrx_f   = (float*)(base);                 // 16MB [1024][4096]
  u16*   lrx_bf  = (u16*)  (base + (16ll << 20));  // 8MB
  u16*   lrxT_bf = (u16*)  (base + (24ll << 20));  // 8MB [4096][1024]
  u16*   hrx_bf  = (u16*)  (base + (32ll << 20));  // 16MB [2048][4096]
  char* sh = base + (48ll << 20);                  // shared region, 160MB
  // stage A
  u16* x_bf  = (u16*)(sh);                         // 2MB
  float* xT  = (float*)(sh + (2ll << 20));         // 4MB
  u16* Wq1T  = (u16*)(sh + (6ll << 20));           // 8MB each (Wk1T follows Wq1T)
  u16* Wk1T  = (u16*)(sh + (14ll << 20));
  u16* Wv1T  = (u16*)(sh + (22ll << 20));
  u16* Ws1T  = (u16*)(sh + (30ll << 20));
  u16* Q1bf  = (u16*)(sh + (38ll << 20));          // 8MB [1024][4096] (K1bf follows)
  u16* K1bf  = (u16*)(sh + (46ll << 20));          // 8MB
  u16* V1T   = (u16*)(sh + (54ll << 20));          // 8MB [4096][1024]
  u16* S1bf  = (u16*)(sh + (62ll << 20));          // 16MB [8][1024][1024]
  // GN1 partials in dead S1bf space (consumed before V2T/H2 writes)
  float* ps1  = (float*)(sh + (66ll << 20));       // 2MB [128][4096]
  float* pss1 = (float*)(sh + (68ll << 20));       // 2MB
  // stage B (aliases stage A)
  u16* Wq2T  = (u16*)(sh);                         // 4MB each (Wk2T follows)
  u16* Wk2T  = (u16*)(sh + (4ll << 20));
  u16* Wv2T  = (u16*)(sh + (8ll << 20));
  u16* Ws2T  = (u16*)(sh + (12ll << 20));
  u16* Q2bf  = (u16*)(sh + (16ll << 20));          // 16MB [4096][2048] (K2bf follows)
  u16* K2bf  = (u16*)(sh + (32ll << 20));          // 16MB
  u16* V2T   = (u16*)(sh + (48ll << 20));          // 16MB [2048][4096]
  float* H2  = (float*)(sh + (64ll << 20));        // 32MB [4096][2048]
  u16* S2bf  = (u16*)(sh + (96ll << 20));          // 64MB [4][2048][4096]
  float* gpart = (float*)(sh + (96ll << 20));      // 16MB lr-gram partials (S2 dead)
  // GN2 partials in dead S2bf space (consumed before gpart written)
  float* ps2  = (float*)(sh + (120ll << 20));      // 2MB [256][2048]
  float* pss2 = (float*)(sh + (122ll << 20));      // 2MB
  // small tail
  float* tail    = (float*)(base + (208ll << 20));
  float* qe      = tail;             // 8192
  float* ae      = qe + 8192;        // 8192
  float* af1     = ae + 8192;        // 4096
  float* cf1     = af1 + 4096;       // 4096
  float* A2v     = cf1 + 4096;       // 2048
  float* C2v     = A2v + 2048;       // 2048
  float* biasQK1 = C2v + 2048;       // 8192
  float* biasQK2 = biasQK1 + 8192;   // 4096

  float* out0 = (float*)d_out;                   // hr [2048][2048]
  float* out1 = out0 + (long long)2048 * 2048;   // lr gram [1024][1024]

  // ---- stage 0: conversions ----
  xpose_k<<<dim3(32, 32), 256, 0, stream>>>(x, xT, 1024, 1024);
  cvt_k<<<dim3(1024), 256, 0, stream>>>(x, x_bf);
  tcvt_k<<<dim3(128, 32), 256, 0, stream>>>(Wq1,    Wq1T, 1024, 4096);
  tcvt_k<<<dim3(128, 32), 256, 0, stream>>>(Wk1,    Wk1T, 1024, 4096);
  tcvt_k<<<dim3(128, 32), 256, 0, stream>>>(Wv1,    Wv1T, 1024, 4096);
  tcvt_k<<<dim3(128, 32), 256, 0, stream>>>(Wskip1, Ws1T, 1024, 4096);
  pack2_k<<<dim3(16), 256, 0, stream>>>(bq1, bk1, biasQK1, 4096);
  pack2_k<<<dim3(8),  256, 0, stream>>>(bq2, bk2, biasQK2, 2048);

  // ---- conv1 Q+K batched (z=2), V (transposed out), skip (fp32) ----
  mgemm8d_k<1,false,false,false,true><<<dim3(32, 8, 2), 512, 0, stream>>>(
      x_bf, 1024, 0, Wq1T, 1024, (long long)4096 * 1024, biasQK1, 4096,
      nullptr, Q1bf, 4096, (long long)1024 * 4096, 1024, nullptr, 0, nullptr, 0);
  mgemm8d_k<2,false,false,false,true><<<dim3(32, 8, 1), 512, 0, stream>>>(
      x_bf, 1024, 0, Wv1T, 1024, 0, bv1, 0, nullptr, V1T, 1024, 0, 1024,
      nullptr, 0, nullptr, 0);
  mgemm8d_k<0,false,false,false,true><<<dim3(32, 8, 1), 512, 0, stream>>>(
      x_bf, 1024, 0, Ws1T, 1024, 0, bskip1, 0, lrx_f, nullptr, 4096, 0, 1024,
      nullptr, 0, nullptr, 0);

  qe_k<<<dim3(8192), 64, 0, stream>>>(Q1bf, We1, qe);

  // ---- scores1[h] = Q1h @ K1h^T (raw, bf16 out), batch z=8 heads ----
  mgemm8d_k<1,false,false,false,false><<<dim3(8, 8, 8), 512, 0, stream>>>(
      Q1bf, 4096, 512, K1bf, 4096, 512, nullptr, 0, nullptr, S1bf, 1024, 1048576,
      512, nullptr, 0, nullptr, 0);

  softmax1b_k<<<dim3(1024, 8), 256, 0, stream>>>(S1bf, xT, qe, ae);

  // ---- PV1: lrx += alpha @ V1h + ae*Weh ----
  mgemm8d_k<0,true,false,true,false><<<dim3(4, 8, 8), 512, 0, stream>>>(
      S1bf, 1024, 1048576, V1T, 1024, 512 * 1024, nullptr, 0, lrx_f, nullptr,
      4096, 512, 1024, ae, 1024, We1, 512);

  // ---- GraphNorm1 (affine) + row L2, fused ----
  colpart4_k<<<dim3(4, 128), 256, 0, stream>>>(lrx_f, 1024, 4096, 128, ps1, pss1);
  colfin2_k<0><<<dim3(1024), 256, 0, stream>>>(ps1, pss1, 4096, 128, 1024.f,
                                               ms1, g1, bb1, af1, cf1);
  rowl2gn_k<<<dim3(1024), 256, 0, stream>>>(lrx_f, lrx_bf, af1, cf1);
  tcvt_k<<<dim3(128, 32), 256, 0, stream>>>(lrx_f, lrxT_bf, 1024, 4096);

  // ---- conv2 weights ----
  tcvt_k<<<dim3(64, 32), 256, 0, stream>>>(Wq2,    Wq2T, 1024, 2048);
  tcvt_k<<<dim3(64, 32), 256, 0, stream>>>(Wk2,    Wk2T, 1024, 2048);
  tcvt_k<<<dim3(64, 32), 256, 0, stream>>>(Wv2,    Wv2T, 1024, 2048);
  tcvt_k<<<dim3(64, 32), 256, 0, stream>>>(Wskip2, Ws2T, 1024, 2048);

  // ---- conv2 Q+K on 256^2 dbuf kernel; V + skip on 128^2 ----
  mgemm256d_k<true><<<dim3(8, 16, 2), 512, 0, stream>>>(
      lrxT_bf, 1024, 0, Wq2T, 1024, (long long)2048 * 1024, biasQK2, 2048,
      Q2bf, 2048, (long long)4096 * 2048, 1024);
  mgemm8d_k<2,false,false,false,true><<<dim3(16, 32, 1), 512, 0, stream>>>(
      lrxT_bf, 1024, 0, Wv2T, 1024, 0, bv2, 0, nullptr, V2T, 4096, 0, 1024,
      nullptr, 0, nullptr, 0);
  mgemm8d_k<0,false,false,false,true><<<dim3(16, 32, 1), 512, 0, stream>>>(
      lrxT_bf, 1024, 0, Ws2T, 1024, 0, bskip2, 0, H2, nullptr, 2048, 0, 1024,
      nullptr, 0, nullptr, 0);

  // ---- conv2 attention in 2 chunks of 2048 rows ----
  for (int c = 0; c < 2; ++c) {
    const u16* Qc = Q2bf + (long long)c * 2048 * 2048;
    float* Hc = H2 + (long long)c * 2048 * 2048;
    mgemm256d_k<false><<<dim3(16, 8, 4), 512, 0, stream>>>(
        Qc, 2048, 512, K2bf, 2048, 512, nullptr, 0,
        S2bf, 4096, (long long)2048 * 4096, 512);
    softmax2b_k<<<dim3(2048, 4), 256, 0, stream>>>(S2bf);
    mgemm8d_k<0,true,false,false,false><<<dim3(4, 16, 4), 512, 0, stream>>>(
        S2bf, 4096, (long long)2048 * 4096, V2T, 4096, (long long)512 * 4096,
        nullptr, 0, Hc, nullptr, 2048, 512, 4096, nullptr, 0, nullptr, 0);
  }

  // ---- GraphNorm2 + column L2 fused into one affine transpose-convert ----
  colpart4_k<<<dim3(2, 256), 256, 0, stream>>>(H2, 4096, 2048, 256, ps2, pss2);
  colfin2_k<1><<<dim3(512), 256, 0, stream>>>(ps2, pss2, 2048, 256, 4096.f,
                                              ms2, g2, bb2, A2v, C2v);
  tcvt_aff_k<<<dim3(64, 128), 256, 0, stream>>>(H2, hrx_bf, 4096, 2048, A2v, C2v);

  // ---- outputs: relu Grams ----
  mgemm8d_k<0,false,true,false,false><<<dim3(16, 16, 1), 512, 0, stream>>>(
      hrx_bf, 4096, 0, hrx_bf, 4096, 0, nullptr, 0, out0, nullptr, 2048, 0, 4096,
      nullptr, 0, nullptr, 0);
  // lr-gram: grid-split K 4-way (z) into partials, then reduce+relu
  mgemm8d_k<0,false,false,false,false><<<dim3(8, 8, 4), 512, 0, stream>>>(
      lrx_bf, 4096, 1024, lrx_bf, 4096, 1024, nullptr, 0, gpart, nullptr, 1024,
      (long long)1 << 20, 1024, nullptr, 0, nullptr, 0);
  reduce4relu_k<<<dim3(1024), 256, 0, stream>>>(gpart, out1, 262144);
}

// Round 14
// 640.738 us; speedup vs baseline: 2.5408x; 2.5408x over previous
//
#include <hip/hip_runtime.h>
#include <hip/hip_bf16.h>

typedef unsigned short u16;
typedef __attribute__((ext_vector_type(8))) short bf16x8;
typedef __attribute__((ext_vector_type(4))) float f32x4;

__device__ __constant__ float kInvSqrtD = 0.04419417382415922f; // 1/sqrt(512)

__device__ __forceinline__ u16 f2bf(float f) {
  union { float f; unsigned u; } a; a.f = f;
  unsigned r = a.u + 0x7FFFu + ((a.u >> 16) & 1u);
  return (u16)(r >> 16);
}
__device__ __forceinline__ float bf2f(u16 u) {
  union { unsigned u; float f; } a; a.u = ((unsigned)u) << 16;
  return a.f;
}

// ---------------------------------------------------------------------------
// Block reductions (blockDim.x == 256)
// ---------------------------------------------------------------------------
__device__ __forceinline__ float blockReduceMax(float v, float* red) {
  int tid = threadIdx.x;
  red[tid] = v; __syncthreads();
  #pragma unroll
  for (int w = 128; w > 0; w >>= 1) {
    if (tid < w) red[tid] = fmaxf(red[tid], red[tid + w]);
    __syncthreads();
  }
  float r = red[0];
  __syncthreads();
  return r;
}
__device__ __forceinline__ float blockReduceSum(float v, float* red) {
  int tid = threadIdx.x;
  red[tid] = v; __syncthreads();
  #pragma unroll
  for (int w = 128; w > 0; w >>= 1) {
    if (tid < w) red[tid] = red[tid] + red[tid + w];
    __syncthreads();
  }
  float r = red[0];
  __syncthreads();
  return r;
}

__device__ __forceinline__ float4 blockReduceF4(float4 v, float4* red) {
  int tid = threadIdx.x;
  red[tid] = v; __syncthreads();
  #pragma unroll
  for (int w = 128; w > 0; w >>= 1) {
    if (tid < w) {
      float4 a = red[tid], b = red[tid + w];
      a.x += b.x; a.y += b.y; a.z += b.z; a.w += b.w;
      red[tid] = a;
    }
    __syncthreads();
  }
  float4 r = red[0];
  __syncthreads();
  return r;
}

#define GLDS16(gp, lp)                                                         \
  __builtin_amdgcn_global_load_lds(                                            \
      (const __attribute__((address_space(1))) void*)(gp),                     \
      (__attribute__((address_space(3))) void*)(lp), 16, 0, 0)

// 2-D rectangular XCD partition (bijective); fallback: 1-D chunks
__device__ __forceinline__ void xcd_map(int gx, int gy, int& bx, int& by) {
  const int nwg = gx * gy;
  const int orig = blockIdx.y * gx + blockIdx.x;
  if ((nwg & 7) == 0) {
    int bestfx = 0, bestcost = 1 << 30;
    #pragma unroll
    for (int fx = 1; fx <= 8; fx <<= 1) {
      int fy = 8 / fx;
      if ((gx % fx) == 0 && (gy % fy) == 0) {
        int cost = gx / fx + gy / fy;
        if (cost < bestcost) { bestcost = cost; bestfx = fx; }
      }
    }
    if (bestfx > 0) {
      const int fx = bestfx, fy = 8 / bestfx;
      const int rw = gx / fx, rh = gy / fy;
      const int xcd = orig & 7, lid = orig >> 3;
      bx = (xcd % fx) * rw + lid % rw;
      by = (xcd / fx) * rh + lid / rw;
      return;
    }
    const int q = nwg >> 3;
    const int xcd = orig & 7, lid = orig >> 3;
    const int wgid = xcd * q + lid;
    bx = wgid % gx; by = wgid / gx;
    return;
  }
  const int q = nwg >> 3, r = nwg & 7;
  const int xcd = orig & 7, lid = orig >> 3;
  const int wgid = (xcd < r ? xcd * (q + 1) : r * (q + 1) + (xcd - r) * q) + lid;
  bx = wgid % gx; by = wgid / gx;
}

// ---------------------------------------------------------------------------
// Shared epilogue for the 128x128 8-wave kernels: split-K merge via LDS,
// LDS tile staging, coalesced writeout. smem must hold >= 67584 bytes.
// ---------------------------------------------------------------------------
template<int OUTM, bool ACCUM, bool RELU, bool RANK1, bool BIAS>
__device__ __forceinline__ void epilogue128(
    u16* smem, f32x4 (&acc)[4][4],
    int z, int row0, int col0, int tid, int lane, int w, int wr, int wc,
    const float* bias, int sBias,
    float* Cf, u16* Cb, int ldc, long long sC,
    const float* r1row, int sR1r, const float* r1col, int sR1c)
{
  // cross-group merge: group 1 dumps acc to LDS, group 0 adds
  float* dump = (float*)smem;
  if (w >= 4) {
    float* reg = dump + ((w - 4) << 12);
    #pragma unroll
    for (int f = 0; f < 16; ++f) {
      int mi = f >> 2, ni = f & 3;
      *(f32x4*)(reg + (lane << 6) + (((f + lane) & 15) << 2)) = acc[mi][ni];
    }
  }
  asm volatile("s_waitcnt lgkmcnt(0)" ::: "memory");
  __builtin_amdgcn_s_barrier();
  asm volatile("" ::: "memory");
  if (w < 4) {
    float* reg = dump + (w << 12);
    #pragma unroll
    for (int f = 0; f < 16; ++f) {
      int mi = f >> 2, ni = f & 3;
      acc[mi][ni] += *(const f32x4*)(reg + (lane << 6) + (((f + lane) & 15) << 2));
    }
  }
  asm volatile("s_waitcnt lgkmcnt(0)" ::: "memory");
  __builtin_amdgcn_s_barrier();
  asm volatile("" ::: "memory");

  // tile store (group 0 only) into LDS [128][132] fp32
  float* tile = (float*)smem;
  if (w < 4) {
    const int cn  = lane & 15;
    const int rm4 = (lane >> 4) << 2;
    #pragma unroll
    for (int mi = 0; mi < 4; ++mi) {
      #pragma unroll
      for (int ni = 0; ni < 4; ++ni) {
        const int rl = wr + mi * 16 + rm4;
        const int cl = wc + ni * 16 + cn;
        if (OUTM == 2) {
          *(f32x4*)&tile[cl * 132 + rl] = acc[mi][ni];
        } else {
          #pragma unroll
          for (int j = 0; j < 4; ++j) tile[(rl + j) * 132 + cl] = acc[mi][ni][j];
        }
      }
    }
  }
  asm volatile("s_waitcnt lgkmcnt(0)" ::: "memory");
  __builtin_amdgcn_s_barrier();
  asm volatile("" ::: "memory");

  // coalesced writeout: all 512 threads, 8 passes of 16 rows
  #pragma unroll
  for (int p = 0; p < 8; ++p) {
    const int rr = p * 16 + (tid >> 5);
    const int c4 = (tid & 31) << 2;
    f32x4 v = *(const f32x4*)&tile[rr * 132 + c4];
    if (OUTM == 2) {
      const int cc = col0 + rr;
      float badd = BIAS ? bias[(long long)z * sBias + cc] : 0.f;
      u16* pp = Cb + (long long)z * sC + (long long)cc * ldc + row0 + c4;
      ushort4 o;
      o.x = f2bf(v[0] + badd); o.y = f2bf(v[1] + badd);
      o.z = f2bf(v[2] + badd); o.w = f2bf(v[3] + badd);
      *(ushort4*)pp = o;
    } else {
      const int R = row0 + rr;
      const long long idx = (long long)z * sC + (long long)R * ldc + col0 + c4;
      float val[4] = {v[0], v[1], v[2], v[3]};
      if (BIAS) {
        float4 b4 = *(const float4*)&bias[(long long)z * sBias + col0 + c4];
        val[0] += b4.x; val[1] += b4.y; val[2] += b4.z; val[3] += b4.w;
      }
      if (RANK1) {
        float rr1 = r1row[(long long)z * sR1r + R];
        float4 c4v = *(const float4*)&r1col[(long long)z * sR1c + col0 + c4];
        val[0] += rr1 * c4v.x; val[1] += rr1 * c4v.y;
        val[2] += rr1 * c4v.z; val[3] += rr1 * c4v.w;
      }
      if (OUTM == 0) {
        if (ACCUM) {
          float4 old = *(const float4*)&Cf[idx];
          val[0] += old.x; val[1] += old.y; val[2] += old.z; val[3] += old.w;
        }
        if (RELU) {
          val[0] = fmaxf(val[0], 0.f); val[1] = fmaxf(val[1], 0.f);
          val[2] = fmaxf(val[2], 0.f); val[3] = fmaxf(val[3], 0.f);
        }
        float4 o4; o4.x = val[0]; o4.y = val[1]; o4.z = val[2]; o4.w = val[3];
        *(float4*)&Cf[idx] = o4;
      } else {
        ushort4 o;
        o.x = f2bf(val[0]); o.y = f2bf(val[1]);
        o.z = f2bf(val[2]); o.w = f2bf(val[3]);
        *(ushort4*)&Cb[idx] = o;
      }
    }
  }
}

// ---------------------------------------------------------------------------
// 128x128 8-wave split-K MFMA GEMM, ring-4 (~68 KB LDS -> 2 blocks/CU).
// acc[4][4] = 64 VGPR fits the (512,4) 128-VGPR cap. Ledger: prologue stages
// pairs 0,1; per pair p: vmcnt(4) -> barrier -> reads -> lgkm0+barrier ->
// stage pair p+2 (into pair-p slots) -> MFMA.
// OUTM: 0 = fp32 [M,N], 1 = bf16 [M,N], 2 = bf16 [N,M] (transposed store).
// ---------------------------------------------------------------------------
template<int OUTM, bool ACCUM, bool RELU, bool RANK1, bool BIAS>
__global__ __launch_bounds__(512, 4) void mgemm8d_k(
    const u16* __restrict__ A, int lda, long long sA,
    const u16* __restrict__ B, int ldb, long long sB,
    const float* __restrict__ bias, int sBias,
    float* __restrict__ Cf, u16* __restrict__ Cb, int ldc, long long sC,
    int K,
    const float* __restrict__ r1row, int sR1r,
    const float* __restrict__ r1col, int sR1c)
{
  __shared__ u16 smem[33792];   // max(ring-4 64KB, epilogue tile 67.5KB)
  const int z = blockIdx.z;
  const u16* Ag = A + (long long)z * sA;
  const u16* Bg = B + (long long)z * sB;

  int bx, by;
  xcd_map(gridDim.x, gridDim.y, bx, by);

  const int row0 = by << 7;
  const int col0 = bx << 7;
  const int tid  = threadIdx.x;
  const int lane = tid & 63;
  const int w    = tid >> 6;
  const int g    = w >> 2;
  const int s4   = w & 3;
  const int wr   = (s4 >> 1) << 6;
  const int wc   = (s4 & 1) << 6;

  const int srow = tid >> 2;
  const int ssw  = (tid & 3) ^ ((srow >> 1) & 3);
  const long long aoff = (long long)(row0 + srow) * lda + ssw * 8;
  const long long boff = (long long)(col0 + srow) * ldb + ssw * 8;

  const int frow = lane & 15;
  const int fsw  = (lane >> 4) ^ ((frow >> 1) & 3);
  const int fAoff = ((wr + frow) << 5) + (fsw << 3);
  const int fBoff = ((wc + frow) << 5) + (fsw << 3);

#define STAGE4(tt) do {                                                        \
    u16* _sb = smem + (((tt) & 3) << 13);                                      \
    const long long _k = (long long)(tt) << 5;                                 \
    GLDS16(Ag + aoff + _k, _sb + (tid << 3));                                  \
    GLDS16(Bg + boff + _k, _sb + 4096 + (tid << 3));                           \
  } while (0)

  f32x4 acc[4][4];
  #pragma unroll
  for (int mi = 0; mi < 4; ++mi)
    #pragma unroll
    for (int ni = 0; ni < 4; ++ni) {
      acc[mi][ni][0] = 0.f; acc[mi][ni][1] = 0.f;
      acc[mi][ni][2] = 0.f; acc[mi][ni][3] = 0.f;
    }

  const int NT = K >> 5;
  const int NP = NT >> 1;   // >= 2 for all our shapes
  STAGE4(0); STAGE4(1); STAGE4(2); STAGE4(3);   // pairs 0,1 (8 loads)

  for (int p = 0; p < NP; ++p) {
    if (p + 1 < NP) asm volatile("s_waitcnt vmcnt(4)" ::: "memory");
    else            asm volatile("s_waitcnt vmcnt(0)" ::: "memory");
    __builtin_amdgcn_s_barrier();
    asm volatile("" ::: "memory");

    const u16* base = smem + (((2 * p + g) & 3) << 13);
    bf16x8 af[4], bfr[4];
    #pragma unroll
    for (int mi = 0; mi < 4; ++mi) af[mi]  = *(const bf16x8*)(base + fAoff + mi * 512);
    #pragma unroll
    for (int ni = 0; ni < 4; ++ni) bfr[ni] = *(const bf16x8*)(base + 4096 + fBoff + ni * 512);
    asm volatile("s_waitcnt lgkmcnt(0)" ::: "memory");
    __builtin_amdgcn_s_barrier();
    asm volatile("" ::: "memory");

    if (p + 2 < NP) { STAGE4(2 * p + 4); STAGE4(2 * p + 5); }

    __builtin_amdgcn_s_setprio(1);
    #pragma unroll
    for (int mi = 0; mi < 4; ++mi)
      #pragma unroll
      for (int ni = 0; ni < 4; ++ni)
        acc[mi][ni] = __builtin_amdgcn_mfma_f32_16x16x32_bf16(
            af[mi], bfr[ni], acc[mi][ni], 0, 0, 0);
    __builtin_amdgcn_s_setprio(0);
  }
#undef STAGE4

  epilogue128<OUTM, ACCUM, RELU, RANK1, BIAS>(
      smem, acc, z, row0, col0, tid, lane, w, wr, wc,
      bias, sBias, Cf, Cb, ldc, sC, r1row, sR1r, r1col, sR1c);
}

// ---------------------------------------------------------------------------
// 256x256 MFMA GEMM (R12-proven), 8 waves each owning 128x64. BK=32, ring-4
// x 32KB LDS (128 KB), 3 tiles in flight, counted vmcnt, direct epilogue.
// launch_bounds(512,2): acc[8][4]=128 VGPR needs the 256-VGPR cap; this
// kernel is structurally 1 block/CU (do NOT raise the occupancy floor).
// ---------------------------------------------------------------------------
template<bool BIAS>
__global__ __launch_bounds__(512, 2) void mgemm256_k(
    const u16* __restrict__ A, int lda, long long sA,
    const u16* __restrict__ B, int ldb, long long sB,
    const float* __restrict__ bias, int sBias,
    u16* __restrict__ Cb, int ldc, long long sC,
    int K)
{
  __shared__ u16 smem[4 * 16384];
  const int z = blockIdx.z;
  const u16* Ag = A + (long long)z * sA;
  const u16* Bg = B + (long long)z * sB;

  int bx, by;
  xcd_map(gridDim.x, gridDim.y, bx, by);

  const int row0r = by << 8;
  const int col0 = bx << 8;
  const int tid  = threadIdx.x;
  const int lane = tid & 63;
  const int w    = tid >> 6;
  const int wrow = w >> 2;
  const int wcol = w & 3;

  const int srow = tid >> 2;
  const int ssw  = (tid & 3) ^ ((srow >> 1) & 3);
  const long long aoff0 = (long long)(row0r + srow)       * lda + ssw * 8;
  const long long aoff1 = (long long)(row0r + srow + 128) * lda + ssw * 8;
  const long long boff0 = (long long)(col0 + srow)        * ldb + ssw * 8;
  const long long boff1 = (long long)(col0 + srow + 128)  * ldb + ssw * 8;

  const int frow = lane & 15;
  const int fsw  = (lane >> 4) ^ ((frow >> 1) & 3);
  const int fAoff = ((wrow * 128 + frow) << 5) + (fsw << 3);
  const int fBoff = ((wcol * 64  + frow) << 5) + (fsw << 3);

#define STG256(tt) do {                                                        \
    u16* _sb = smem + (((tt) & 3) << 14);                                      \
    const long long _k = (long long)(tt) << 5;                                 \
    GLDS16(Ag + aoff0 + _k, _sb + (tid << 3));                                 \
    GLDS16(Ag + aoff1 + _k, _sb + 4096 + (tid << 3));                          \
    GLDS16(Bg + boff0 + _k, _sb + 8192 + (tid << 3));                          \
    GLDS16(Bg + boff1 + _k, _sb + 12288 + (tid << 3));                         \
  } while (0)

  f32x4 acc[8][4];
  #pragma unroll
  for (int mi = 0; mi < 8; ++mi)
    #pragma unroll
    for (int ni = 0; ni < 4; ++ni) {
      acc[mi][ni][0] = 0.f; acc[mi][ni][1] = 0.f;
      acc[mi][ni][2] = 0.f; acc[mi][ni][3] = 0.f;
    }

  const int NT = K >> 5;
  STG256(0); STG256(1); STG256(2);
  asm volatile("s_waitcnt vmcnt(8)" ::: "memory");
  __builtin_amdgcn_s_barrier();
  asm volatile("" ::: "memory");

  for (int t = 0; t < NT; ++t) {
    if (t + 3 < NT) STG256(t + 3);

    const u16* base = smem + ((t & 3) << 14);
    bf16x8 af[8], bfr[4];
    #pragma unroll
    for (int mi = 0; mi < 8; ++mi) af[mi]  = *(const bf16x8*)(base + fAoff + mi * 512);
    #pragma unroll
    for (int ni = 0; ni < 4; ++ni) bfr[ni] = *(const bf16x8*)(base + 8192 + fBoff + ni * 512);
    __builtin_amdgcn_s_setprio(1);
    #pragma unroll
    for (int mi = 0; mi < 8; ++mi)
      #pragma unroll
      for (int ni = 0; ni < 4; ++ni)
        acc[mi][ni] = __builtin_amdgcn_mfma_f32_16x16x32_bf16(
            af[mi], bfr[ni], acc[mi][ni], 0, 0, 0);
    __builtin_amdgcn_s_setprio(0);

    if (t + 1 < NT) {
      if (t + 3 < NT)      asm volatile("s_waitcnt vmcnt(8)" ::: "memory");
      else if (t + 2 < NT) asm volatile("s_waitcnt vmcnt(4)" ::: "memory");
      else                 asm volatile("s_waitcnt vmcnt(0)" ::: "memory");
      __builtin_amdgcn_s_barrier();
      asm volatile("" ::: "memory");
    }
  }
#undef STG256

  const int cn  = lane & 15;
  const int rm4 = (lane >> 4) << 2;
  #pragma unroll
  for (int mi = 0; mi < 8; ++mi) {
    #pragma unroll
    for (int ni = 0; ni < 4; ++ni) {
      const int rb = row0r + wrow * 128 + mi * 16 + rm4;
      const int cc = col0 + wcol * 64 + ni * 16 + cn;
      float badd = BIAS ? bias[(long long)z * sBias + cc] : 0.f;
      f32x4 v = acc[mi][ni];
      #pragma unroll
      for (int j = 0; j < 4; ++j)
        Cb[(long long)z * sC + (long long)(rb + j) * ldc + cc] = f2bf(v[j] + badd);
    }
  }
}

// out = relu(p0+p1+p2+p3), partials stride 1M floats, n4 = n/4 float4s
__global__ __launch_bounds__(256) void reduce4relu_k(
    const float* __restrict__ p, float* __restrict__ out, int n4)
{
  int i = blockIdx.x * 256 + threadIdx.x;
  if (i < n4) {
    float4 a = ((const float4*)p)[i];
    float4 b = ((const float4*)(p + (1ll << 20)))[i];
    float4 c = ((const float4*)(p + (2ll << 20)))[i];
    float4 d = ((const float4*)(p + (3ll << 20)))[i];
    float4 o;
    o.x = fmaxf(a.x + b.x + c.x + d.x, 0.f);
    o.y = fmaxf(a.y + b.y + c.y + d.y, 0.f);
    o.z = fmaxf(a.z + b.z + c.z + d.z, 0.f);
    o.w = fmaxf(a.w + b.w + c.w + d.w, 0.f);
    ((float4*)out)[i] = o;
  }
}

// ---------------------------------------------------------------------------
__global__ __launch_bounds__(256) void xpose_k(
    const float* __restrict__ in, float* __restrict__ out, int R, int Cc)
{
  __shared__ float tile[32][33];
  int c0 = blockIdx.x * 32, r0 = blockIdx.y * 32;
  int tx = threadIdx.x & 31, ty = threadIdx.x >> 5;
  #pragma unroll
  for (int rr = ty; rr < 32; rr += 8)
    tile[rr][tx] = in[(long long)(r0 + rr) * Cc + c0 + tx];
  __syncthreads();
  #pragma unroll
  for (int cc = ty; cc < 32; cc += 8)
    out[(long long)(c0 + cc) * R + r0 + tx] = tile[tx][cc];
}

__global__ __launch_bounds__(256) void tcvt_k(
    const float* __restrict__ in, u16* __restrict__ out, int R, int Cc)
{
  __shared__ float tile[32][33];
  int c0 = blockIdx.x * 32, r0 = blockIdx.y * 32;
  int tx = threadIdx.x & 31, ty = threadIdx.x >> 5;
  #pragma unroll
  for (int rr = ty; rr < 32; rr += 8)
    tile[rr][tx] = in[(long long)(r0 + rr) * Cc + c0 + tx];
  __syncthreads();
  #pragma unroll
  for (int cc = ty; cc < 32; cc += 8)
    out[(long long)(c0 + cc) * R + r0 + tx] = f2bf(tile[tx][cc]);
}

__global__ __launch_bounds__(256) void tcvt_aff_k(
    const float* __restrict__ in, u16* __restrict__ out, int R, int Cc,
    const float* __restrict__ A2, const float* __restrict__ C2)
{
  __shared__ float tile[32][33];
  int c0 = blockIdx.x * 32, r0 = blockIdx.y * 32;
  int tx = threadIdx.x & 31, ty = threadIdx.x >> 5;
  #pragma unroll
  for (int rr = ty; rr < 32; rr += 8)
    tile[rr][tx] = in[(long long)(r0 + rr) * Cc + c0 + tx];
  __syncthreads();
  #pragma unroll
  for (int cc = ty; cc < 32; cc += 8) {
    float v = A2[c0 + cc] * tile[tx][cc] + C2[c0 + cc];
    out[(long long)(c0 + cc) * R + r0 + tx] = f2bf(v);
  }
}

__global__ __launch_bounds__(256) void cvt_k(
    const float* __restrict__ in, u16* __restrict__ out)
{
  int i = blockIdx.x * 256 + threadIdx.x;
  float4 v = ((const float4*)in)[i];
  ushort4 o;
  o.x = f2bf(v.x); o.y = f2bf(v.y); o.z = f2bf(v.z); o.w = f2bf(v.w);
  ((ushort4*)out)[i] = o;
}

__global__ __launch_bounds__(256) void pack2_k(
    const float* __restrict__ a, const float* __restrict__ b,
    float* __restrict__ out, int n)
{
  int i = blockIdx.x * 256 + threadIdx.x;
  if (i < n) { out[i] = a[i]; out[n + i] = b[i]; }
}

// ---------------------------------------------------------------------------
__global__ __launch_bounds__(64) void qe_k(const u16* __restrict__ Q1,
                                           const float* __restrict__ We1,
                                           float* __restrict__ qe)
{
  int h = blockIdx.x >> 10;
  int i = blockIdx.x & 1023;
  const u16* q = Q1 + (long long)i * 4096 + h * 512;
  const float* wv = We1 + h * 512;
  int l = threadIdx.x;
  float s = 0.f;
  #pragma unroll
  for (int r = 0; r < 8; ++r) s += bf2f(q[l + r * 64]) * wv[l + r * 64];
  #pragma unroll
  for (int off = 32; off > 0; off >>= 1) s += __shfl_down(s, off);
  if (l == 0) qe[blockIdx.x] = s;
}

// ---------------------------------------------------------------------------
__global__ __launch_bounds__(256) void softmax1b_k(
    u16* __restrict__ S, const float* __restrict__ xT,
    const float* __restrict__ qe, float* __restrict__ ae)
{
  int i = blockIdx.x, h = blockIdx.y;
  u16* s = S + ((long long)h * 1024 + i) * 1024;
  const float* e = xT + (long long)i * 1024;
  float q = qe[h * 1024 + i];
  int tid = threadIdx.x;
  __shared__ float red[256];

  ushort4 sv = ((const ushort4*)s)[tid];
  float4  evv = ((const float4*)e)[tid];
  float ev[4] = {evv.x, evv.y, evv.z, evv.w};
  float t[4];
  t[0] = (bf2f(sv.x) + q * ev[0]) * kInvSqrtD;
  t[1] = (bf2f(sv.y) + q * ev[1]) * kInvSqrtD;
  t[2] = (bf2f(sv.z) + q * ev[2]) * kInvSqrtD;
  t[3] = (bf2f(sv.w) + q * ev[3]) * kInvSqrtD;
  float m = fmaxf(fmaxf(t[0], t[1]), fmaxf(t[2], t[3]));
  m = blockReduceMax(m, red);
  float sum = 0.f;
  #pragma unroll
  for (int r = 0; r < 4; ++r) { t[r] = __expf(t[r] - m); sum += t[r]; }
  sum = blockReduceSum(sum, red);
  float invl = 1.f / sum;
  float aes = 0.f;
  ushort4 o;
  o.x = f2bf(t[0] * invl); o.y = f2bf(t[1] * invl);
  o.z = f2bf(t[2] * invl); o.w = f2bf(t[3] * invl);
  #pragma unroll
  for (int r = 0; r < 4; ++r) aes += (t[r] * invl) * ev[r];
  ((ushort4*)s)[tid] = o;
  aes = blockReduceSum(aes, red);
  if (tid == 0) ae[h * 1024 + i] = aes;
}

__global__ __launch_bounds__(256) void softmax2b_k(u16* __restrict__ S)
{
  u16* s = S + ((long long)blockIdx.y * 2048 + blockIdx.x) * 4096;
  int tid = threadIdx.x;
  __shared__ float red[256];
  float t[16];
  float m = -1e30f;
  #pragma unroll
  for (int r = 0; r < 4; ++r) {
    ushort4 sv = ((const ushort4*)s)[tid + r * 256];
    t[r*4+0] = bf2f(sv.x) * kInvSqrtD; t[r*4+1] = bf2f(sv.y) * kInvSqrtD;
    t[r*4+2] = bf2f(sv.z) * kInvSqrtD; t[r*4+3] = bf2f(sv.w) * kInvSqrtD;
    m = fmaxf(m, fmaxf(fmaxf(t[r*4], t[r*4+1]), fmaxf(t[r*4+2], t[r*4+3])));
  }
  m = blockReduceMax(m, red);
  float sum = 0.f;
  #pragma unroll
  for (int r = 0; r < 16; ++r) { t[r] = __expf(t[r] - m); sum += t[r]; }
  sum = blockReduceSum(sum, red);
  float invl = 1.f / sum;
  #pragma unroll
  for (int r = 0; r < 4; ++r) {
    ushort4 o;
    o.x = f2bf(t[r*4+0] * invl); o.y = f2bf(t[r*4+1] * invl);
    o.z = f2bf(t[r*4+2] * invl); o.w = f2bf(t[r*4+3] * invl);
    ((ushort4*)s)[tid + r * 256] = o;
  }
}

// ---------------------------------------------------------------------------
__global__ __launch_bounds__(256) void colpart4_k(const float* __restrict__ h,
    int N, int F, int nchunk, float* __restrict__ ps, float* __restrict__ pss)
{
  const int f4 = blockIdx.x * 256 + threadIdx.x;
  const int chunk = blockIdx.y;
  const int rows = N / nchunk;
  const int rbeg = chunk * rows;
  const int F4 = F >> 2;
  const float4* h4 = (const float4*)h;
  float4 s = {0.f, 0.f, 0.f, 0.f}, ss = {0.f, 0.f, 0.f, 0.f};
  #pragma unroll 8
  for (int i = 0; i < rows; ++i) {
    float4 v = h4[(long long)(rbeg + i) * F4 + f4];
    s.x += v.x; s.y += v.y; s.z += v.z; s.w += v.w;
    ss.x += v.x * v.x; ss.y += v.y * v.y;
    ss.z += v.z * v.z; ss.w += v.w * v.w;
  }
  ((float4*)(ps  + (long long)chunk * F))[f4] = s;
  ((float4*)(pss + (long long)chunk * F))[f4] = ss;
}

// Parallel finisher: one block per float4-column; 256 threads split chunks.
template<int MODE>
__global__ __launch_bounds__(256) void colfin2_k(
    const float* __restrict__ ps, const float* __restrict__ pss,
    int F, int nchunk, float Nf,
    const float* __restrict__ ms, const float* __restrict__ g,
    const float* __restrict__ beta,
    float* __restrict__ outA, float* __restrict__ outC)
{
  __shared__ float4 red4[256];
  const int f4 = blockIdx.x;
  const int tid = threadIdx.x;
  float4 s = {0.f, 0.f, 0.f, 0.f}, ss = {0.f, 0.f, 0.f, 0.f};
  for (int c = tid; c < nchunk; c += 256) {
    float4 v = ((const float4*)(ps  + (long long)c * F))[f4];
    float4 u = ((const float4*)(pss + (long long)c * F))[f4];
    s.x += v.x; s.y += v.y; s.z += v.z; s.w += v.w;
    ss.x += u.x; ss.y += u.y; ss.z += u.z; ss.w += u.w;
  }
  s  = blockReduceF4(s, red4);
  ss = blockReduceF4(ss, red4);
  if (tid < 4) {
    const int f = f4 * 4 + tid;
    float sv  = (tid == 0) ? s.x  : (tid == 1) ? s.y  : (tid == 2) ? s.z  : s.w;
    float ssv = (tid == 0) ? ss.x : (tid == 1) ? ss.y : (tid == 2) ? ss.z : ss.w;
    float Ninv = 1.f / Nf;
    float mean = sv * Ninv;
    float mm = ms[f] * mean;
    float var = ssv * Ninv - 2.f * mm * mean + mm * mm;
    float is = rsqrtf(var + 1e-5f);
    float a = g[f] * is;
    float c = beta[f] - a * mm;
    if (MODE == 1) {
      float sy2 = a * a * ssv + 2.f * a * c * sv + Nf * c * c;
      float cinv = rsqrtf(sy2);
      a *= cinv; c *= cinv;
    }
    outA[f] = a;
    outC[f] = c;
  }
}

__global__ __launch_bounds__(256) void rowl2gn_k(
    float* __restrict__ h, u16* __restrict__ hb,
    const float* __restrict__ a, const float* __restrict__ c)
{
  int i = blockIdx.x;
  float* row = h + (long long)i * 4096;
  u16* rb = hb + (long long)i * 4096;
  int tid = threadIdx.x;
  __shared__ float red[256];
  float t[16];
  float ss = 0.f;
  #pragma unroll
  for (int r = 0; r < 4; ++r) {
    int j = tid + r * 256;
    float4 hv = ((const float4*)row)[j];
    float4 av = ((const float4*)a)[j];
    float4 cv = ((const float4*)c)[j];
    t[r*4+0] = av.x * hv.x + cv.x;
    t[r*4+1] = av.y * hv.y + cv.y;
    t[r*4+2] = av.z * hv.z + cv.z;
    t[r*4+3] = av.w * hv.w + cv.w;
    ss += t[r*4+0]*t[r*4+0] + t[r*4+1]*t[r*4+1]
        + t[r*4+2]*t[r*4+2] + t[r*4+3]*t[r*4+3];
  }
  ss = blockReduceSum(ss, red);
  float inv = rsqrtf(ss);
  #pragma unroll
  for (int r = 0; r < 4; ++r) {
    int j = tid + r * 256;
    float4 o4;
    o4.x = t[r*4+0] * inv; o4.y = t[r*4+1] * inv;
    o4.z = t[r*4+2] * inv; o4.w = t[r*4+3] * inv;
    ((float4*)row)[j] = o4;
    ushort4 ob;
    ob.x = f2bf(o4.x); ob.y = f2bf(o4.y); ob.z = f2bf(o4.z); ob.w = f2bf(o4.w);
    ((ushort4*)rb)[j] = ob;
  }
}

// ---------------------------------------------------------------------------
extern "C" void kernel_launch(void* const* d_in, const int* in_sizes, int n_in,
                              void* d_out, int out_size, void* d_ws, size_t ws_size,
                              hipStream_t stream)
{
  (void)in_sizes; (void)n_in; (void)out_size; (void)ws_size;

  const float* x      = (const float*)d_in[0];
  const float* Wq1    = (const float*)d_in[1];
  const float* bq1    = (const float*)d_in[2];
  const float* Wk1    = (const float*)d_in[3];
  const float* bk1    = (const float*)d_in[4];
  const float* Wv1    = (const float*)d_in[5];
  const float* bv1    = (const float*)d_in[6];
  const float* We1    = (const float*)d_in[7];
  const float* Wskip1 = (const float*)d_in[8];
  const float* bskip1 = (const float*)d_in[9];
  const float* g1     = (const float*)d_in[10];
  const float* bb1    = (const float*)d_in[11];
  const float* ms1    = (const float*)d_in[12];
  const float* Wq2    = (const float*)d_in[13];
  const float* bq2    = (const float*)d_in[14];
  const float* Wk2    = (const float*)d_in[15];
  const float* bk2    = (const float*)d_in[16];
  const float* Wv2    = (const float*)d_in[17];
  const float* bv2    = (const float*)d_in[18];
  const float* Wskip2 = (const float*)d_in[19];
  const float* bskip2 = (const float*)d_in[20];
  const float* g2     = (const float*)d_in[21];
  const float* bb2    = (const float*)d_in[22];
  const float* ms2    = (const float*)d_in[23];

  // ---- workspace arena (~209 MB) ----
  char* base = (char*)d_ws;
  float* lrx_f   = (float*)(base);                 // 16MB [1024][4096]
  u16*   lrx_bf  = (u16*)  (base + (16ll << 20));  // 8MB
  u16*   lrxT_bf = (u16*)  (base + (24ll << 20));  // 8MB [4096][1024]
  u16*   hrx_bf  = (u16*)  (base + (32ll << 20));  // 16MB [2048][4096]
  char* sh = base + (48ll << 20);                  // shared region, 160MB
  // stage A
  u16* x_bf  = (u16*)(sh);                         // 2MB
  float* xT  = (float*)(sh + (2ll << 20));         // 4MB
  u16* Wq1T  = (u16*)(sh + (6ll << 20));           // 8MB each (Wk1T follows Wq1T)
  u16* Wk1T  = (u16*)(sh + (14ll << 20));
  u16* Wv1T  = (u16*)(sh + (22ll << 20));
  u16* Ws1T  = (u16*)(sh + (30ll << 20));
  u16* Q1bf  = (u16*)(sh + (38ll << 20));          // 8MB [1024][4096] (K1bf follows)
  u16* K1bf  = (u16*)(sh + (46ll << 20));          // 8MB
  u16* V1T   = (u16*)(sh + (54ll << 20));          // 8MB [4096][1024]
  u16* S1bf  = (u16*)(sh + (62ll << 20));          // 16MB [8][1024][1024]
  // GN1 partials in dead S1bf space (consumed before V2T/H2 writes)
  float* ps1  = (float*)(sh + (66ll << 20));       // 2MB [128][4096]
  float* pss1 = (float*)(sh + (68ll << 20));       // 2MB
  // stage B (aliases stage A)
  u16* Wq2T  = (u16*)(sh);                         // 4MB each (Wk2T follows)
  u16* Wk2T  = (u16*)(sh + (4ll << 20));
  u16* Wv2T  = (u16*)(sh + (8ll << 20));
  u16* Ws2T  = (u16*)(sh + (12ll << 20));
  u16* Q2bf  = (u16*)(sh + (16ll << 20));          // 16MB [4096][2048] (K2bf follows)
  u16* K2bf  = (u16*)(sh + (32ll << 20));          // 16MB
  u16* V2T   = (u16*)(sh + (48ll << 20));          // 16MB [2048][4096]
  float* H2  = (float*)(sh + (64ll << 20));        // 32MB [4096][2048]
  u16* S2bf  = (u16*)(sh + (96ll << 20));          // 64MB [4][2048][4096]
  float* gpart = (float*)(sh + (96ll << 20));      // 16MB lr-gram partials (S2 dead)
  // GN2 partials in dead S2bf space (consumed before gpart written)
  float* ps2  = (float*)(sh + (120ll << 20));      // 2MB [256][2048]
  float* pss2 = (float*)(sh + (122ll << 20));      // 2MB
  // small tail
  float* tail    = (float*)(base + (208ll << 20));
  float* qe      = tail;             // 8192
  float* ae      = qe + 8192;        // 8192
  float* af1     = ae + 8192;        // 4096
  float* cf1     = af1 + 4096;       // 4096
  float* A2v     = cf1 + 4096;       // 2048
  float* C2v     = A2v + 2048;       // 2048
  float* biasQK1 = C2v + 2048;       // 8192
  float* biasQK2 = biasQK1 + 8192;   // 4096

  float* out0 = (float*)d_out;                   // hr [2048][2048]
  float* out1 = out0 + (long long)2048 * 2048;   // lr gram [1024][1024]

  // ---- stage 0: conversions ----
  xpose_k<<<dim3(32, 32), 256, 0, stream>>>(x, xT, 1024, 1024);
  cvt_k<<<dim3(1024), 256, 0, stream>>>(x, x_bf);
  tcvt_k<<<dim3(128, 32), 256, 0, stream>>>(Wq1,    Wq1T, 1024, 4096);
  tcvt_k<<<dim3(128, 32), 256, 0, stream>>>(Wk1,    Wk1T, 1024, 4096);
  tcvt_k<<<dim3(128, 32), 256, 0, stream>>>(Wv1,    Wv1T, 1024, 4096);
  tcvt_k<<<dim3(128, 32), 256, 0, stream>>>(Wskip1, Ws1T, 1024, 4096);
  pack2_k<<<dim3(16), 256, 0, stream>>>(bq1, bk1, biasQK1, 4096);
  pack2_k<<<dim3(8),  256, 0, stream>>>(bq2, bk2, biasQK2, 2048);

  // ---- conv1 Q+K batched (z=2), V (transposed out), skip (fp32) ----
  mgemm8d_k<1,false,false,false,true><<<dim3(32, 8, 2), 512, 0, stream>>>(
      x_bf, 1024, 0, Wq1T, 1024, (long long)4096 * 1024, biasQK1, 4096,
      nullptr, Q1bf, 4096, (long long)1024 * 4096, 1024, nullptr, 0, nullptr, 0);
  mgemm8d_k<2,false,false,false,true><<<dim3(32, 8, 1), 512, 0, stream>>>(
      x_bf, 1024, 0, Wv1T, 1024, 0, bv1, 0, nullptr, V1T, 1024, 0, 1024,
      nullptr, 0, nullptr, 0);
  mgemm8d_k<0,false,false,false,true><<<dim3(32, 8, 1), 512, 0, stream>>>(
      x_bf, 1024, 0, Ws1T, 1024, 0, bskip1, 0, lrx_f, nullptr, 4096, 0, 1024,
      nullptr, 0, nullptr, 0);

  qe_k<<<dim3(8192), 64, 0, stream>>>(Q1bf, We1, qe);

  // ---- scores1[h] = Q1h @ K1h^T (raw, bf16 out), batch z=8 heads ----
  mgemm8d_k<1,false,false,false,false><<<dim3(8, 8, 8), 512, 0, stream>>>(
      Q1bf, 4096, 512, K1bf, 4096, 512, nullptr, 0, nullptr, S1bf, 1024, 1048576,
      512, nullptr, 0, nullptr, 0);

  softmax1b_k<<<dim3(1024, 8), 256, 0, stream>>>(S1bf, xT, qe, ae);

  // ---- PV1: lrx += alpha @ V1h + ae*Weh ----
  mgemm8d_k<0,true,false,true,false><<<dim3(4, 8, 8), 512, 0, stream>>>(
      S1bf, 1024, 1048576, V1T, 1024, 512 * 1024, nullptr, 0, lrx_f, nullptr,
      4096, 512, 1024, ae, 1024, We1, 512);

  // ---- GraphNorm1 (affine) + row L2, fused ----
  colpart4_k<<<dim3(4, 128), 256, 0, stream>>>(lrx_f, 1024, 4096, 128, ps1, pss1);
  colfin2_k<0><<<dim3(1024), 256, 0, stream>>>(ps1, pss1, 4096, 128, 1024.f,
                                               ms1, g1, bb1, af1, cf1);
  rowl2gn_k<<<dim3(1024), 256, 0, stream>>>(lrx_f, lrx_bf, af1, cf1);
  tcvt_k<<<dim3(128, 32), 256, 0, stream>>>(lrx_f, lrxT_bf, 1024, 4096);

  // ---- conv2 weights ----
  tcvt_k<<<dim3(64, 32), 256, 0, stream>>>(Wq2,    Wq2T, 1024, 2048);
  tcvt_k<<<dim3(64, 32), 256, 0, stream>>>(Wk2,    Wk2T, 1024, 2048);
  tcvt_k<<<dim3(64, 32), 256, 0, stream>>>(Wv2,    Wv2T, 1024, 2048);
  tcvt_k<<<dim3(64, 32), 256, 0, stream>>>(Wskip2, Ws2T, 1024, 2048);

  // ---- conv2 Q+K on 256^2 kernel (R12-proven); V + skip on 128^2 ----
  mgemm256_k<true><<<dim3(8, 16, 2), 512, 0, stream>>>(
      lrxT_bf, 1024, 0, Wq2T, 1024, (long long)2048 * 1024, biasQK2, 2048,
      Q2bf, 2048, (long long)4096 * 2048, 1024);
  mgemm8d_k<2,false,false,false,true><<<dim3(16, 32, 1), 512, 0, stream>>>(
      lrxT_bf, 1024, 0, Wv2T, 1024, 0, bv2, 0, nullptr, V2T, 4096, 0, 1024,
      nullptr, 0, nullptr, 0);
  mgemm8d_k<0,false,false,false,true><<<dim3(16, 32, 1), 512, 0, stream>>>(
      lrxT_bf, 1024, 0, Ws2T, 1024, 0, bskip2, 0, H2, nullptr, 2048, 0, 1024,
      nullptr, 0, nullptr, 0);

  // ---- conv2 attention in 2 chunks of 2048 rows ----
  for (int c = 0; c < 2; ++c) {
    const u16* Qc = Q2bf + (long long)c * 2048 * 2048;
    float* Hc = H2 + (long long)c * 2048 * 2048;
    mgemm256_k<false><<<dim3(16, 8, 4), 512, 0, stream>>>(
        Qc, 2048, 512, K2bf, 2048, 512, nullptr, 0,
        S2bf, 4096, (long long)2048 * 4096, 512);
    softmax2b_k<<<dim3(2048, 4), 256, 0, stream>>>(S2bf);
    mgemm8d_k<0,true,false,false,false><<<dim3(4, 16, 4), 512, 0, stream>>>(
        S2bf, 4096, (long long)2048 * 4096, V2T, 4096, (long long)512 * 4096,
        nullptr, 0, Hc, nullptr, 2048, 512, 4096, nullptr, 0, nullptr, 0);
  }

  // ---- GraphNorm2 + column L2 fused into one affine transpose-convert ----
  colpart4_k<<<dim3(2, 256), 256, 0, stream>>>(H2, 4096, 2048, 256, ps2, pss2);
  colfin2_k<1><<<dim3(512), 256, 0, stream>>>(ps2, pss2, 2048, 256, 4096.f,
                                              ms2, g2, bb2, A2v, C2v);
  tcvt_aff_k<<<dim3(64, 128), 256, 0, stream>>>(H2, hrx_bf, 4096, 2048, A2v, C2v);

  // ---- outputs: relu Grams ----
  mgemm8d_k<0,false,true,false,false><<<dim3(16, 16, 1), 512, 0, stream>>>(
      hrx_bf, 4096, 0, hrx_bf, 4096, 0, nullptr, 0, out0, nullptr, 2048, 0, 4096,
      nullptr, 0, nullptr, 0);
  // lr-gram: grid-split K 4-way (z) into partials, then reduce+relu
  mgemm8d_k<0,false,false,false,false><<<dim3(8, 8, 4), 512, 0, stream>>>(
      lrx_bf, 4096, 1024, lrx_bf, 4096, 1024, nullptr, 0, gpart, nullptr, 1024,
      (long long)1 << 20, 1024, nullptr, 0, nullptr, 0);
  reduce4relu_k<<<dim3(1024), 256, 0, stream>>>(gpart, out1, 262144);
}

// Round 15
// 629.766 us; speedup vs baseline: 2.5850x; 1.0174x over previous
//
#include <hip/hip_runtime.h>
#include <hip/hip_bf16.h>

typedef unsigned short u16;
typedef __attribute__((ext_vector_type(8))) short bf16x8;
typedef __attribute__((ext_vector_type(4))) float f32x4;

__device__ __constant__ float kInvSqrtD = 0.04419417382415922f; // 1/sqrt(512)

__device__ __forceinline__ u16 f2bf(float f) {
  union { float f; unsigned u; } a; a.f = f;
  unsigned r = a.u + 0x7FFFu + ((a.u >> 16) & 1u);
  return (u16)(r >> 16);
}
__device__ __forceinline__ float bf2f(u16 u) {
  union { unsigned u; float f; } a; a.u = ((unsigned)u) << 16;
  return a.f;
}

// ---------------------------------------------------------------------------
// Block reductions (blockDim.x == 256)
// ---------------------------------------------------------------------------
__device__ __forceinline__ float blockReduceMax(float v, float* red) {
  int tid = threadIdx.x;
  red[tid] = v; __syncthreads();
  #pragma unroll
  for (int w = 128; w > 0; w >>= 1) {
    if (tid < w) red[tid] = fmaxf(red[tid], red[tid + w]);
    __syncthreads();
  }
  float r = red[0];
  __syncthreads();
  return r;
}
__device__ __forceinline__ float blockReduceSum(float v, float* red) {
  int tid = threadIdx.x;
  red[tid] = v; __syncthreads();
  #pragma unroll
  for (int w = 128; w > 0; w >>= 1) {
    if (tid < w) red[tid] = red[tid] + red[tid + w];
    __syncthreads();
  }
  float r = red[0];
  __syncthreads();
  return r;
}

__device__ __forceinline__ float4 blockReduceF4(float4 v, float4* red) {
  int tid = threadIdx.x;
  red[tid] = v; __syncthreads();
  #pragma unroll
  for (int w = 128; w > 0; w >>= 1) {
    if (tid < w) {
      float4 a = red[tid], b = red[tid + w];
      a.x += b.x; a.y += b.y; a.z += b.z; a.w += b.w;
      red[tid] = a;
    }
    __syncthreads();
  }
  float4 r = red[0];
  __syncthreads();
  return r;
}

#define GLDS16(gp, lp)                                                         \
  __builtin_amdgcn_global_load_lds(                                            \
      (const __attribute__((address_space(1))) void*)(gp),                     \
      (__attribute__((address_space(3))) void*)(lp), 16, 0, 0)

// 2-D rectangular XCD partition (bijective); fallback: 1-D chunks
__device__ __forceinline__ void xcd_map(int gx, int gy, int& bx, int& by) {
  const int nwg = gx * gy;
  const int orig = blockIdx.y * gx + blockIdx.x;
  if ((nwg & 7) == 0) {
    int bestfx = 0, bestcost = 1 << 30;
    #pragma unroll
    for (int fx = 1; fx <= 8; fx <<= 1) {
      int fy = 8 / fx;
      if ((gx % fx) == 0 && (gy % fy) == 0) {
        int cost = gx / fx + gy / fy;
        if (cost < bestcost) { bestcost = cost; bestfx = fx; }
      }
    }
    if (bestfx > 0) {
      const int fx = bestfx, fy = 8 / bestfx;
      const int rw = gx / fx, rh = gy / fy;
      const int xcd = orig & 7, lid = orig >> 3;
      bx = (xcd % fx) * rw + lid % rw;
      by = (xcd / fx) * rh + lid / rw;
      return;
    }
    const int q = nwg >> 3;
    const int xcd = orig & 7, lid = orig >> 3;
    const int wgid = xcd * q + lid;
    bx = wgid % gx; by = wgid / gx;
    return;
  }
  const int q = nwg >> 3, r = nwg & 7;
  const int xcd = orig & 7, lid = orig >> 3;
  const int wgid = (xcd < r ? xcd * (q + 1) : r * (q + 1) + (xcd - r) * q) + lid;
  bx = wgid % gx; by = wgid / gx;
}

// ---------------------------------------------------------------------------
// Shared epilogue for the 128x128 8-wave kernels: split-K merge via LDS,
// LDS tile staging, coalesced writeout. smem must hold >= 67584 bytes.
// ---------------------------------------------------------------------------
template<int OUTM, bool ACCUM, bool RELU, bool RANK1, bool BIAS>
__device__ __forceinline__ void epilogue128(
    u16* smem, f32x4 (&acc)[4][4],
    int z, int row0, int col0, int tid, int lane, int w, int wr, int wc,
    const float* bias, int sBias,
    float* Cf, u16* Cb, int ldc, long long sC,
    const float* r1row, int sR1r, const float* r1col, int sR1c)
{
  // cross-group merge: group 1 dumps acc to LDS, group 0 adds
  float* dump = (float*)smem;
  if (w >= 4) {
    float* reg = dump + ((w - 4) << 12);
    #pragma unroll
    for (int f = 0; f < 16; ++f) {
      int mi = f >> 2, ni = f & 3;
      *(f32x4*)(reg + (lane << 6) + (((f + lane) & 15) << 2)) = acc[mi][ni];
    }
  }
  asm volatile("s_waitcnt lgkmcnt(0)" ::: "memory");
  __builtin_amdgcn_s_barrier();
  asm volatile("" ::: "memory");
  if (w < 4) {
    float* reg = dump + (w << 12);
    #pragma unroll
    for (int f = 0; f < 16; ++f) {
      int mi = f >> 2, ni = f & 3;
      acc[mi][ni] += *(const f32x4*)(reg + (lane << 6) + (((f + lane) & 15) << 2));
    }
  }
  asm volatile("s_waitcnt lgkmcnt(0)" ::: "memory");
  __builtin_amdgcn_s_barrier();
  asm volatile("" ::: "memory");

  // tile store (group 0 only) into LDS [128][132] fp32
  float* tile = (float*)smem;
  if (w < 4) {
    const int cn  = lane & 15;
    const int rm4 = (lane >> 4) << 2;
    #pragma unroll
    for (int mi = 0; mi < 4; ++mi) {
      #pragma unroll
      for (int ni = 0; ni < 4; ++ni) {
        const int rl = wr + mi * 16 + rm4;
        const int cl = wc + ni * 16 + cn;
        if (OUTM == 2) {
          *(f32x4*)&tile[cl * 132 + rl] = acc[mi][ni];
        } else {
          #pragma unroll
          for (int j = 0; j < 4; ++j) tile[(rl + j) * 132 + cl] = acc[mi][ni][j];
        }
      }
    }
  }
  asm volatile("s_waitcnt lgkmcnt(0)" ::: "memory");
  __builtin_amdgcn_s_barrier();
  asm volatile("" ::: "memory");

  // coalesced writeout: all 512 threads, 8 passes of 16 rows
  #pragma unroll
  for (int p = 0; p < 8; ++p) {
    const int rr = p * 16 + (tid >> 5);
    const int c4 = (tid & 31) << 2;
    f32x4 v = *(const f32x4*)&tile[rr * 132 + c4];
    if (OUTM == 2) {
      const int cc = col0 + rr;
      float badd = BIAS ? bias[(long long)z * sBias + cc] : 0.f;
      u16* pp = Cb + (long long)z * sC + (long long)cc * ldc + row0 + c4;
      ushort4 o;
      o.x = f2bf(v[0] + badd); o.y = f2bf(v[1] + badd);
      o.z = f2bf(v[2] + badd); o.w = f2bf(v[3] + badd);
      *(ushort4*)pp = o;
    } else {
      const int R = row0 + rr;
      const long long idx = (long long)z * sC + (long long)R * ldc + col0 + c4;
      float val[4] = {v[0], v[1], v[2], v[3]};
      if (BIAS) {
        float4 b4 = *(const float4*)&bias[(long long)z * sBias + col0 + c4];
        val[0] += b4.x; val[1] += b4.y; val[2] += b4.z; val[3] += b4.w;
      }
      if (RANK1) {
        float rr1 = r1row[(long long)z * sR1r + R];
        float4 c4v = *(const float4*)&r1col[(long long)z * sR1c + col0 + c4];
        val[0] += rr1 * c4v.x; val[1] += rr1 * c4v.y;
        val[2] += rr1 * c4v.z; val[3] += rr1 * c4v.w;
      }
      if (OUTM == 0) {
        if (ACCUM) {
          float4 old = *(const float4*)&Cf[idx];
          val[0] += old.x; val[1] += old.y; val[2] += old.z; val[3] += old.w;
        }
        if (RELU) {
          val[0] = fmaxf(val[0], 0.f); val[1] = fmaxf(val[1], 0.f);
          val[2] = fmaxf(val[2], 0.f); val[3] = fmaxf(val[3], 0.f);
        }
        float4 o4; o4.x = val[0]; o4.y = val[1]; o4.z = val[2]; o4.w = val[3];
        *(float4*)&Cf[idx] = o4;
      } else {
        ushort4 o;
        o.x = f2bf(val[0]); o.y = f2bf(val[1]);
        o.z = f2bf(val[2]); o.w = f2bf(val[3]);
        *(ushort4*)&Cb[idx] = o;
      }
    }
  }
}

// ---------------------------------------------------------------------------
// 8-wave split-K MFMA GEMM (ring-8, 128 KB, 1 block/CU): for <=256-block,
// K-heavy dispatches where deep prefetch (3 pairs in flight) wins.
// ---------------------------------------------------------------------------
template<int OUTM, bool ACCUM, bool RELU, bool RANK1, bool BIAS>
__global__ __launch_bounds__(512) void mgemm8_k(
    const u16* __restrict__ A, int lda, long long sA,
    const u16* __restrict__ B, int ldb, long long sB,
    const float* __restrict__ bias, int sBias,
    float* __restrict__ Cf, u16* __restrict__ Cb, int ldc, long long sC,
    int K,
    const float* __restrict__ r1row, int sR1r,
    const float* __restrict__ r1col, int sR1c)
{
  __shared__ u16 smem[8 * 8192];   // 8 slots x 16KB = 128 KB
  const int z = blockIdx.z;
  const u16* Ag = A + (long long)z * sA;
  const u16* Bg = B + (long long)z * sB;

  int bx, by;
  xcd_map(gridDim.x, gridDim.y, bx, by);

  const int row0 = by << 7;
  const int col0 = bx << 7;
  const int tid  = threadIdx.x;
  const int lane = tid & 63;
  const int w    = tid >> 6;
  const int g    = w >> 2;
  const int s4   = w & 3;
  const int wr   = (s4 >> 1) << 6;
  const int wc   = (s4 & 1) << 6;

  const int srow = tid >> 2;
  const int ssw  = (tid & 3) ^ ((srow >> 1) & 3);
  const long long aoff = (long long)(row0 + srow) * lda + ssw * 8;
  const long long boff = (long long)(col0 + srow) * ldb + ssw * 8;

  const int frow = lane & 15;
  const int fsw  = (lane >> 4) ^ ((frow >> 1) & 3);
  const int fAoff = ((wr + frow) << 5) + (fsw << 3);
  const int fBoff = ((wc + frow) << 5) + (fsw << 3);

#define STAGE8(tt) do {                                                        \
    u16* _sb = smem + (((tt) & 7) << 13);                                      \
    const long long _k = (long long)(tt) << 5;                                 \
    GLDS16(Ag + aoff + _k, _sb + (tid << 3));                                  \
    GLDS16(Bg + boff + _k, _sb + 4096 + (tid << 3));                           \
  } while (0)

  f32x4 acc[4][4];
  #pragma unroll
  for (int mi = 0; mi < 4; ++mi)
    #pragma unroll
    for (int ni = 0; ni < 4; ++ni) {
      acc[mi][ni][0] = 0.f; acc[mi][ni][1] = 0.f;
      acc[mi][ni][2] = 0.f; acc[mi][ni][3] = 0.f;
    }

  const int NT = K >> 5;
  const int NP = NT >> 1;
  STAGE8(0); STAGE8(1); STAGE8(2); STAGE8(3); STAGE8(4); STAGE8(5);
  asm volatile("s_waitcnt vmcnt(8)" ::: "memory");
  __builtin_amdgcn_s_barrier();
  asm volatile("" ::: "memory");

  for (int i = 0; i < NP; ++i) {
    if (i + 3 < NP) { STAGE8(2 * i + 6); STAGE8(2 * i + 7); }

    const u16* base = smem + (((2 * i + g) & 7) << 13);
    bf16x8 af[4], bfr[4];
    #pragma unroll
    for (int mi = 0; mi < 4; ++mi) af[mi]  = *(const bf16x8*)(base + fAoff + mi * 512);
    #pragma unroll
    for (int ni = 0; ni < 4; ++ni) bfr[ni] = *(const bf16x8*)(base + 4096 + fBoff + ni * 512);
    __builtin_amdgcn_s_setprio(1);
    #pragma unroll
    for (int mi = 0; mi < 4; ++mi)
      #pragma unroll
      for (int ni = 0; ni < 4; ++ni)
        acc[mi][ni] = __builtin_amdgcn_mfma_f32_16x16x32_bf16(
            af[mi], bfr[ni], acc[mi][ni], 0, 0, 0);
    __builtin_amdgcn_s_setprio(0);

    if (i + 1 < NP) {
      if (i + 3 < NP)      asm volatile("s_waitcnt vmcnt(8)" ::: "memory");
      else if (i + 2 < NP) asm volatile("s_waitcnt vmcnt(4)" ::: "memory");
      else                 asm volatile("s_waitcnt vmcnt(0)" ::: "memory");
      __builtin_amdgcn_s_barrier();
      asm volatile("" ::: "memory");
    }
  }
#undef STAGE8

  epilogue128<OUTM, ACCUM, RELU, RANK1, BIAS>(
      smem, acc, z, row0, col0, tid, lane, w, wr, wc,
      bias, sBias, Cf, Cb, ldc, sC, r1row, sR1r, r1col, sR1c);
}

// ---------------------------------------------------------------------------
// Ring-4 variant (~68 KB LDS -> 2 blocks/CU): for > 256-block dispatches
// where co-residency beats prefetch depth. acc[4][4]=64 VGPR fits the
// (512,4) 128-VGPR cap.
// ---------------------------------------------------------------------------
template<int OUTM, bool ACCUM, bool RELU, bool RANK1, bool BIAS>
__global__ __launch_bounds__(512, 4) void mgemm8d_k(
    const u16* __restrict__ A, int lda, long long sA,
    const u16* __restrict__ B, int ldb, long long sB,
    const float* __restrict__ bias, int sBias,
    float* __restrict__ Cf, u16* __restrict__ Cb, int ldc, long long sC,
    int K,
    const float* __restrict__ r1row, int sR1r,
    const float* __restrict__ r1col, int sR1c)
{
  __shared__ u16 smem[33792];   // max(ring-4 64KB, epilogue tile 67.5KB)
  const int z = blockIdx.z;
  const u16* Ag = A + (long long)z * sA;
  const u16* Bg = B + (long long)z * sB;

  int bx, by;
  xcd_map(gridDim.x, gridDim.y, bx, by);

  const int row0 = by << 7;
  const int col0 = bx << 7;
  const int tid  = threadIdx.x;
  const int lane = tid & 63;
  const int w    = tid >> 6;
  const int g    = w >> 2;
  const int s4   = w & 3;
  const int wr   = (s4 >> 1) << 6;
  const int wc   = (s4 & 1) << 6;

  const int srow = tid >> 2;
  const int ssw  = (tid & 3) ^ ((srow >> 1) & 3);
  const long long aoff = (long long)(row0 + srow) * lda + ssw * 8;
  const long long boff = (long long)(col0 + srow) * ldb + ssw * 8;

  const int frow = lane & 15;
  const int fsw  = (lane >> 4) ^ ((frow >> 1) & 3);
  const int fAoff = ((wr + frow) << 5) + (fsw << 3);
  const int fBoff = ((wc + frow) << 5) + (fsw << 3);

#define STAGE4(tt) do {                                                        \
    u16* _sb = smem + (((tt) & 3) << 13);                                      \
    const long long _k = (long long)(tt) << 5;                                 \
    GLDS16(Ag + aoff + _k, _sb + (tid << 3));                                  \
    GLDS16(Bg + boff + _k, _sb + 4096 + (tid << 3));                           \
  } while (0)

  f32x4 acc[4][4];
  #pragma unroll
  for (int mi = 0; mi < 4; ++mi)
    #pragma unroll
    for (int ni = 0; ni < 4; ++ni) {
      acc[mi][ni][0] = 0.f; acc[mi][ni][1] = 0.f;
      acc[mi][ni][2] = 0.f; acc[mi][ni][3] = 0.f;
    }

  const int NT = K >> 5;
  const int NP = NT >> 1;   // >= 2 for all our shapes
  STAGE4(0); STAGE4(1); STAGE4(2); STAGE4(3);   // pairs 0,1 (8 loads)

  for (int p = 0; p < NP; ++p) {
    if (p + 1 < NP) asm volatile("s_waitcnt vmcnt(4)" ::: "memory");
    else            asm volatile("s_waitcnt vmcnt(0)" ::: "memory");
    __builtin_amdgcn_s_barrier();
    asm volatile("" ::: "memory");

    const u16* base = smem + (((2 * p + g) & 3) << 13);
    bf16x8 af[4], bfr[4];
    #pragma unroll
    for (int mi = 0; mi < 4; ++mi) af[mi]  = *(const bf16x8*)(base + fAoff + mi * 512);
    #pragma unroll
    for (int ni = 0; ni < 4; ++ni) bfr[ni] = *(const bf16x8*)(base + 4096 + fBoff + ni * 512);
    asm volatile("s_waitcnt lgkmcnt(0)" ::: "memory");
    __builtin_amdgcn_s_barrier();
    asm volatile("" ::: "memory");

    if (p + 2 < NP) { STAGE4(2 * p + 4); STAGE4(2 * p + 5); }

    __builtin_amdgcn_s_setprio(1);
    #pragma unroll
    for (int mi = 0; mi < 4; ++mi)
      #pragma unroll
      for (int ni = 0; ni < 4; ++ni)
        acc[mi][ni] = __builtin_amdgcn_mfma_f32_16x16x32_bf16(
            af[mi], bfr[ni], acc[mi][ni], 0, 0, 0);
    __builtin_amdgcn_s_setprio(0);
  }
#undef STAGE4

  epilogue128<OUTM, ACCUM, RELU, RANK1, BIAS>(
      smem, acc, z, row0, col0, tid, lane, w, wr, wc,
      bias, sBias, Cf, Cb, ldc, sC, r1row, sR1r, r1col, sR1c);
}

// ---------------------------------------------------------------------------
// 256x256 MFMA GEMM, 8 waves each owning 128x64. BK=32, ring-4 x 32KB LDS
// (128 KB), 3 tiles in flight, counted vmcnt, direct epilogue.
// launch_bounds(512,2): acc[8][4]=128 VGPR needs the 256-VGPR cap; this
// kernel is structurally 1 block/CU (do NOT raise the occupancy floor).
// ---------------------------------------------------------------------------
template<bool BIAS>
__global__ __launch_bounds__(512, 2) void mgemm256_k(
    const u16* __restrict__ A, int lda, long long sA,
    const u16* __restrict__ B, int ldb, long long sB,
    const float* __restrict__ bias, int sBias,
    u16* __restrict__ Cb, int ldc, long long sC,
    int K)
{
  __shared__ u16 smem[4 * 16384];
  const int z = blockIdx.z;
  const u16* Ag = A + (long long)z * sA;
  const u16* Bg = B + (long long)z * sB;

  int bx, by;
  xcd_map(gridDim.x, gridDim.y, bx, by);

  const int row0r = by << 8;
  const int col0 = bx << 8;
  const int tid  = threadIdx.x;
  const int lane = tid & 63;
  const int w    = tid >> 6;
  const int wrow = w >> 2;
  const int wcol = w & 3;

  const int srow = tid >> 2;
  const int ssw  = (tid & 3) ^ ((srow >> 1) & 3);
  const long long aoff0 = (long long)(row0r + srow)       * lda + ssw * 8;
  const long long aoff1 = (long long)(row0r + srow + 128) * lda + ssw * 8;
  const long long boff0 = (long long)(col0 + srow)        * ldb + ssw * 8;
  const long long boff1 = (long long)(col0 + srow + 128)  * ldb + ssw * 8;

  const int frow = lane & 15;
  const int fsw  = (lane >> 4) ^ ((frow >> 1) & 3);
  const int fAoff = ((wrow * 128 + frow) << 5) + (fsw << 3);
  const int fBoff = ((wcol * 64  + frow) << 5) + (fsw << 3);

#define STG256(tt) do {                                                        \
    u16* _sb = smem + (((tt) & 3) << 14);                                      \
    const long long _k = (long long)(tt) << 5;                                 \
    GLDS16(Ag + aoff0 + _k, _sb + (tid << 3));                                 \
    GLDS16(Ag + aoff1 + _k, _sb + 4096 + (tid << 3));                          \
    GLDS16(Bg + boff0 + _k, _sb + 8192 + (tid << 3));                          \
    GLDS16(Bg + boff1 + _k, _sb + 12288 + (tid << 3));                         \
  } while (0)

  f32x4 acc[8][4];
  #pragma unroll
  for (int mi = 0; mi < 8; ++mi)
    #pragma unroll
    for (int ni = 0; ni < 4; ++ni) {
      acc[mi][ni][0] = 0.f; acc[mi][ni][1] = 0.f;
      acc[mi][ni][2] = 0.f; acc[mi][ni][3] = 0.f;
    }

  const int NT = K >> 5;
  STG256(0); STG256(1); STG256(2);
  asm volatile("s_waitcnt vmcnt(8)" ::: "memory");
  __builtin_amdgcn_s_barrier();
  asm volatile("" ::: "memory");

  for (int t = 0; t < NT; ++t) {
    if (t + 3 < NT) STG256(t + 3);

    const u16* base = smem + ((t & 3) << 14);
    bf16x8 af[8], bfr[4];
    #pragma unroll
    for (int mi = 0; mi < 8; ++mi) af[mi]  = *(const bf16x8*)(base + fAoff + mi * 512);
    #pragma unroll
    for (int ni = 0; ni < 4; ++ni) bfr[ni] = *(const bf16x8*)(base + 8192 + fBoff + ni * 512);
    __builtin_amdgcn_s_setprio(1);
    #pragma unroll
    for (int mi = 0; mi < 8; ++mi)
      #pragma unroll
      for (int ni = 0; ni < 4; ++ni)
        acc[mi][ni] = __builtin_amdgcn_mfma_f32_16x16x32_bf16(
            af[mi], bfr[ni], acc[mi][ni], 0, 0, 0);
    __builtin_amdgcn_s_setprio(0);

    if (t + 1 < NT) {
      if (t + 3 < NT)      asm volatile("s_waitcnt vmcnt(8)" ::: "memory");
      else if (t + 2 < NT) asm volatile("s_waitcnt vmcnt(4)" ::: "memory");
      else                 asm volatile("s_waitcnt vmcnt(0)" ::: "memory");
      __builtin_amdgcn_s_barrier();
      asm volatile("" ::: "memory");
    }
  }
#undef STG256

  const int cn  = lane & 15;
  const int rm4 = (lane >> 4) << 2;
  #pragma unroll
  for (int mi = 0; mi < 8; ++mi) {
    #pragma unroll
    for (int ni = 0; ni < 4; ++ni) {
      const int rb = row0r + wrow * 128 + mi * 16 + rm4;
      const int cc = col0 + wcol * 64 + ni * 16 + cn;
      float badd = BIAS ? bias[(long long)z * sBias + cc] : 0.f;
      f32x4 v = acc[mi][ni];
      #pragma unroll
      for (int j = 0; j < 4; ++j)
        Cb[(long long)z * sC + (long long)(rb + j) * ldc + cc] = f2bf(v[j] + badd);
    }
  }
}

// out = relu(p0+p1+p2+p3), partials stride 1M floats, n4 = n/4 float4s
__global__ __launch_bounds__(256) void reduce4relu_k(
    const float* __restrict__ p, float* __restrict__ out, int n4)
{
  int i = blockIdx.x * 256 + threadIdx.x;
  if (i < n4) {
    float4 a = ((const float4*)p)[i];
    float4 b = ((const float4*)(p + (1ll << 20)))[i];
    float4 c = ((const float4*)(p + (2ll << 20)))[i];
    float4 d = ((const float4*)(p + (3ll << 20)))[i];
    float4 o;
    o.x = fmaxf(a.x + b.x + c.x + d.x, 0.f);
    o.y = fmaxf(a.y + b.y + c.y + d.y, 0.f);
    o.z = fmaxf(a.z + b.z + c.z + d.z, 0.f);
    o.w = fmaxf(a.w + b.w + c.w + d.w, 0.f);
    ((float4*)out)[i] = o;
  }
}

// ---------------------------------------------------------------------------
__global__ __launch_bounds__(256) void xpose_k(
    const float* __restrict__ in, float* __restrict__ out, int R, int Cc)
{
  __shared__ float tile[32][33];
  int c0 = blockIdx.x * 32, r0 = blockIdx.y * 32;
  int tx = threadIdx.x & 31, ty = threadIdx.x >> 5;
  #pragma unroll
  for (int rr = ty; rr < 32; rr += 8)
    tile[rr][tx] = in[(long long)(r0 + rr) * Cc + c0 + tx];
  __syncthreads();
  #pragma unroll
  for (int cc = ty; cc < 32; cc += 8)
    out[(long long)(c0 + cc) * R + r0 + tx] = tile[tx][cc];
}

__global__ __launch_bounds__(256) void tcvt_k(
    const float* __restrict__ in, u16* __restrict__ out, int R, int Cc)
{
  __shared__ float tile[32][33];
  int c0 = blockIdx.x * 32, r0 = blockIdx.y * 32;
  int tx = threadIdx.x & 31, ty = threadIdx.x >> 5;
  #pragma unroll
  for (int rr = ty; rr < 32; rr += 8)
    tile[rr][tx] = in[(long long)(r0 + rr) * Cc + c0 + tx];
  __syncthreads();
  #pragma unroll
  for (int cc = ty; cc < 32; cc += 8)
    out[(long long)(c0 + cc) * R + r0 + tx] = f2bf(tile[tx][cc]);
}

__global__ __launch_bounds__(256) void tcvt_aff_k(
    const float* __restrict__ in, u16* __restrict__ out, int R, int Cc,
    const float* __restrict__ A2, const float* __restrict__ C2)
{
  __shared__ float tile[32][33];
  int c0 = blockIdx.x * 32, r0 = blockIdx.y * 32;
  int tx = threadIdx.x & 31, ty = threadIdx.x >> 5;
  #pragma unroll
  for (int rr = ty; rr < 32; rr += 8)
    tile[rr][tx] = in[(long long)(r0 + rr) * Cc + c0 + tx];
  __syncthreads();
  #pragma unroll
  for (int cc = ty; cc < 32; cc += 8) {
    float v = A2[c0 + cc] * tile[tx][cc] + C2[c0 + cc];
    out[(long long)(c0 + cc) * R + r0 + tx] = f2bf(v);
  }
}

__global__ __launch_bounds__(256) void cvt_k(
    const float* __restrict__ in, u16* __restrict__ out)
{
  int i = blockIdx.x * 256 + threadIdx.x;
  float4 v = ((const float4*)in)[i];
  ushort4 o;
  o.x = f2bf(v.x); o.y = f2bf(v.y); o.z = f2bf(v.z); o.w = f2bf(v.w);
  ((ushort4*)out)[i] = o;
}

__global__ __launch_bounds__(256) void pack2_k(
    const float* __restrict__ a, const float* __restrict__ b,
    float* __restrict__ out, int n)
{
  int i = blockIdx.x * 256 + threadIdx.x;
  if (i < n) { out[i] = a[i]; out[n + i] = b[i]; }
}

// ---------------------------------------------------------------------------
__global__ __launch_bounds__(64) void qe_k(const u16* __restrict__ Q1,
                                           const float* __restrict__ We1,
                                           float* __restrict__ qe)
{
  int h = blockIdx.x >> 10;
  int i = blockIdx.x & 1023;
  const u16* q = Q1 + (long long)i * 4096 + h * 512;
  const float* wv = We1 + h * 512;
  int l = threadIdx.x;
  float s = 0.f;
  #pragma unroll
  for (int r = 0; r < 8; ++r) s += bf2f(q[l + r * 64]) * wv[l + r * 64];
  #pragma unroll
  for (int off = 32; off > 0; off >>= 1) s += __shfl_down(s, off);
  if (l == 0) qe[blockIdx.x] = s;
}

// ---------------------------------------------------------------------------
__global__ __launch_bounds__(256) void softmax1b_k(
    u16* __restrict__ S, const float* __restrict__ xT,
    const float* __restrict__ qe, float* __restrict__ ae)
{
  int i = blockIdx.x, h = blockIdx.y;
  u16* s = S + ((long long)h * 1024 + i) * 1024;
  const float* e = xT + (long long)i * 1024;
  float q = qe[h * 1024 + i];
  int tid = threadIdx.x;
  __shared__ float red[256];

  ushort4 sv = ((const ushort4*)s)[tid];
  float4  evv = ((const float4*)e)[tid];
  float ev[4] = {evv.x, evv.y, evv.z, evv.w};
  float t[4];
  t[0] = (bf2f(sv.x) + q * ev[0]) * kInvSqrtD;
  t[1] = (bf2f(sv.y) + q * ev[1]) * kInvSqrtD;
  t[2] = (bf2f(sv.z) + q * ev[2]) * kInvSqrtD;
  t[3] = (bf2f(sv.w) + q * ev[3]) * kInvSqrtD;
  float m = fmaxf(fmaxf(t[0], t[1]), fmaxf(t[2], t[3]));
  m = blockReduceMax(m, red);
  float sum = 0.f;
  #pragma unroll
  for (int r = 0; r < 4; ++r) { t[r] = __expf(t[r] - m); sum += t[r]; }
  sum = blockReduceSum(sum, red);
  float invl = 1.f / sum;
  float aes = 0.f;
  ushort4 o;
  o.x = f2bf(t[0] * invl); o.y = f2bf(t[1] * invl);
  o.z = f2bf(t[2] * invl); o.w = f2bf(t[3] * invl);
  #pragma unroll
  for (int r = 0; r < 4; ++r) aes += (t[r] * invl) * ev[r];
  ((ushort4*)s)[tid] = o;
  aes = blockReduceSum(aes, red);
  if (tid == 0) ae[h * 1024 + i] = aes;
}

__global__ __launch_bounds__(256) void softmax2b_k(u16* __restrict__ S)
{
  u16* s = S + ((long long)blockIdx.y * 2048 + blockIdx.x) * 4096;
  int tid = threadIdx.x;
  __shared__ float red[256];
  float t[16];
  float m = -1e30f;
  #pragma unroll
  for (int r = 0; r < 4; ++r) {
    ushort4 sv = ((const ushort4*)s)[tid + r * 256];
    t[r*4+0] = bf2f(sv.x) * kInvSqrtD; t[r*4+1] = bf2f(sv.y) * kInvSqrtD;
    t[r*4+2] = bf2f(sv.z) * kInvSqrtD; t[r*4+3] = bf2f(sv.w) * kInvSqrtD;
    m = fmaxf(m, fmaxf(fmaxf(t[r*4], t[r*4+1]), fmaxf(t[r*4+2], t[r*4+3])));
  }
  m = blockReduceMax(m, red);
  float sum = 0.f;
  #pragma unroll
  for (int r = 0; r < 16; ++r) { t[r] = __expf(t[r] - m); sum += t[r]; }
  sum = blockReduceSum(sum, red);
  float invl = 1.f / sum;
  #pragma unroll
  for (int r = 0; r < 4; ++r) {
    ushort4 o;
    o.x = f2bf(t[r*4+0] * invl); o.y = f2bf(t[r*4+1] * invl);
    o.z = f2bf(t[r*4+2] * invl); o.w = f2bf(t[r*4+3] * invl);
    ((ushort4*)s)[tid + r * 256] = o;
  }
}

// ---------------------------------------------------------------------------
__global__ __launch_bounds__(256) void colpart4_k(const float* __restrict__ h,
    int N, int F, int nchunk, float* __restrict__ ps, float* __restrict__ pss)
{
  const int f4 = blockIdx.x * 256 + threadIdx.x;
  const int chunk = blockIdx.y;
  const int rows = N / nchunk;
  const int rbeg = chunk * rows;
  const int F4 = F >> 2;
  const float4* h4 = (const float4*)h;
  float4 s = {0.f, 0.f, 0.f, 0.f}, ss = {0.f, 0.f, 0.f, 0.f};
  #pragma unroll 8
  for (int i = 0; i < rows; ++i) {
    float4 v = h4[(long long)(rbeg + i) * F4 + f4];
    s.x += v.x; s.y += v.y; s.z += v.z; s.w += v.w;
    ss.x += v.x * v.x; ss.y += v.y * v.y;
    ss.z += v.z * v.z; ss.w += v.w * v.w;
  }
  ((float4*)(ps  + (long long)chunk * F))[f4] = s;
  ((float4*)(pss + (long long)chunk * F))[f4] = ss;
}

// Parallel finisher: one block per float4-column; 256 threads split chunks.
template<int MODE>
__global__ __launch_bounds__(256) void colfin2_k(
    const float* __restrict__ ps, const float* __restrict__ pss,
    int F, int nchunk, float Nf,
    const float* __restrict__ ms, const float* __restrict__ g,
    const float* __restrict__ beta,
    float* __restrict__ outA, float* __restrict__ outC)
{
  __shared__ float4 red4[256];
  const int f4 = blockIdx.x;
  const int tid = threadIdx.x;
  float4 s = {0.f, 0.f, 0.f, 0.f}, ss = {0.f, 0.f, 0.f, 0.f};
  for (int c = tid; c < nchunk; c += 256) {
    float4 v = ((const float4*)(ps  + (long long)c * F))[f4];
    float4 u = ((const float4*)(pss + (long long)c * F))[f4];
    s.x += v.x; s.y += v.y; s.z += v.z; s.w += v.w;
    ss.x += u.x; ss.y += u.y; ss.z += u.z; ss.w += u.w;
  }
  s  = blockReduceF4(s, red4);
  ss = blockReduceF4(ss, red4);
  if (tid < 4) {
    const int f = f4 * 4 + tid;
    float sv  = (tid == 0) ? s.x  : (tid == 1) ? s.y  : (tid == 2) ? s.z  : s.w;
    float ssv = (tid == 0) ? ss.x : (tid == 1) ? ss.y : (tid == 2) ? ss.z : ss.w;
    float Ninv = 1.f / Nf;
    float mean = sv * Ninv;
    float mm = ms[f] * mean;
    float var = ssv * Ninv - 2.f * mm * mean + mm * mm;
    float is = rsqrtf(var + 1e-5f);
    float a = g[f] * is;
    float c = beta[f] - a * mm;
    if (MODE == 1) {
      float sy2 = a * a * ssv + 2.f * a * c * sv + Nf * c * c;
      float cinv = rsqrtf(sy2);
      a *= cinv; c *= cinv;
    }
    outA[f] = a;
    outC[f] = c;
  }
}

__global__ __launch_bounds__(256) void rowl2gn_k(
    float* __restrict__ h, u16* __restrict__ hb,
    const float* __restrict__ a, const float* __restrict__ c)
{
  int i = blockIdx.x;
  float* row = h + (long long)i * 4096;
  u16* rb = hb + (long long)i * 4096;
  int tid = threadIdx.x;
  __shared__ float red[256];
  float t[16];
  float ss = 0.f;
  #pragma unroll
  for (int r = 0; r < 4; ++r) {
    int j = tid + r * 256;
    float4 hv = ((const float4*)row)[j];
    float4 av = ((const float4*)a)[j];
    float4 cv = ((const float4*)c)[j];
    t[r*4+0] = av.x * hv.x + cv.x;
    t[r*4+1] = av.y * hv.y + cv.y;
    t[r*4+2] = av.z * hv.z + cv.z;
    t[r*4+3] = av.w * hv.w + cv.w;
    ss += t[r*4+0]*t[r*4+0] + t[r*4+1]*t[r*4+1]
        + t[r*4+2]*t[r*4+2] + t[r*4+3]*t[r*4+3];
  }
  ss = blockReduceSum(ss, red);
  float inv = rsqrtf(ss);
  #pragma unroll
  for (int r = 0; r < 4; ++r) {
    int j = tid + r * 256;
    float4 o4;
    o4.x = t[r*4+0] * inv; o4.y = t[r*4+1] * inv;
    o4.z = t[r*4+2] * inv; o4.w = t[r*4+3] * inv;
    ((float4*)row)[j] = o4;
    ushort4 ob;
    ob.x = f2bf(o4.x); ob.y = f2bf(o4.y); ob.z = f2bf(o4.z); ob.w = f2bf(o4.w);
    ((ushort4*)rb)[j] = ob;
  }
}

// ---------------------------------------------------------------------------
extern "C" void kernel_launch(void* const* d_in, const int* in_sizes, int n_in,
                              void* d_out, int out_size, void* d_ws, size_t ws_size,
                              hipStream_t stream)
{
  (void)in_sizes; (void)n_in; (void)out_size; (void)ws_size;

  const float* x      = (const float*)d_in[0];
  const float* Wq1    = (const float*)d_in[1];
  const float* bq1    = (const float*)d_in[2];
  const float* Wk1    = (const float*)d_in[3];
  const float* bk1    = (const float*)d_in[4];
  const float* Wv1    = (const float*)d_in[5];
  const float* bv1    = (const float*)d_in[6];
  const float* We1    = (const float*)d_in[7];
  const float* Wskip1 = (const float*)d_in[8];
  const float* bskip1 = (const float*)d_in[9];
  const float* g1     = (const float*)d_in[10];
  const float* bb1    = (const float*)d_in[11];
  const float* ms1    = (const float*)d_in[12];
  const float* Wq2    = (const float*)d_in[13];
  const float* bq2    = (const float*)d_in[14];
  const float* Wk2    = (const float*)d_in[15];
  const float* bk2    = (const float*)d_in[16];
  const float* Wv2    = (const float*)d_in[17];
  const float* bv2    = (const float*)d_in[18];
  const float* Wskip2 = (const float*)d_in[19];
  const float* bskip2 = (const float*)d_in[20];
  const float* g2     = (const float*)d_in[21];
  const float* bb2    = (const float*)d_in[22];
  const float* ms2    = (const float*)d_in[23];

  // ---- workspace arena (~209 MB) ----
  char* base = (char*)d_ws;
  float* lrx_f   = (float*)(base);                 // 16MB [1024][4096]
  u16*   lrx_bf  = (u16*)  (base + (16ll << 20));  // 8MB
  u16*   lrxT_bf = (u16*)  (base + (24ll << 20));  // 8MB [4096][1024]
  u16*   hrx_bf  = (u16*)  (base + (32ll << 20));  // 16MB [2048][4096]
  char* sh = base + (48ll << 20);                  // shared region, 160MB
  // stage A
  u16* x_bf  = (u16*)(sh);                         // 2MB
  float* xT  = (float*)(sh + (2ll << 20));         // 4MB
  u16* Wq1T  = (u16*)(sh + (6ll << 20));           // 8MB each (Wk1T follows Wq1T)
  u16* Wk1T  = (u16*)(sh + (14ll << 20));
  u16* Wv1T  = (u16*)(sh + (22ll << 20));
  u16* Ws1T  = (u16*)(sh + (30ll << 20));
  u16* Q1bf  = (u16*)(sh + (38ll << 20));          // 8MB [1024][4096] (K1bf follows)
  u16* K1bf  = (u16*)(sh + (46ll << 20));          // 8MB
  u16* V1T   = (u16*)(sh + (54ll << 20));          // 8MB [4096][1024]
  u16* S1bf  = (u16*)(sh + (62ll << 20));          // 16MB [8][1024][1024]
  // GN1 partials in dead S1bf space (consumed before V2T/H2 writes)
  float* ps1  = (float*)(sh + (66ll << 20));       // 2MB [128][4096]
  float* pss1 = (float*)(sh + (68ll << 20));       // 2MB
  // stage B (aliases stage A)
  u16* Wq2T  = (u16*)(sh);                         // 4MB each (Wk2T follows)
  u16* Wk2T  = (u16*)(sh + (4ll << 20));
  u16* Wv2T  = (u16*)(sh + (8ll << 20));
  u16* Ws2T  = (u16*)(sh + (12ll << 20));
  u16* Q2bf  = (u16*)(sh + (16ll << 20));          // 16MB [4096][2048] (K2bf follows)
  u16* K2bf  = (u16*)(sh + (32ll << 20));          // 16MB
  u16* V2T   = (u16*)(sh + (48ll << 20));          // 16MB [2048][4096]
  float* H2  = (float*)(sh + (64ll << 20));        // 32MB [4096][2048]
  u16* S2bf  = (u16*)(sh + (96ll << 20));          // 64MB [4][2048][4096]
  float* gpart = (float*)(sh + (96ll << 20));      // 16MB lr-gram partials (S2 dead)
  // GN2 partials in dead S2bf space (consumed before gpart written)
  float* ps2  = (float*)(sh + (120ll << 20));      // 2MB [256][2048]
  float* pss2 = (float*)(sh + (122ll << 20));      // 2MB
  // small tail
  float* tail    = (float*)(base + (208ll << 20));
  float* qe      = tail;             // 8192
  float* ae      = qe + 8192;        // 8192
  float* af1     = ae + 8192;        // 4096
  float* cf1     = af1 + 4096;       // 4096
  float* A2v     = cf1 + 4096;       // 2048
  float* C2v     = A2v + 2048;       // 2048
  float* biasQK1 = C2v + 2048;       // 8192
  float* biasQK2 = biasQK1 + 8192;   // 4096

  float* out0 = (float*)d_out;                   // hr [2048][2048]
  float* out1 = out0 + (long long)2048 * 2048;   // lr gram [1024][1024]

  // ---- stage 0: conversions ----
  xpose_k<<<dim3(32, 32), 256, 0, stream>>>(x, xT, 1024, 1024);
  cvt_k<<<dim3(1024), 256, 0, stream>>>(x, x_bf);
  tcvt_k<<<dim3(128, 32), 256, 0, stream>>>(Wq1,    Wq1T, 1024, 4096);
  tcvt_k<<<dim3(128, 32), 256, 0, stream>>>(Wk1,    Wk1T, 1024, 4096);
  tcvt_k<<<dim3(128, 32), 256, 0, stream>>>(Wv1,    Wv1T, 1024, 4096);
  tcvt_k<<<dim3(128, 32), 256, 0, stream>>>(Wskip1, Ws1T, 1024, 4096);
  pack2_k<<<dim3(16), 256, 0, stream>>>(bq1, bk1, biasQK1, 4096);
  pack2_k<<<dim3(8),  256, 0, stream>>>(bq2, bk2, biasQK2, 2048);

  // ---- conv1 Q+K batched (z=2, 512 blocks -> ring-4), V + skip (ring-8) ----
  mgemm8d_k<1,false,false,false,true><<<dim3(32, 8, 2), 512, 0, stream>>>(
      x_bf, 1024, 0, Wq1T, 1024, (long long)4096 * 1024, biasQK1, 4096,
      nullptr, Q1bf, 4096, (long long)1024 * 4096, 1024, nullptr, 0, nullptr, 0);
  mgemm8_k<2,false,false,false,true><<<dim3(32, 8, 1), 512, 0, stream>>>(
      x_bf, 1024, 0, Wv1T, 1024, 0, bv1, 0, nullptr, V1T, 1024, 0, 1024,
      nullptr, 0, nullptr, 0);
  mgemm8_k<0,false,false,false,true><<<dim3(32, 8, 1), 512, 0, stream>>>(
      x_bf, 1024, 0, Ws1T, 1024, 0, bskip1, 0, lrx_f, nullptr, 4096, 0, 1024,
      nullptr, 0, nullptr, 0);

  qe_k<<<dim3(8192), 64, 0, stream>>>(Q1bf, We1, qe);

  // ---- scores1[h] (512 blocks -> ring-4) ----
  mgemm8d_k<1,false,false,false,false><<<dim3(8, 8, 8), 512, 0, stream>>>(
      Q1bf, 4096, 512, K1bf, 4096, 512, nullptr, 0, nullptr, S1bf, 1024, 1048576,
      512, nullptr, 0, nullptr, 0);

  softmax1b_k<<<dim3(1024, 8), 256, 0, stream>>>(S1bf, xT, qe, ae);

  // ---- PV1 (256 blocks -> ring-8) ----
  mgemm8_k<0,true,false,true,false><<<dim3(4, 8, 8), 512, 0, stream>>>(
      S1bf, 1024, 1048576, V1T, 1024, 512 * 1024, nullptr, 0, lrx_f, nullptr,
      4096, 512, 1024, ae, 1024, We1, 512);

  // ---- GraphNorm1 (affine) + row L2, fused ----
  colpart4_k<<<dim3(4, 128), 256, 0, stream>>>(lrx_f, 1024, 4096, 128, ps1, pss1);
  colfin2_k<0><<<dim3(1024), 256, 0, stream>>>(ps1, pss1, 4096, 128, 1024.f,
                                               ms1, g1, bb1, af1, cf1);
  rowl2gn_k<<<dim3(1024), 256, 0, stream>>>(lrx_f, lrx_bf, af1, cf1);
  tcvt_k<<<dim3(128, 32), 256, 0, stream>>>(lrx_f, lrxT_bf, 1024, 4096);

  // ---- conv2 weights ----
  tcvt_k<<<dim3(64, 32), 256, 0, stream>>>(Wq2,    Wq2T, 1024, 2048);
  tcvt_k<<<dim3(64, 32), 256, 0, stream>>>(Wk2,    Wk2T, 1024, 2048);
  tcvt_k<<<dim3(64, 32), 256, 0, stream>>>(Wv2,    Wv2T, 1024, 2048);
  tcvt_k<<<dim3(64, 32), 256, 0, stream>>>(Wskip2, Ws2T, 1024, 2048);

  // ---- conv2 Q+K on 256^2 kernel; V + skip (512 blocks -> ring-4) ----
  mgemm256_k<true><<<dim3(8, 16, 2), 512, 0, stream>>>(
      lrxT_bf, 1024, 0, Wq2T, 1024, (long long)2048 * 1024, biasQK2, 2048,
      Q2bf, 2048, (long long)4096 * 2048, 1024);
  mgemm8d_k<2,false,false,false,true><<<dim3(16, 32, 1), 512, 0, stream>>>(
      lrxT_bf, 1024, 0, Wv2T, 1024, 0, bv2, 0, nullptr, V2T, 4096, 0, 1024,
      nullptr, 0, nullptr, 0);
  mgemm8d_k<0,false,false,false,true><<<dim3(16, 32, 1), 512, 0, stream>>>(
      lrxT_bf, 1024, 0, Ws2T, 1024, 0, bskip2, 0, H2, nullptr, 2048, 0, 1024,
      nullptr, 0, nullptr, 0);

  // ---- conv2 attention in 2 chunks of 2048 rows ----
  for (int c = 0; c < 2; ++c) {
    const u16* Qc = Q2bf + (long long)c * 2048 * 2048;
    float* Hc = H2 + (long long)c * 2048 * 2048;
    mgemm256_k<false><<<dim3(16, 8, 4), 512, 0, stream>>>(
        Qc, 2048, 512, K2bf, 2048, 512, nullptr, 0,
        S2bf, 4096, (long long)2048 * 4096, 512);
    softmax2b_k<<<dim3(2048, 4), 256, 0, stream>>>(S2bf);
    mgemm8_k<0,true,false,false,false><<<dim3(4, 16, 4), 512, 0, stream>>>(
        S2bf, 4096, (long long)2048 * 4096, V2T, 4096, (long long)512 * 4096,
        nullptr, 0, Hc, nullptr, 2048, 512, 4096, nullptr, 0, nullptr, 0);
  }

  // ---- GraphNorm2 + column L2 fused into one affine transpose-convert ----
  colpart4_k<<<dim3(2, 256), 256, 0, stream>>>(H2, 4096, 2048, 256, ps2, pss2);
  colfin2_k<1><<<dim3(512), 256, 0, stream>>>(ps2, pss2, 2048, 256, 4096.f,
                                              ms2, g2, bb2, A2v, C2v);
  tcvt_aff_k<<<dim3(64, 128), 256, 0, stream>>>(H2, hrx_bf, 4096, 2048, A2v, C2v);

  // ---- outputs: relu Grams ----
  mgemm8_k<0,false,true,false,false><<<dim3(16, 16, 1), 512, 0, stream>>>(
      hrx_bf, 4096, 0, hrx_bf, 4096, 0, nullptr, 0, out0, nullptr, 2048, 0, 4096,
      nullptr, 0, nullptr, 0);
  // lr-gram: grid-split K 4-way (z) into partials, then reduce+relu
  mgemm8_k<0,false,false,false,false><<<dim3(8, 8, 4), 512, 0, stream>>>(
      lrx_bf, 4096, 1024, lrx_bf, 4096, 1024, nullptr, 0, gpart, nullptr, 1024,
      (long long)1 << 20, 1024, nullptr, 0, nullptr, 0);
  reduce4relu_k<<<dim3(1024), 256, 0, stream>>>(gpart, out1, 262144);
}

// Round 16
// 614.017 us; speedup vs baseline: 2.6513x; 1.0256x over previous
//
#include <hip/hip_runtime.h>
#include <hip/hip_bf16.h>

typedef unsigned short u16;
typedef __attribute__((ext_vector_type(8))) short bf16x8;
typedef __attribute__((ext_vector_type(4))) float f32x4;

__device__ __constant__ float kInvSqrtD = 0.04419417382415922f; // 1/sqrt(512)

__device__ __forceinline__ u16 f2bf(float f) {
  union { float f; unsigned u; } a; a.f = f;
  unsigned r = a.u + 0x7FFFu + ((a.u >> 16) & 1u);
  return (u16)(r >> 16);
}
__device__ __forceinline__ float bf2f(u16 u) {
  union { unsigned u; float f; } a; a.u = ((unsigned)u) << 16;
  return a.f;
}

// ---------------------------------------------------------------------------
// Block reductions (blockDim.x == 256)
// ---------------------------------------------------------------------------
__device__ __forceinline__ float blockReduceMax(float v, float* red) {
  int tid = threadIdx.x;
  red[tid] = v; __syncthreads();
  #pragma unroll
  for (int w = 128; w > 0; w >>= 1) {
    if (tid < w) red[tid] = fmaxf(red[tid], red[tid + w]);
    __syncthreads();
  }
  float r = red[0];
  __syncthreads();
  return r;
}
__device__ __forceinline__ float blockReduceSum(float v, float* red) {
  int tid = threadIdx.x;
  red[tid] = v; __syncthreads();
  #pragma unroll
  for (int w = 128; w > 0; w >>= 1) {
    if (tid < w) red[tid] = red[tid] + red[tid + w];
    __syncthreads();
  }
  float r = red[0];
  __syncthreads();
  return r;
}

__device__ __forceinline__ float4 blockReduceF4(float4 v, float4* red) {
  int tid = threadIdx.x;
  red[tid] = v; __syncthreads();
  #pragma unroll
  for (int w = 128; w > 0; w >>= 1) {
    if (tid < w) {
      float4 a = red[tid], b = red[tid + w];
      a.x += b.x; a.y += b.y; a.z += b.z; a.w += b.w;
      red[tid] = a;
    }
    __syncthreads();
  }
  float4 r = red[0];
  __syncthreads();
  return r;
}

#define GLDS16(gp, lp)                                                         \
  __builtin_amdgcn_global_load_lds(                                            \
      (const __attribute__((address_space(1))) void*)(gp),                     \
      (__attribute__((address_space(3))) void*)(lp), 16, 0, 0)

// 2-D rectangular XCD partition (bijective); fallback: 1-D chunks
__device__ __forceinline__ void xcd_map(int gx, int gy, int& bx, int& by) {
  const int nwg = gx * gy;
  const int orig = blockIdx.y * gx + blockIdx.x;
  if ((nwg & 7) == 0) {
    int bestfx = 0, bestcost = 1 << 30;
    #pragma unroll
    for (int fx = 1; fx <= 8; fx <<= 1) {
      int fy = 8 / fx;
      if ((gx % fx) == 0 && (gy % fy) == 0) {
        int cost = gx / fx + gy / fy;
        if (cost < bestcost) { bestcost = cost; bestfx = fx; }
      }
    }
    if (bestfx > 0) {
      const int fx = bestfx, fy = 8 / bestfx;
      const int rw = gx / fx, rh = gy / fy;
      const int xcd = orig & 7, lid = orig >> 3;
      bx = (xcd % fx) * rw + lid % rw;
      by = (xcd / fx) * rh + lid / rw;
      return;
    }
    const int q = nwg >> 3;
    const int xcd = orig & 7, lid = orig >> 3;
    const int wgid = xcd * q + lid;
    bx = wgid % gx; by = wgid / gx;
    return;
  }
  const int q = nwg >> 3, r = nwg & 7;
  const int xcd = orig & 7, lid = orig >> 3;
  const int wgid = (xcd < r ? xcd * (q + 1) : r * (q + 1) + (xcd - r) * q) + lid;
  bx = wgid % gx; by = wgid / gx;
}

// ---------------------------------------------------------------------------
// Shared epilogue for the 128x128 8-wave kernels: split-K merge via LDS,
// LDS tile staging, coalesced writeout. smem must hold >= 67584 bytes.
// ---------------------------------------------------------------------------
template<int OUTM, bool ACCUM, bool RELU, bool RANK1, bool BIAS>
__device__ __forceinline__ void epilogue128(
    u16* smem, f32x4 (&acc)[4][4],
    int z, int row0, int col0, int tid, int lane, int w, int wr, int wc,
    const float* bias, int sBias,
    float* Cf, u16* Cb, int ldc, long long sC,
    const float* r1row, int sR1r, const float* r1col, int sR1c)
{
  // cross-group merge: group 1 dumps acc to LDS, group 0 adds
  float* dump = (float*)smem;
  if (w >= 4) {
    float* reg = dump + ((w - 4) << 12);
    #pragma unroll
    for (int f = 0; f < 16; ++f) {
      int mi = f >> 2, ni = f & 3;
      *(f32x4*)(reg + (lane << 6) + (((f + lane) & 15) << 2)) = acc[mi][ni];
    }
  }
  asm volatile("s_waitcnt lgkmcnt(0)" ::: "memory");
  __builtin_amdgcn_s_barrier();
  asm volatile("" ::: "memory");
  if (w < 4) {
    float* reg = dump + (w << 12);
    #pragma unroll
    for (int f = 0; f < 16; ++f) {
      int mi = f >> 2, ni = f & 3;
      acc[mi][ni] += *(const f32x4*)(reg + (lane << 6) + (((f + lane) & 15) << 2));
    }
  }
  asm volatile("s_waitcnt lgkmcnt(0)" ::: "memory");
  __builtin_amdgcn_s_barrier();
  asm volatile("" ::: "memory");

  // tile store (group 0 only) into LDS [128][132] fp32
  float* tile = (float*)smem;
  if (w < 4) {
    const int cn  = lane & 15;
    const int rm4 = (lane >> 4) << 2;
    #pragma unroll
    for (int mi = 0; mi < 4; ++mi) {
      #pragma unroll
      for (int ni = 0; ni < 4; ++ni) {
        const int rl = wr + mi * 16 + rm4;
        const int cl = wc + ni * 16 + cn;
        if (OUTM == 2) {
          *(f32x4*)&tile[cl * 132 + rl] = acc[mi][ni];
        } else {
          #pragma unroll
          for (int j = 0; j < 4; ++j) tile[(rl + j) * 132 + cl] = acc[mi][ni][j];
        }
      }
    }
  }
  asm volatile("s_waitcnt lgkmcnt(0)" ::: "memory");
  __builtin_amdgcn_s_barrier();
  asm volatile("" ::: "memory");

  // coalesced writeout: all 512 threads, 8 passes of 16 rows
  #pragma unroll
  for (int p = 0; p < 8; ++p) {
    const int rr = p * 16 + (tid >> 5);
    const int c4 = (tid & 31) << 2;
    f32x4 v = *(const f32x4*)&tile[rr * 132 + c4];
    if (OUTM == 2) {
      const int cc = col0 + rr;
      float badd = BIAS ? bias[(long long)z * sBias + cc] : 0.f;
      u16* pp = Cb + (long long)z * sC + (long long)cc * ldc + row0 + c4;
      ushort4 o;
      o.x = f2bf(v[0] + badd); o.y = f2bf(v[1] + badd);
      o.z = f2bf(v[2] + badd); o.w = f2bf(v[3] + badd);
      *(ushort4*)pp = o;
    } else {
      const int R = row0 + rr;
      const long long idx = (long long)z * sC + (long long)R * ldc + col0 + c4;
      float val[4] = {v[0], v[1], v[2], v[3]};
      if (BIAS) {
        float4 b4 = *(const float4*)&bias[(long long)z * sBias + col0 + c4];
        val[0] += b4.x; val[1] += b4.y; val[2] += b4.z; val[3] += b4.w;
      }
      if (RANK1) {
        float rr1 = r1row[(long long)z * sR1r + R];
        float4 c4v = *(const float4*)&r1col[(long long)z * sR1c + col0 + c4];
        val[0] += rr1 * c4v.x; val[1] += rr1 * c4v.y;
        val[2] += rr1 * c4v.z; val[3] += rr1 * c4v.w;
      }
      if (OUTM == 0) {
        if (ACCUM) {
          float4 old = *(const float4*)&Cf[idx];
          val[0] += old.x; val[1] += old.y; val[2] += old.z; val[3] += old.w;
        }
        if (RELU) {
          val[0] = fmaxf(val[0], 0.f); val[1] = fmaxf(val[1], 0.f);
          val[2] = fmaxf(val[2], 0.f); val[3] = fmaxf(val[3], 0.f);
        }
        float4 o4; o4.x = val[0]; o4.y = val[1]; o4.z = val[2]; o4.w = val[3];
        *(float4*)&Cf[idx] = o4;
      } else {
        ushort4 o;
        o.x = f2bf(val[0]); o.y = f2bf(val[1]);
        o.z = f2bf(val[2]); o.w = f2bf(val[3]);
        *(ushort4*)&Cb[idx] = o;
      }
    }
  }
}

// ---------------------------------------------------------------------------
// 8-wave split-K MFMA GEMM (ring-8, 128 KB, 1 block/CU): for <=256-block,
// K-heavy dispatches where deep prefetch (3 pairs in flight) wins.
// ---------------------------------------------------------------------------
template<int OUTM, bool ACCUM, bool RELU, bool RANK1, bool BIAS>
__global__ __launch_bounds__(512) void mgemm8_k(
    const u16* __restrict__ A, int lda, long long sA,
    const u16* __restrict__ B, int ldb, long long sB,
    const float* __restrict__ bias, int sBias,
    float* __restrict__ Cf, u16* __restrict__ Cb, int ldc, long long sC,
    int K,
    const float* __restrict__ r1row, int sR1r,
    const float* __restrict__ r1col, int sR1c)
{
  __shared__ u16 smem[8 * 8192];   // 8 slots x 16KB = 128 KB
  const int z = blockIdx.z;
  const u16* Ag = A + (long long)z * sA;
  const u16* Bg = B + (long long)z * sB;

  int bx, by;
  xcd_map(gridDim.x, gridDim.y, bx, by);

  const int row0 = by << 7;
  const int col0 = bx << 7;
  const int tid  = threadIdx.x;
  const int lane = tid & 63;
  const int w    = tid >> 6;
  const int g    = w >> 2;
  const int s4   = w & 3;
  const int wr   = (s4 >> 1) << 6;
  const int wc   = (s4 & 1) << 6;

  const int srow = tid >> 2;
  const int ssw  = (tid & 3) ^ ((srow >> 1) & 3);
  const long long aoff = (long long)(row0 + srow) * lda + ssw * 8;
  const long long boff = (long long)(col0 + srow) * ldb + ssw * 8;

  const int frow = lane & 15;
  const int fsw  = (lane >> 4) ^ ((frow >> 1) & 3);
  const int fAoff = ((wr + frow) << 5) + (fsw << 3);
  const int fBoff = ((wc + frow) << 5) + (fsw << 3);

#define STAGE8(tt) do {                                                        \
    u16* _sb = smem + (((tt) & 7) << 13);                                      \
    const long long _k = (long long)(tt) << 5;                                 \
    GLDS16(Ag + aoff + _k, _sb + (tid << 3));                                  \
    GLDS16(Bg + boff + _k, _sb + 4096 + (tid << 3));                           \
  } while (0)

  f32x4 acc[4][4];
  #pragma unroll
  for (int mi = 0; mi < 4; ++mi)
    #pragma unroll
    for (int ni = 0; ni < 4; ++ni) {
      acc[mi][ni][0] = 0.f; acc[mi][ni][1] = 0.f;
      acc[mi][ni][2] = 0.f; acc[mi][ni][3] = 0.f;
    }

  const int NT = K >> 5;
  const int NP = NT >> 1;
  STAGE8(0); STAGE8(1); STAGE8(2); STAGE8(3); STAGE8(4); STAGE8(5);
  asm volatile("s_waitcnt vmcnt(8)" ::: "memory");
  __builtin_amdgcn_s_barrier();
  asm volatile("" ::: "memory");

  for (int i = 0; i < NP; ++i) {
    if (i + 3 < NP) { STAGE8(2 * i + 6); STAGE8(2 * i + 7); }

    const u16* base = smem + (((2 * i + g) & 7) << 13);
    bf16x8 af[4], bfr[4];
    #pragma unroll
    for (int mi = 0; mi < 4; ++mi) af[mi]  = *(const bf16x8*)(base + fAoff + mi * 512);
    #pragma unroll
    for (int ni = 0; ni < 4; ++ni) bfr[ni] = *(const bf16x8*)(base + 4096 + fBoff + ni * 512);
    __builtin_amdgcn_s_setprio(1);
    #pragma unroll
    for (int mi = 0; mi < 4; ++mi)
      #pragma unroll
      for (int ni = 0; ni < 4; ++ni)
        acc[mi][ni] = __builtin_amdgcn_mfma_f32_16x16x32_bf16(
            af[mi], bfr[ni], acc[mi][ni], 0, 0, 0);
    __builtin_amdgcn_s_setprio(0);

    if (i + 1 < NP) {
      if (i + 3 < NP)      asm volatile("s_waitcnt vmcnt(8)" ::: "memory");
      else if (i + 2 < NP) asm volatile("s_waitcnt vmcnt(4)" ::: "memory");
      else                 asm volatile("s_waitcnt vmcnt(0)" ::: "memory");
      __builtin_amdgcn_s_barrier();
      asm volatile("" ::: "memory");
    }
  }
#undef STAGE8

  epilogue128<OUTM, ACCUM, RELU, RANK1, BIAS>(
      smem, acc, z, row0, col0, tid, lane, w, wr, wc,
      bias, sBias, Cf, Cb, ldc, sC, r1row, sR1r, r1col, sR1c);
}

// ---------------------------------------------------------------------------
// Ring-4 variant (~68 KB LDS -> 2 blocks/CU): for > 256-block dispatches
// where co-residency beats prefetch depth. acc[4][4]=64 VGPR fits the
// (512,4) 128-VGPR cap.
// ---------------------------------------------------------------------------
template<int OUTM, bool ACCUM, bool RELU, bool RANK1, bool BIAS>
__global__ __launch_bounds__(512, 4) void mgemm8d_k(
    const u16* __restrict__ A, int lda, long long sA,
    const u16* __restrict__ B, int ldb, long long sB,
    const float* __restrict__ bias, int sBias,
    float* __restrict__ Cf, u16* __restrict__ Cb, int ldc, long long sC,
    int K,
    const float* __restrict__ r1row, int sR1r,
    const float* __restrict__ r1col, int sR1c)
{
  __shared__ u16 smem[33792];   // max(ring-4 64KB, epilogue tile 67.5KB)
  const int z = blockIdx.z;
  const u16* Ag = A + (long long)z * sA;
  const u16* Bg = B + (long long)z * sB;

  int bx, by;
  xcd_map(gridDim.x, gridDim.y, bx, by);

  const int row0 = by << 7;
  const int col0 = bx << 7;
  const int tid  = threadIdx.x;
  const int lane = tid & 63;
  const int w    = tid >> 6;
  const int g    = w >> 2;
  const int s4   = w & 3;
  const int wr   = (s4 >> 1) << 6;
  const int wc   = (s4 & 1) << 6;

  const int srow = tid >> 2;
  const int ssw  = (tid & 3) ^ ((srow >> 1) & 3);
  const long long aoff = (long long)(row0 + srow) * lda + ssw * 8;
  const long long boff = (long long)(col0 + srow) * ldb + ssw * 8;

  const int frow = lane & 15;
  const int fsw  = (lane >> 4) ^ ((frow >> 1) & 3);
  const int fAoff = ((wr + frow) << 5) + (fsw << 3);
  const int fBoff = ((wc + frow) << 5) + (fsw << 3);

#define STAGE4(tt) do {                                                        \
    u16* _sb = smem + (((tt) & 3) << 13);                                      \
    const long long _k = (long long)(tt) << 5;                                 \
    GLDS16(Ag + aoff + _k, _sb + (tid << 3));                                  \
    GLDS16(Bg + boff + _k, _sb + 4096 + (tid << 3));                           \
  } while (0)

  f32x4 acc[4][4];
  #pragma unroll
  for (int mi = 0; mi < 4; ++mi)
    #pragma unroll
    for (int ni = 0; ni < 4; ++ni) {
      acc[mi][ni][0] = 0.f; acc[mi][ni][1] = 0.f;
      acc[mi][ni][2] = 0.f; acc[mi][ni][3] = 0.f;
    }

  const int NT = K >> 5;
  const int NP = NT >> 1;   // >= 2 for all our shapes
  STAGE4(0); STAGE4(1); STAGE4(2); STAGE4(3);   // pairs 0,1 (8 loads)

  for (int p = 0; p < NP; ++p) {
    if (p + 1 < NP) asm volatile("s_waitcnt vmcnt(4)" ::: "memory");
    else            asm volatile("s_waitcnt vmcnt(0)" ::: "memory");
    __builtin_amdgcn_s_barrier();
    asm volatile("" ::: "memory");

    const u16* base = smem + (((2 * p + g) & 3) << 13);
    bf16x8 af[4], bfr[4];
    #pragma unroll
    for (int mi = 0; mi < 4; ++mi) af[mi]  = *(const bf16x8*)(base + fAoff + mi * 512);
    #pragma unroll
    for (int ni = 0; ni < 4; ++ni) bfr[ni] = *(const bf16x8*)(base + 4096 + fBoff + ni * 512);
    asm volatile("s_waitcnt lgkmcnt(0)" ::: "memory");
    __builtin_amdgcn_s_barrier();
    asm volatile("" ::: "memory");

    if (p + 2 < NP) { STAGE4(2 * p + 4); STAGE4(2 * p + 5); }

    __builtin_amdgcn_s_setprio(1);
    #pragma unroll
    for (int mi = 0; mi < 4; ++mi)
      #pragma unroll
      for (int ni = 0; ni < 4; ++ni)
        acc[mi][ni] = __builtin_amdgcn_mfma_f32_16x16x32_bf16(
            af[mi], bfr[ni], acc[mi][ni], 0, 0, 0);
    __builtin_amdgcn_s_setprio(0);
  }
#undef STAGE4

  epilogue128<OUTM, ACCUM, RELU, RANK1, BIAS>(
      smem, acc, z, row0, col0, tid, lane, w, wr, wc,
      bias, sBias, Cf, Cb, ldc, sC, r1row, sR1r, r1col, sR1c);
}

// ---------------------------------------------------------------------------
// 256x256 MFMA GEMM, 8 waves each owning 128x64. BK=32, ring-4 x 32KB LDS
// (128 KB), 3 tiles in flight, counted vmcnt, direct epilogue.
// launch_bounds(512,2): acc[8][4]=128 VGPR needs the 256-VGPR cap; this
// kernel is structurally 1 block/CU (do NOT raise the occupancy floor).
// ---------------------------------------------------------------------------
template<bool BIAS>
__global__ __launch_bounds__(512, 2) void mgemm256_k(
    const u16* __restrict__ A, int lda, long long sA,
    const u16* __restrict__ B, int ldb, long long sB,
    const float* __restrict__ bias, int sBias,
    u16* __restrict__ Cb, int ldc, long long sC,
    int K)
{
  __shared__ u16 smem[4 * 16384];
  const int z = blockIdx.z;
  const u16* Ag = A + (long long)z * sA;
  const u16* Bg = B + (long long)z * sB;

  int bx, by;
  xcd_map(gridDim.x, gridDim.y, bx, by);

  const int row0r = by << 8;
  const int col0 = bx << 8;
  const int tid  = threadIdx.x;
  const int lane = tid & 63;
  const int w    = tid >> 6;
  const int wrow = w >> 2;
  const int wcol = w & 3;

  const int srow = tid >> 2;
  const int ssw  = (tid & 3) ^ ((srow >> 1) & 3);
  const long long aoff0 = (long long)(row0r + srow)       * lda + ssw * 8;
  const long long aoff1 = (long long)(row0r + srow + 128) * lda + ssw * 8;
  const long long boff0 = (long long)(col0 + srow)        * ldb + ssw * 8;
  const long long boff1 = (long long)(col0 + srow + 128)  * ldb + ssw * 8;

  const int frow = lane & 15;
  const int fsw  = (lane >> 4) ^ ((frow >> 1) & 3);
  const int fAoff = ((wrow * 128 + frow) << 5) + (fsw << 3);
  const int fBoff = ((wcol * 64  + frow) << 5) + (fsw << 3);

#define STG256(tt) do {                                                        \
    u16* _sb = smem + (((tt) & 3) << 14);                                      \
    const long long _k = (long long)(tt) << 5;                                 \
    GLDS16(Ag + aoff0 + _k, _sb + (tid << 3));                                 \
    GLDS16(Ag + aoff1 + _k, _sb + 4096 + (tid << 3));                          \
    GLDS16(Bg + boff0 + _k, _sb + 8192 + (tid << 3));                          \
    GLDS16(Bg + boff1 + _k, _sb + 12288 + (tid << 3));                         \
  } while (0)

  f32x4 acc[8][4];
  #pragma unroll
  for (int mi = 0; mi < 8; ++mi)
    #pragma unroll
    for (int ni = 0; ni < 4; ++ni) {
      acc[mi][ni][0] = 0.f; acc[mi][ni][1] = 0.f;
      acc[mi][ni][2] = 0.f; acc[mi][ni][3] = 0.f;
    }

  const int NT = K >> 5;
  STG256(0); STG256(1); STG256(2);
  asm volatile("s_waitcnt vmcnt(8)" ::: "memory");
  __builtin_amdgcn_s_barrier();
  asm volatile("" ::: "memory");

  for (int t = 0; t < NT; ++t) {
    if (t + 3 < NT) STG256(t + 3);

    const u16* base = smem + ((t & 3) << 14);
    bf16x8 af[8], bfr[4];
    #pragma unroll
    for (int mi = 0; mi < 8; ++mi) af[mi]  = *(const bf16x8*)(base + fAoff + mi * 512);
    #pragma unroll
    for (int ni = 0; ni < 4; ++ni) bfr[ni] = *(const bf16x8*)(base + 8192 + fBoff + ni * 512);
    __builtin_amdgcn_s_setprio(1);
    #pragma unroll
    for (int mi = 0; mi < 8; ++mi)
      #pragma unroll
      for (int ni = 0; ni < 4; ++ni)
        acc[mi][ni] = __builtin_amdgcn_mfma_f32_16x16x32_bf16(
            af[mi], bfr[ni], acc[mi][ni], 0, 0, 0);
    __builtin_amdgcn_s_setprio(0);

    if (t + 1 < NT) {
      if (t + 3 < NT)      asm volatile("s_waitcnt vmcnt(8)" ::: "memory");
      else if (t + 2 < NT) asm volatile("s_waitcnt vmcnt(4)" ::: "memory");
      else                 asm volatile("s_waitcnt vmcnt(0)" ::: "memory");
      __builtin_amdgcn_s_barrier();
      asm volatile("" ::: "memory");
    }
  }
#undef STG256

  const int cn  = lane & 15;
  const int rm4 = (lane >> 4) << 2;
  #pragma unroll
  for (int mi = 0; mi < 8; ++mi) {
    #pragma unroll
    for (int ni = 0; ni < 4; ++ni) {
      const int rb = row0r + wrow * 128 + mi * 16 + rm4;
      const int cc = col0 + wcol * 64 + ni * 16 + cn;
      float badd = BIAS ? bias[(long long)z * sBias + cc] : 0.f;
      f32x4 v = acc[mi][ni];
      #pragma unroll
      for (int j = 0; j < 4; ++j)
        Cb[(long long)z * sC + (long long)(rb + j) * ldc + cc] = f2bf(v[j] + badd);
    }
  }
}

// out = relu(p0+p1+p2+p3), partials stride 1M floats, n4 = n/4 float4s
__global__ __launch_bounds__(256) void reduce4relu_k(
    const float* __restrict__ p, float* __restrict__ out, int n4)
{
  int i = blockIdx.x * 256 + threadIdx.x;
  if (i < n4) {
    float4 a = ((const float4*)p)[i];
    float4 b = ((const float4*)(p + (1ll << 20)))[i];
    float4 c = ((const float4*)(p + (2ll << 20)))[i];
    float4 d = ((const float4*)(p + (3ll << 20)))[i];
    float4 o;
    o.x = fmaxf(a.x + b.x + c.x + d.x, 0.f);
    o.y = fmaxf(a.y + b.y + c.y + d.y, 0.f);
    o.z = fmaxf(a.z + b.z + c.z + d.z, 0.f);
    o.w = fmaxf(a.w + b.w + c.w + d.w, 0.f);
    ((float4*)out)[i] = o;
  }
}

// ---------------------------------------------------------------------------
// Fused: xT[c][r] = x[r][c] (fp32) AND x_bf[r][c] = bf16(x[r][c]).
// Reads x once. grid (32,32), 256 threads.
// ---------------------------------------------------------------------------
__global__ __launch_bounds__(256) void xc_k(
    const float* __restrict__ x, float* __restrict__ xT, u16* __restrict__ xbf)
{
  __shared__ float tile[32][33];
  int c0 = blockIdx.x * 32, r0 = blockIdx.y * 32;
  int tx = threadIdx.x & 31, ty = threadIdx.x >> 5;
  #pragma unroll
  for (int rr = ty; rr < 32; rr += 8) {
    float v = x[(long long)(r0 + rr) * 1024 + c0 + tx];
    tile[rr][tx] = v;
    xbf[(long long)(r0 + rr) * 1024 + c0 + tx] = f2bf(v);
  }
  __syncthreads();
  #pragma unroll
  for (int cc = ty; cc < 32; cc += 8)
    out_store: ;
  #pragma unroll
  for (int cc = ty; cc < 32; cc += 8)
    xT[(long long)(c0 + cc) * 1024 + r0 + tx] = tile[tx][cc];
}

// fp32 [R][C] -> bf16 [C][R], batched over 4 (src,dst) pairs via blockIdx.z
__global__ __launch_bounds__(256) void wcvt4_k(
    const float* __restrict__ s0, const float* __restrict__ s1,
    const float* __restrict__ s2, const float* __restrict__ s3,
    u16* __restrict__ d0, u16* __restrict__ d1,
    u16* __restrict__ d2, u16* __restrict__ d3, int R, int Cc)
{
  const float* in = (blockIdx.z == 0) ? s0 : (blockIdx.z == 1) ? s1
                  : (blockIdx.z == 2) ? s2 : s3;
  u16* out = (blockIdx.z == 0) ? d0 : (blockIdx.z == 1) ? d1
           : (blockIdx.z == 2) ? d2 : d3;
  __shared__ float tile[32][33];
  int c0 = blockIdx.x * 32, r0 = blockIdx.y * 32;
  int tx = threadIdx.x & 31, ty = threadIdx.x >> 5;
  #pragma unroll
  for (int rr = ty; rr < 32; rr += 8)
    tile[rr][tx] = in[(long long)(r0 + rr) * Cc + c0 + tx];
  __syncthreads();
  #pragma unroll
  for (int cc = ty; cc < 32; cc += 8)
    out[(long long)(c0 + cc) * R + r0 + tx] = f2bf(tile[tx][cc]);
}

// bf16 [R][C] -> bf16 [C][R] (pure transpose; values unchanged)
__global__ __launch_bounds__(256) void btr_k(
    const u16* __restrict__ in, u16* __restrict__ out, int R, int Cc)
{
  __shared__ u16 tile[32][34];
  int c0 = blockIdx.x * 32, r0 = blockIdx.y * 32;
  int tx = threadIdx.x & 31, ty = threadIdx.x >> 5;
  #pragma unroll
  for (int rr = ty; rr < 32; rr += 8)
    tile[rr][tx] = in[(long long)(r0 + rr) * Cc + c0 + tx];
  __syncthreads();
  #pragma unroll
  for (int cc = ty; cc < 32; cc += 8)
    out[(long long)(c0 + cc) * R + r0 + tx] = tile[tx][cc];
}

// fp32 [R][C] -> bf16 [C][R] with per-source-column affine: A2[c]*v + C2[c]
__global__ __launch_bounds__(256) void tcvt_aff_k(
    const float* __restrict__ in, u16* __restrict__ out, int R, int Cc,
    const float* __restrict__ A2, const float* __restrict__ C2)
{
  __shared__ float tile[32][33];
  int c0 = blockIdx.x * 32, r0 = blockIdx.y * 32;
  int tx = threadIdx.x & 31, ty = threadIdx.x >> 5;
  #pragma unroll
  for (int rr = ty; rr < 32; rr += 8)
    tile[rr][tx] = in[(long long)(r0 + rr) * Cc + c0 + tx];
  __syncthreads();
  #pragma unroll
  for (int cc = ty; cc < 32; cc += 8) {
    float v = A2[c0 + cc] * tile[tx][cc] + C2[c0 + cc];
    out[(long long)(c0 + cc) * R + r0 + tx] = f2bf(v);
  }
}

// pack both QK bias pairs in one launch: blocks 0-15 -> biasQK1 (n1=4096),
// blocks 16-23 -> biasQK2 (n2=2048)
__global__ __launch_bounds__(256) void pack2b_k(
    const float* __restrict__ a1, const float* __restrict__ b1,
    float* __restrict__ o1, int n1,
    const float* __restrict__ a2, const float* __restrict__ b2,
    float* __restrict__ o2, int n2)
{
  int i = blockIdx.x * 256 + threadIdx.x;
  if (i < n1) { o1[i] = a1[i]; o1[n1 + i] = b1[i]; }
  int j = i - n1;
  if (j >= 0 && j < n2) { o2[j] = a2[j]; o2[n2 + j] = b2[j]; }
}

// ---------------------------------------------------------------------------
__global__ __launch_bounds__(64) void qe_k(const u16* __restrict__ Q1,
                                           const float* __restrict__ We1,
                                           float* __restrict__ qe)
{
  int h = blockIdx.x >> 10;
  int i = blockIdx.x & 1023;
  const u16* q = Q1 + (long long)i * 4096 + h * 512;
  const float* wv = We1 + h * 512;
  int l = threadIdx.x;
  float s = 0.f;
  #pragma unroll
  for (int r = 0; r < 8; ++r) s += bf2f(q[l + r * 64]) * wv[l + r * 64];
  #pragma unroll
  for (int off = 32; off > 0; off >>= 1) s += __shfl_down(s, off);
  if (l == 0) qe[blockIdx.x] = s;
}

// ---------------------------------------------------------------------------
__global__ __launch_bounds__(256) void softmax1b_k(
    u16* __restrict__ S, const float* __restrict__ xT,
    const float* __restrict__ qe, float* __restrict__ ae)
{
  int i = blockIdx.x, h = blockIdx.y;
  u16* s = S + ((long long)h * 1024 + i) * 1024;
  const float* e = xT + (long long)i * 1024;
  float q = qe[h * 1024 + i];
  int tid = threadIdx.x;
  __shared__ float red[256];

  ushort4 sv = ((const ushort4*)s)[tid];
  float4  evv = ((const float4*)e)[tid];
  float ev[4] = {evv.x, evv.y, evv.z, evv.w};
  float t[4];
  t[0] = (bf2f(sv.x) + q * ev[0]) * kInvSqrtD;
  t[1] = (bf2f(sv.y) + q * ev[1]) * kInvSqrtD;
  t[2] = (bf2f(sv.z) + q * ev[2]) * kInvSqrtD;
  t[3] = (bf2f(sv.w) + q * ev[3]) * kInvSqrtD;
  float m = fmaxf(fmaxf(t[0], t[1]), fmaxf(t[2], t[3]));
  m = blockReduceMax(m, red);
  float sum = 0.f;
  #pragma unroll
  for (int r = 0; r < 4; ++r) { t[r] = __expf(t[r] - m); sum += t[r]; }
  sum = blockReduceSum(sum, red);
  float invl = 1.f / sum;
  float aes = 0.f;
  ushort4 o;
  o.x = f2bf(t[0] * invl); o.y = f2bf(t[1] * invl);
  o.z = f2bf(t[2] * invl); o.w = f2bf(t[3] * invl);
  #pragma unroll
  for (int r = 0; r < 4; ++r) aes += (t[r] * invl) * ev[r];
  ((ushort4*)s)[tid] = o;
  aes = blockReduceSum(aes, red);
  if (tid == 0) ae[h * 1024 + i] = aes;
}

__global__ __launch_bounds__(256) void softmax2b_k(u16* __restrict__ S)
{
  u16* s = S + ((long long)blockIdx.y * 2048 + blockIdx.x) * 4096;
  int tid = threadIdx.x;
  __shared__ float red[256];
  float t[16];
  float m = -1e30f;
  #pragma unroll
  for (int r = 0; r < 4; ++r) {
    ushort4 sv = ((const ushort4*)s)[tid + r * 256];
    t[r*4+0] = bf2f(sv.x) * kInvSqrtD; t[r*4+1] = bf2f(sv.y) * kInvSqrtD;
    t[r*4+2] = bf2f(sv.z) * kInvSqrtD; t[r*4+3] = bf2f(sv.w) * kInvSqrtD;
    m = fmaxf(m, fmaxf(fmaxf(t[r*4], t[r*4+1]), fmaxf(t[r*4+2], t[r*4+3])));
  }
  m = blockReduceMax(m, red);
  float sum = 0.f;
  #pragma unroll
  for (int r = 0; r < 16; ++r) { t[r] = __expf(t[r] - m); sum += t[r]; }
  sum = blockReduceSum(sum, red);
  float invl = 1.f / sum;
  #pragma unroll
  for (int r = 0; r < 4; ++r) {
    ushort4 o;
    o.x = f2bf(t[r*4+0] * invl); o.y = f2bf(t[r*4+1] * invl);
    o.z = f2bf(t[r*4+2] * invl); o.w = f2bf(t[r*4+3] * invl);
    ((ushort4*)s)[tid + r * 256] = o;
  }
}

// ---------------------------------------------------------------------------
__global__ __launch_bounds__(256) void colpart4_k(const float* __restrict__ h,
    int N, int F, int nchunk, float* __restrict__ ps, float* __restrict__ pss)
{
  const int f4 = blockIdx.x * 256 + threadIdx.x;
  const int chunk = blockIdx.y;
  const int rows = N / nchunk;
  const int rbeg = chunk * rows;
  const int F4 = F >> 2;
  const float4* h4 = (const float4*)h;
  float4 s = {0.f, 0.f, 0.f, 0.f}, ss = {0.f, 0.f, 0.f, 0.f};
  #pragma unroll 8
  for (int i = 0; i < rows; ++i) {
    float4 v = h4[(long long)(rbeg + i) * F4 + f4];
    s.x += v.x; s.y += v.y; s.z += v.z; s.w += v.w;
    ss.x += v.x * v.x; ss.y += v.y * v.y;
    ss.z += v.z * v.z; ss.w += v.w * v.w;
  }
  ((float4*)(ps  + (long long)chunk * F))[f4] = s;
  ((float4*)(pss + (long long)chunk * F))[f4] = ss;
}

// Parallel finisher: one block per float4-column; 256 threads split chunks.
template<int MODE>
__global__ __launch_bounds__(256) void colfin2_k(
    const float* __restrict__ ps, const float* __restrict__ pss,
    int F, int nchunk, float Nf,
    const float* __restrict__ ms, const float* __restrict__ g,
    const float* __restrict__ beta,
    float* __restrict__ outA, float* __restrict__ outC)
{
  __shared__ float4 red4[256];
  const int f4 = blockIdx.x;
  const int tid = threadIdx.x;
  float4 s = {0.f, 0.f, 0.f, 0.f}, ss = {0.f, 0.f, 0.f, 0.f};
  for (int c = tid; c < nchunk; c += 256) {
    float4 v = ((const float4*)(ps  + (long long)c * F))[f4];
    float4 u = ((const float4*)(pss + (long long)c * F))[f4];
    s.x += v.x; s.y += v.y; s.z += v.z; s.w += v.w;
    ss.x += u.x; ss.y += u.y; ss.z += u.z; ss.w += u.w;
  }
  s  = blockReduceF4(s, red4);
  ss = blockReduceF4(ss, red4);
  if (tid < 4) {
    const int f = f4 * 4 + tid;
    float sv  = (tid == 0) ? s.x  : (tid == 1) ? s.y  : (tid == 2) ? s.z  : s.w;
    float ssv = (tid == 0) ? ss.x : (tid == 1) ? ss.y : (tid == 2) ? ss.z : ss.w;
    float Ninv = 1.f / Nf;
    float mean = sv * Ninv;
    float mm = ms[f] * mean;
    float var = ssv * Ninv - 2.f * mm * mean + mm * mm;
    float is = rsqrtf(var + 1e-5f);
    float a = g[f] * is;
    float c = beta[f] - a * mm;
    if (MODE == 1) {
      float sy2 = a * a * ssv + 2.f * a * c * sv + Nf * c * c;
      float cinv = rsqrtf(sy2);
      a *= cinv; c *= cinv;
    }
    outA[f] = a;
    outC[f] = c;
  }
}

__global__ __launch_bounds__(256) void rowl2gn_k(
    float* __restrict__ h, u16* __restrict__ hb,
    const float* __restrict__ a, const float* __restrict__ c)
{
  int i = blockIdx.x;
  float* row = h + (long long)i * 4096;
  u16* rb = hb + (long long)i * 4096;
  int tid = threadIdx.x;
  __shared__ float red[256];
  float t[16];
  float ss = 0.f;
  #pragma unroll
  for (int r = 0; r < 4; ++r) {
    int j = tid + r * 256;
    float4 hv = ((const float4*)row)[j];
    float4 av = ((const float4*)a)[j];
    float4 cv = ((const float4*)c)[j];
    t[r*4+0] = av.x * hv.x + cv.x;
    t[r*4+1] = av.y * hv.y + cv.y;
    t[r*4+2] = av.z * hv.z + cv.z;
    t[r*4+3] = av.w * hv.w + cv.w;
    ss += t[r*4+0]*t[r*4+0] + t[r*4+1]*t[r*4+1]
        + t[r*4+2]*t[r*4+2] + t[r*4+3]*t[r*4+3];
  }
  ss = blockReduceSum(ss, red);
  float inv = rsqrtf(ss);
  #pragma unroll
  for (int r = 0; r < 4; ++r) {
    int j = tid + r * 256;
    float4 o4;
    o4.x = t[r*4+0] * inv; o4.y = t[r*4+1] * inv;
    o4.z = t[r*4+2] * inv; o4.w = t[r*4+3] * inv;
    ((float4*)row)[j] = o4;
    ushort4 ob;
    ob.x = f2bf(o4.x); ob.y = f2bf(o4.y); ob.z = f2bf(o4.z); ob.w = f2bf(o4.w);
    ((ushort4*)rb)[j] = ob;
  }
}

// ---------------------------------------------------------------------------
extern "C" void kernel_launch(void* const* d_in, const int* in_sizes, int n_in,
                              void* d_out, int out_size, void* d_ws, size_t ws_size,
                              hipStream_t stream)
{
  (void)in_sizes; (void)n_in; (void)out_size; (void)ws_size;

  const float* x      = (const float*)d_in[0];
  const float* Wq1    = (const float*)d_in[1];
  const float* bq1    = (const float*)d_in[2];
  const float* Wk1    = (const float*)d_in[3];
  const float* bk1    = (const float*)d_in[4];
  const float* Wv1    = (const float*)d_in[5];
  const float* bv1    = (const float*)d_in[6];
  const float* We1    = (const float*)d_in[7];
  const float* Wskip1 = (const float*)d_in[8];
  const float* bskip1 = (const float*)d_in[9];
  const float* g1     = (const float*)d_in[10];
  const float* bb1    = (const float*)d_in[11];
  const float* ms1    = (const float*)d_in[12];
  const float* Wq2    = (const float*)d_in[13];
  const float* bq2    = (const float*)d_in[14];
  const float* Wk2    = (const float*)d_in[15];
  const float* bk2    = (const float*)d_in[16];
  const float* Wv2    = (const float*)d_in[17];
  const float* bv2    = (const float*)d_in[18];
  const float* Wskip2 = (const float*)d_in[19];
  const float* bskip2 = (const float*)d_in[20];
  const float* g2     = (const float*)d_in[21];
  const float* bb2    = (const float*)d_in[22];
  const float* ms2    = (const float*)d_in[23];

  // ---- workspace arena (~209 MB) ----
  char* base = (char*)d_ws;
  float* lrx_f   = (float*)(base);                 // 16MB [1024][4096]
  u16*   lrx_bf  = (u16*)  (base + (16ll << 20));  // 8MB
  u16*   lrxT_bf = (u16*)  (base + (24ll << 20));  // 8MB [4096][1024]
  u16*   hrx_bf  = (u16*)  (base + (32ll << 20));  // 16MB [2048][4096]
  char* sh = base + (48ll << 20);                  // shared region, 160MB
  // stage A
  u16* x_bf  = (u16*)(sh);                         // 2MB
  float* xT  = (float*)(sh + (2ll << 20));         // 4MB
  u16* Wq1T  = (u16*)(sh + (6ll << 20));           // 8MB each (Wk1T follows Wq1T)
  u16* Wk1T  = (u16*)(sh + (14ll << 20));
  u16* Wv1T  = (u16*)(sh + (22ll << 20));
  u16* Ws1T  = (u16*)(sh + (30ll << 20));
  u16* Q1bf  = (u16*)(sh + (38ll << 20));          // 8MB [1024][4096] (K1bf follows)
  u16* K1bf  = (u16*)(sh + (46ll << 20));          // 8MB
  u16* V1T   = (u16*)(sh + (54ll << 20));          // 8MB [4096][1024]
  u16* S1bf  = (u16*)(sh + (62ll << 20));          // 16MB [8][1024][1024]
  // GN1 partials in dead S1bf space (consumed before V2T/H2 writes)
  float* ps1  = (float*)(sh + (66ll << 20));       // 2MB [128][4096]
  float* pss1 = (float*)(sh + (68ll << 20));       // 2MB
  // stage B (aliases stage A)
  u16* Wq2T  = (u16*)(sh);                         // 4MB each (Wk2T follows)
  u16* Wk2T  = (u16*)(sh + (4ll << 20));
  u16* Wv2T  = (u16*)(sh + (8ll << 20));
  u16* Ws2T  = (u16*)(sh + (12ll << 20));
  u16* Q2bf  = (u16*)(sh + (16ll << 20));          // 16MB [4096][2048] (K2bf follows)
  u16* K2bf  = (u16*)(sh + (32ll << 20));          // 16MB
  u16* V2T   = (u16*)(sh + (48ll << 20));          // 16MB [2048][4096]
  float* H2  = (float*)(sh + (64ll << 20));        // 32MB [4096][2048]
  u16* S2bf  = (u16*)(sh + (96ll << 20));          // 64MB [4][2048][4096]
  float* gpart = (float*)(sh + (96ll << 20));      // 16MB lr-gram partials (S2 dead)
  // GN2 partials in dead S2bf space (consumed before gpart written)
  float* ps2  = (float*)(sh + (120ll << 20));      // 2MB [256][2048]
  float* pss2 = (float*)(sh + (122ll << 20));      // 2MB
  // small tail
  float* tail    = (float*)(base + (208ll << 20));
  float* qe      = tail;             // 8192
  float* ae      = qe + 8192;        // 8192
  float* af1     = ae + 8192;        // 4096
  float* cf1     = af1 + 4096;       // 4096
  float* A2v     = cf1 + 4096;       // 2048
  float* C2v     = A2v + 2048;       // 2048
  float* biasQK1 = C2v + 2048;       // 8192
  float* biasQK2 = biasQK1 + 8192;   // 4096

  float* out0 = (float*)d_out;                   // hr [2048][2048]
  float* out1 = out0 + (long long)2048 * 2048;   // lr gram [1024][1024]

  // ---- stage 0: fused conversions ----
  xc_k<<<dim3(32, 32), 256, 0, stream>>>(x, xT, x_bf);
  wcvt4_k<<<dim3(128, 32, 4), 256, 0, stream>>>(
      Wq1, Wk1, Wv1, Wskip1, Wq1T, Wk1T, Wv1T, Ws1T, 1024, 4096);
  pack2b_k<<<dim3(24), 256, 0, stream>>>(bq1, bk1, biasQK1, 4096,
                                         bq2, bk2, biasQK2, 2048);

  // ---- conv1 Q+K batched (z=2, 512 blocks -> ring-4), V + skip (ring-8) ----
  mgemm8d_k<1,false,false,false,true><<<dim3(32, 8, 2), 512, 0, stream>>>(
      x_bf, 1024, 0, Wq1T, 1024, (long long)4096 * 1024, biasQK1, 4096,
      nullptr, Q1bf, 4096, (long long)1024 * 4096, 1024, nullptr, 0, nullptr, 0);
  mgemm8_k<2,false,false,false,true><<<dim3(32, 8, 1), 512, 0, stream>>>(
      x_bf, 1024, 0, Wv1T, 1024, 0, bv1, 0, nullptr, V1T, 1024, 0, 1024,
      nullptr, 0, nullptr, 0);
  mgemm8_k<0,false,false,false,true><<<dim3(32, 8, 1), 512, 0, stream>>>(
      x_bf, 1024, 0, Ws1T, 1024, 0, bskip1, 0, lrx_f, nullptr, 4096, 0, 1024,
      nullptr, 0, nullptr, 0);

  qe_k<<<dim3(8192), 64, 0, stream>>>(Q1bf, We1, qe);

  // ---- scores1[h] (512 blocks -> ring-4) ----
  mgemm8d_k<1,false,false,false,false><<<dim3(8, 8, 8), 512, 0, stream>>>(
      Q1bf, 4096, 512, K1bf, 4096, 512, nullptr, 0, nullptr, S1bf, 1024, 1048576,
      512, nullptr, 0, nullptr, 0);

  softmax1b_k<<<dim3(1024, 8), 256, 0, stream>>>(S1bf, xT, qe, ae);

  // ---- PV1 (256 blocks -> ring-8) ----
  mgemm8_k<0,true,false,true,false><<<dim3(4, 8, 8), 512, 0, stream>>>(
      S1bf, 1024, 1048576, V1T, 1024, 512 * 1024, nullptr, 0, lrx_f, nullptr,
      4096, 512, 1024, ae, 1024, We1, 512);

  // ---- GraphNorm1 (affine) + row L2, fused ----
  colpart4_k<<<dim3(4, 128), 256, 0, stream>>>(lrx_f, 1024, 4096, 128, ps1, pss1);
  colfin2_k<0><<<dim3(1024), 256, 0, stream>>>(ps1, pss1, 4096, 128, 1024.f,
                                               ms1, g1, bb1, af1, cf1);
  rowl2gn_k<<<dim3(1024), 256, 0, stream>>>(lrx_f, lrx_bf, af1, cf1);
  btr_k<<<dim3(128, 32), 256, 0, stream>>>(lrx_bf, lrxT_bf, 1024, 4096);

  // ---- conv2 weights (batched; region aliases stage A) ----
  wcvt4_k<<<dim3(64, 32, 4), 256, 0, stream>>>(
      Wq2, Wk2, Wv2, Wskip2, Wq2T, Wk2T, Wv2T, Ws2T, 1024, 2048);

  // ---- conv2 Q+K on 256^2 kernel; V + skip (512 blocks -> ring-4) ----
  mgemm256_k<true><<<dim3(8, 16, 2), 512, 0, stream>>>(
      lrxT_bf, 1024, 0, Wq2T, 1024, (long long)2048 * 1024, biasQK2, 2048,
      Q2bf, 2048, (long long)4096 * 2048, 1024);
  mgemm8d_k<2,false,false,false,true><<<dim3(16, 32, 1), 512, 0, stream>>>(
      lrxT_bf, 1024, 0, Wv2T, 1024, 0, bv2, 0, nullptr, V2T, 4096, 0, 1024,
      nullptr, 0, nullptr, 0);
  mgemm8d_k<0,false,false,false,true><<<dim3(16, 32, 1), 512, 0, stream>>>(
      lrxT_bf, 1024, 0, Ws2T, 1024, 0, bskip2, 0, H2, nullptr, 2048, 0, 1024,
      nullptr, 0, nullptr, 0);

  // ---- conv2 attention in 2 chunks of 2048 rows ----
  for (int c = 0; c < 2; ++c) {
    const u16* Qc = Q2bf + (long long)c * 2048 * 2048;
    float* Hc = H2 + (long long)c * 2048 * 2048;
    mgemm256_k<false><<<dim3(16, 8, 4), 512, 0, stream>>>(
        Qc, 2048, 512, K2bf, 2048, 512, nullptr, 0,
        S2bf, 4096, (long long)2048 * 4096, 512);
    softmax2b_k<<<dim3(2048, 4), 256, 0, stream>>>(S2bf);
    mgemm8_k<0,true,false,false,false><<<dim3(4, 16, 4), 512, 0, stream>>>(
        S2bf, 4096, (long long)2048 * 4096, V2T, 4096, (long long)512 * 4096,
        nullptr, 0, Hc, nullptr, 2048, 512, 4096, nullptr, 0, nullptr, 0);
  }

  // ---- GraphNorm2 + column L2 fused into one affine transpose-convert ----
  colpart4_k<<<dim3(2, 256), 256, 0, stream>>>(H2, 4096, 2048, 256, ps2, pss2);
  colfin2_k<1><<<dim3(512), 256, 0, stream>>>(ps2, pss2, 2048, 256, 4096.f,
                                              ms2, g2, bb2, A2v, C2v);
  tcvt_aff_k<<<dim3(64, 128), 256, 0, stream>>>(H2, hrx_bf, 4096, 2048, A2v, C2v);

  // ---- outputs: relu Grams ----
  mgemm8_k<0,false,true,false,false><<<dim3(16, 16, 1), 512, 0, stream>>>(
      hrx_bf, 4096, 0, hrx_bf, 4096, 0, nullptr, 0, out0, nullptr, 2048, 0, 4096,
      nullptr, 0, nullptr, 0);
  // lr-gram: grid-split K 4-way (z) into partials, then reduce+relu
  mgemm8_k<0,false,false,false,false><<<dim3(8, 8, 4), 512, 0, stream>>>(
      lrx_bf, 4096, 1024, lrx_bf, 4096, 1024, nullptr, 0, gpart, nullptr, 1024,
      (long long)1 << 20, 1024, nullptr, 0, nullptr, 0);
  reduce4relu_k<<<dim3(1024), 256, 0, stream>>>(gpart, out1, 262144);
}

// Round 17
// 610.285 us; speedup vs baseline: 2.6675x; 1.0061x over previous
//
#include <hip/hip_runtime.h>
#include <hip/hip_bf16.h>

typedef unsigned short u16;
typedef __attribute__((ext_vector_type(8))) short bf16x8;
typedef __attribute__((ext_vector_type(4))) float f32x4;

__device__ __constant__ float kInvSqrtD = 0.04419417382415922f; // 1/sqrt(512)

__device__ __forceinline__ u16 f2bf(float f) {
  union { float f; unsigned u; } a; a.f = f;
  unsigned r = a.u + 0x7FFFu + ((a.u >> 16) & 1u);
  return (u16)(r >> 16);
}
__device__ __forceinline__ float bf2f(u16 u) {
  union { unsigned u; float f; } a; a.u = ((unsigned)u) << 16;
  return a.f;
}

// ---------------------------------------------------------------------------
// Block reductions (blockDim.x == 256)
// ---------------------------------------------------------------------------
__device__ __forceinline__ float blockReduceMax(float v, float* red) {
  int tid = threadIdx.x;
  red[tid] = v; __syncthreads();
  #pragma unroll
  for (int w = 128; w > 0; w >>= 1) {
    if (tid < w) red[tid] = fmaxf(red[tid], red[tid + w]);
    __syncthreads();
  }
  float r = red[0];
  __syncthreads();
  return r;
}
__device__ __forceinline__ float blockReduceSum(float v, float* red) {
  int tid = threadIdx.x;
  red[tid] = v; __syncthreads();
  #pragma unroll
  for (int w = 128; w > 0; w >>= 1) {
    if (tid < w) red[tid] = red[tid] + red[tid + w];
    __syncthreads();
  }
  float r = red[0];
  __syncthreads();
  return r;
}

__device__ __forceinline__ float4 blockReduceF4(float4 v, float4* red) {
  int tid = threadIdx.x;
  red[tid] = v; __syncthreads();
  #pragma unroll
  for (int w = 128; w > 0; w >>= 1) {
    if (tid < w) {
      float4 a = red[tid], b = red[tid + w];
      a.x += b.x; a.y += b.y; a.z += b.z; a.w += b.w;
      red[tid] = a;
    }
    __syncthreads();
  }
  float4 r = red[0];
  __syncthreads();
  return r;
}

#define GLDS16(gp, lp)                                                         \
  __builtin_amdgcn_global_load_lds(                                            \
      (const __attribute__((address_space(1))) void*)(gp),                     \
      (__attribute__((address_space(3))) void*)(lp), 16, 0, 0)

// 2-D rectangular XCD partition (bijective); fallback: 1-D chunks
__device__ __forceinline__ void xcd_map(int gx, int gy, int& bx, int& by) {
  const int nwg = gx * gy;
  const int orig = blockIdx.y * gx + blockIdx.x;
  if ((nwg & 7) == 0) {
    int bestfx = 0, bestcost = 1 << 30;
    #pragma unroll
    for (int fx = 1; fx <= 8; fx <<= 1) {
      int fy = 8 / fx;
      if ((gx % fx) == 0 && (gy % fy) == 0) {
        int cost = gx / fx + gy / fy;
        if (cost < bestcost) { bestcost = cost; bestfx = fx; }
      }
    }
    if (bestfx > 0) {
      const int fx = bestfx, fy = 8 / bestfx;
      const int rw = gx / fx, rh = gy / fy;
      const int xcd = orig & 7, lid = orig >> 3;
      bx = (xcd % fx) * rw + lid % rw;
      by = (xcd / fx) * rh + lid / rw;
      return;
    }
    const int q = nwg >> 3;
    const int xcd = orig & 7, lid = orig >> 3;
    const int wgid = xcd * q + lid;
    bx = wgid % gx; by = wgid / gx;
    return;
  }
  const int q = nwg >> 3, r = nwg & 7;
  const int xcd = orig & 7, lid = orig >> 3;
  const int wgid = (xcd < r ? xcd * (q + 1) : r * (q + 1) + (xcd - r) * q) + lid;
  bx = wgid % gx; by = wgid / gx;
}

// ---------------------------------------------------------------------------
// Shared epilogue for the 128x128 8-wave kernels: split-K merge via LDS,
// LDS tile staging, coalesced writeout. smem must hold >= 67584 bytes.
// OUTM 1 honors ACCUM by read-add-write on the bf16 output (full-line r/w).
// ---------------------------------------------------------------------------
template<int OUTM, bool ACCUM, bool RELU, bool RANK1, bool BIAS>
__device__ __forceinline__ void epilogue128(
    u16* smem, f32x4 (&acc)[4][4],
    int z, int row0, int col0, int tid, int lane, int w, int wr, int wc,
    const float* bias, int sBias,
    float* Cf, u16* Cb, int ldc, long long sC,
    const float* r1row, int sR1r, const float* r1col, int sR1c)
{
  // cross-group merge: group 1 dumps acc to LDS, group 0 adds
  float* dump = (float*)smem;
  if (w >= 4) {
    float* reg = dump + ((w - 4) << 12);
    #pragma unroll
    for (int f = 0; f < 16; ++f) {
      int mi = f >> 2, ni = f & 3;
      *(f32x4*)(reg + (lane << 6) + (((f + lane) & 15) << 2)) = acc[mi][ni];
    }
  }
  asm volatile("s_waitcnt lgkmcnt(0)" ::: "memory");
  __builtin_amdgcn_s_barrier();
  asm volatile("" ::: "memory");
  if (w < 4) {
    float* reg = dump + (w << 12);
    #pragma unroll
    for (int f = 0; f < 16; ++f) {
      int mi = f >> 2, ni = f & 3;
      acc[mi][ni] += *(const f32x4*)(reg + (lane << 6) + (((f + lane) & 15) << 2));
    }
  }
  asm volatile("s_waitcnt lgkmcnt(0)" ::: "memory");
  __builtin_amdgcn_s_barrier();
  asm volatile("" ::: "memory");

  // tile store (group 0 only) into LDS [128][132] fp32
  float* tile = (float*)smem;
  if (w < 4) {
    const int cn  = lane & 15;
    const int rm4 = (lane >> 4) << 2;
    #pragma unroll
    for (int mi = 0; mi < 4; ++mi) {
      #pragma unroll
      for (int ni = 0; ni < 4; ++ni) {
        const int rl = wr + mi * 16 + rm4;
        const int cl = wc + ni * 16 + cn;
        if (OUTM == 2) {
          *(f32x4*)&tile[cl * 132 + rl] = acc[mi][ni];
        } else {
          #pragma unroll
          for (int j = 0; j < 4; ++j) tile[(rl + j) * 132 + cl] = acc[mi][ni][j];
        }
      }
    }
  }
  asm volatile("s_waitcnt lgkmcnt(0)" ::: "memory");
  __builtin_amdgcn_s_barrier();
  asm volatile("" ::: "memory");

  // coalesced writeout: all 512 threads, 8 passes of 16 rows
  #pragma unroll
  for (int p = 0; p < 8; ++p) {
    const int rr = p * 16 + (tid >> 5);
    const int c4 = (tid & 31) << 2;
    f32x4 v = *(const f32x4*)&tile[rr * 132 + c4];
    if (OUTM == 2) {
      const int cc = col0 + rr;
      float badd = BIAS ? bias[(long long)z * sBias + cc] : 0.f;
      u16* pp = Cb + (long long)z * sC + (long long)cc * ldc + row0 + c4;
      ushort4 o;
      o.x = f2bf(v[0] + badd); o.y = f2bf(v[1] + badd);
      o.z = f2bf(v[2] + badd); o.w = f2bf(v[3] + badd);
      *(ushort4*)pp = o;
    } else {
      const int R = row0 + rr;
      const long long idx = (long long)z * sC + (long long)R * ldc + col0 + c4;
      float val[4] = {v[0], v[1], v[2], v[3]};
      if (BIAS) {
        float4 b4 = *(const float4*)&bias[(long long)z * sBias + col0 + c4];
        val[0] += b4.x; val[1] += b4.y; val[2] += b4.z; val[3] += b4.w;
      }
      if (RANK1) {
        float rr1 = r1row[(long long)z * sR1r + R];
        float4 c4v = *(const float4*)&r1col[(long long)z * sR1c + col0 + c4];
        val[0] += rr1 * c4v.x; val[1] += rr1 * c4v.y;
        val[2] += rr1 * c4v.z; val[3] += rr1 * c4v.w;
      }
      if (OUTM == 0) {
        if (ACCUM) {
          float4 old = *(const float4*)&Cf[idx];
          val[0] += old.x; val[1] += old.y; val[2] += old.z; val[3] += old.w;
        }
        if (RELU) {
          val[0] = fmaxf(val[0], 0.f); val[1] = fmaxf(val[1], 0.f);
          val[2] = fmaxf(val[2], 0.f); val[3] = fmaxf(val[3], 0.f);
        }
        float4 o4; o4.x = val[0]; o4.y = val[1]; o4.z = val[2]; o4.w = val[3];
        *(float4*)&Cf[idx] = o4;
      } else {
        if (ACCUM) {
          ushort4 old = *(const ushort4*)&Cb[idx];
          val[0] += bf2f(old.x); val[1] += bf2f(old.y);
          val[2] += bf2f(old.z); val[3] += bf2f(old.w);
        }
        ushort4 o;
        o.x = f2bf(val[0]); o.y = f2bf(val[1]);
        o.z = f2bf(val[2]); o.w = f2bf(val[3]);
        *(ushort4*)&Cb[idx] = o;
      }
    }
  }
}

// ---------------------------------------------------------------------------
// 8-wave split-K MFMA GEMM (ring-8, 128 KB, 1 block/CU): for <=256-block,
// K-heavy dispatches where deep prefetch (3 pairs in flight) wins.
// ---------------------------------------------------------------------------
template<int OUTM, bool ACCUM, bool RELU, bool RANK1, bool BIAS>
__global__ __launch_bounds__(512) void mgemm8_k(
    const u16* __restrict__ A, int lda, long long sA,
    const u16* __restrict__ B, int ldb, long long sB,
    const float* __restrict__ bias, int sBias,
    float* __restrict__ Cf, u16* __restrict__ Cb, int ldc, long long sC,
    int K,
    const float* __restrict__ r1row, int sR1r,
    const float* __restrict__ r1col, int sR1c)
{
  __shared__ u16 smem[8 * 8192];   // 8 slots x 16KB = 128 KB
  const int z = blockIdx.z;
  const u16* Ag = A + (long long)z * sA;
  const u16* Bg = B + (long long)z * sB;

  int bx, by;
  xcd_map(gridDim.x, gridDim.y, bx, by);

  const int row0 = by << 7;
  const int col0 = bx << 7;
  const int tid  = threadIdx.x;
  const int lane = tid & 63;
  const int w    = tid >> 6;
  const int g    = w >> 2;
  const int s4   = w & 3;
  const int wr   = (s4 >> 1) << 6;
  const int wc   = (s4 & 1) << 6;

  const int srow = tid >> 2;
  const int ssw  = (tid & 3) ^ ((srow >> 1) & 3);
  const long long aoff = (long long)(row0 + srow) * lda + ssw * 8;
  const long long boff = (long long)(col0 + srow) * ldb + ssw * 8;

  const int frow = lane & 15;
  const int fsw  = (lane >> 4) ^ ((frow >> 1) & 3);
  const int fAoff = ((wr + frow) << 5) + (fsw << 3);
  const int fBoff = ((wc + frow) << 5) + (fsw << 3);

#define STAGE8(tt) do {                                                        \
    u16* _sb = smem + (((tt) & 7) << 13);                                      \
    const long long _k = (long long)(tt) << 5;                                 \
    GLDS16(Ag + aoff + _k, _sb + (tid << 3));                                  \
    GLDS16(Bg + boff + _k, _sb + 4096 + (tid << 3));                           \
  } while (0)

  f32x4 acc[4][4];
  #pragma unroll
  for (int mi = 0; mi < 4; ++mi)
    #pragma unroll
    for (int ni = 0; ni < 4; ++ni) {
      acc[mi][ni][0] = 0.f; acc[mi][ni][1] = 0.f;
      acc[mi][ni][2] = 0.f; acc[mi][ni][3] = 0.f;
    }

  const int NT = K >> 5;
  const int NP = NT >> 1;
  STAGE8(0); STAGE8(1); STAGE8(2); STAGE8(3); STAGE8(4); STAGE8(5);
  asm volatile("s_waitcnt vmcnt(8)" ::: "memory");
  __builtin_amdgcn_s_barrier();
  asm volatile("" ::: "memory");

  for (int i = 0; i < NP; ++i) {
    if (i + 3 < NP) { STAGE8(2 * i + 6); STAGE8(2 * i + 7); }

    const u16* base = smem + (((2 * i + g) & 7) << 13);
    bf16x8 af[4], bfr[4];
    #pragma unroll
    for (int mi = 0; mi < 4; ++mi) af[mi]  = *(const bf16x8*)(base + fAoff + mi * 512);
    #pragma unroll
    for (int ni = 0; ni < 4; ++ni) bfr[ni] = *(const bf16x8*)(base + 4096 + fBoff + ni * 512);
    __builtin_amdgcn_s_setprio(1);
    #pragma unroll
    for (int mi = 0; mi < 4; ++mi)
      #pragma unroll
      for (int ni = 0; ni < 4; ++ni)
        acc[mi][ni] = __builtin_amdgcn_mfma_f32_16x16x32_bf16(
            af[mi], bfr[ni], acc[mi][ni], 0, 0, 0);
    __builtin_amdgcn_s_setprio(0);

    if (i + 1 < NP) {
      if (i + 3 < NP)      asm volatile("s_waitcnt vmcnt(8)" ::: "memory");
      else if (i + 2 < NP) asm volatile("s_waitcnt vmcnt(4)" ::: "memory");
      else                 asm volatile("s_waitcnt vmcnt(0)" ::: "memory");
      __builtin_amdgcn_s_barrier();
      asm volatile("" ::: "memory");
    }
  }
#undef STAGE8

  epilogue128<OUTM, ACCUM, RELU, RANK1, BIAS>(
      smem, acc, z, row0, col0, tid, lane, w, wr, wc,
      bias, sBias, Cf, Cb, ldc, sC, r1row, sR1r, r1col, sR1c);
}

// ---------------------------------------------------------------------------
// Ring-4 variant (~68 KB LDS -> 2 blocks/CU): for > 256-block dispatches
// where co-residency beats prefetch depth. acc[4][4]=64 VGPR fits the
// (512,4) 128-VGPR cap.
// ---------------------------------------------------------------------------
template<int OUTM, bool ACCUM, bool RELU, bool RANK1, bool BIAS>
__global__ __launch_bounds__(512, 4) void mgemm8d_k(
    const u16* __restrict__ A, int lda, long long sA,
    const u16* __restrict__ B, int ldb, long long sB,
    const float* __restrict__ bias, int sBias,
    float* __restrict__ Cf, u16* __restrict__ Cb, int ldc, long long sC,
    int K,
    const float* __restrict__ r1row, int sR1r,
    const float* __restrict__ r1col, int sR1c)
{
  __shared__ u16 smem[33792];   // max(ring-4 64KB, epilogue tile 67.5KB)
  const int z = blockIdx.z;
  const u16* Ag = A + (long long)z * sA;
  const u16* Bg = B + (long long)z * sB;

  int bx, by;
  xcd_map(gridDim.x, gridDim.y, bx, by);

  const int row0 = by << 7;
  const int col0 = bx << 7;
  const int tid  = threadIdx.x;
  const int lane = tid & 63;
  const int w    = tid >> 6;
  const int g    = w >> 2;
  const int s4   = w & 3;
  const int wr   = (s4 >> 1) << 6;
  const int wc   = (s4 & 1) << 6;

  const int srow = tid >> 2;
  const int ssw  = (tid & 3) ^ ((srow >> 1) & 3);
  const long long aoff = (long long)(row0 + srow) * lda + ssw * 8;
  const long long boff = (long long)(col0 + srow) * ldb + ssw * 8;

  const int frow = lane & 15;
  const int fsw  = (lane >> 4) ^ ((frow >> 1) & 3);
  const int fAoff = ((wr + frow) << 5) + (fsw << 3);
  const int fBoff = ((wc + frow) << 5) + (fsw << 3);

#define STAGE4(tt) do {                                                        \
    u16* _sb = smem + (((tt) & 3) << 13);                                      \
    const long long _k = (long long)(tt) << 5;                                 \
    GLDS16(Ag + aoff + _k, _sb + (tid << 3));                                  \
    GLDS16(Bg + boff + _k, _sb + 4096 + (tid << 3));                           \
  } while (0)

  f32x4 acc[4][4];
  #pragma unroll
  for (int mi = 0; mi < 4; ++mi)
    #pragma unroll
    for (int ni = 0; ni < 4; ++ni) {
      acc[mi][ni][0] = 0.f; acc[mi][ni][1] = 0.f;
      acc[mi][ni][2] = 0.f; acc[mi][ni][3] = 0.f;
    }

  const int NT = K >> 5;
  const int NP = NT >> 1;   // >= 2 for all our shapes
  STAGE4(0); STAGE4(1); STAGE4(2); STAGE4(3);   // pairs 0,1 (8 loads)

  for (int p = 0; p < NP; ++p) {
    if (p + 1 < NP) asm volatile("s_waitcnt vmcnt(4)" ::: "memory");
    else            asm volatile("s_waitcnt vmcnt(0)" ::: "memory");
    __builtin_amdgcn_s_barrier();
    asm volatile("" ::: "memory");

    const u16* base = smem + (((2 * p + g) & 3) << 13);
    bf16x8 af[4], bfr[4];
    #pragma unroll
    for (int mi = 0; mi < 4; ++mi) af[mi]  = *(const bf16x8*)(base + fAoff + mi * 512);
    #pragma unroll
    for (int ni = 0; ni < 4; ++ni) bfr[ni] = *(const bf16x8*)(base + 4096 + fBoff + ni * 512);
    asm volatile("s_waitcnt lgkmcnt(0)" ::: "memory");
    __builtin_amdgcn_s_barrier();
    asm volatile("" ::: "memory");

    if (p + 2 < NP) { STAGE4(2 * p + 4); STAGE4(2 * p + 5); }

    __builtin_amdgcn_s_setprio(1);
    #pragma unroll
    for (int mi = 0; mi < 4; ++mi)
      #pragma unroll
      for (int ni = 0; ni < 4; ++ni)
        acc[mi][ni] = __builtin_amdgcn_mfma_f32_16x16x32_bf16(
            af[mi], bfr[ni], acc[mi][ni], 0, 0, 0);
    __builtin_amdgcn_s_setprio(0);
  }
#undef STAGE4

  epilogue128<OUTM, ACCUM, RELU, RANK1, BIAS>(
      smem, acc, z, row0, col0, tid, lane, w, wr, wc,
      bias, sBias, Cf, Cb, ldc, sC, r1row, sR1r, r1col, sR1c);
}

// ---------------------------------------------------------------------------
// 256x256 MFMA GEMM, 8 waves each owning 128x64. BK=32, ring-4 x 32KB LDS
// (128 KB), 3 tiles in flight, counted vmcnt, direct epilogue.
// launch_bounds(512,2): acc[8][4]=128 VGPR needs the 256-VGPR cap; this
// kernel is structurally 1 block/CU (do NOT raise the occupancy floor).
// ---------------------------------------------------------------------------
template<bool BIAS>
__global__ __launch_bounds__(512, 2) void mgemm256_k(
    const u16* __restrict__ A, int lda, long long sA,
    const u16* __restrict__ B, int ldb, long long sB,
    const float* __restrict__ bias, int sBias,
    u16* __restrict__ Cb, int ldc, long long sC,
    int K)
{
  __shared__ u16 smem[4 * 16384];
  const int z = blockIdx.z;
  const u16* Ag = A + (long long)z * sA;
  const u16* Bg = B + (long long)z * sB;

  int bx, by;
  xcd_map(gridDim.x, gridDim.y, bx, by);

  const int row0r = by << 8;
  const int col0 = bx << 8;
  const int tid  = threadIdx.x;
  const int lane = tid & 63;
  const int w    = tid >> 6;
  const int wrow = w >> 2;
  const int wcol = w & 3;

  const int srow = tid >> 2;
  const int ssw  = (tid & 3) ^ ((srow >> 1) & 3);
  const long long aoff0 = (long long)(row0r + srow)       * lda + ssw * 8;
  const long long aoff1 = (long long)(row0r + srow + 128) * lda + ssw * 8;
  const long long boff0 = (long long)(col0 + srow)        * ldb + ssw * 8;
  const long long boff1 = (long long)(col0 + srow + 128)  * ldb + ssw * 8;

  const int frow = lane & 15;
  const int fsw  = (lane >> 4) ^ ((frow >> 1) & 3);
  const int fAoff = ((wrow * 128 + frow) << 5) + (fsw << 3);
  const int fBoff = ((wcol * 64  + frow) << 5) + (fsw << 3);

#define STG256(tt) do {                                                        \
    u16* _sb = smem + (((tt) & 3) << 14);                                      \
    const long long _k = (long long)(tt) << 5;                                 \
    GLDS16(Ag + aoff0 + _k, _sb + (tid << 3));                                 \
    GLDS16(Ag + aoff1 + _k, _sb + 4096 + (tid << 3));                          \
    GLDS16(Bg + boff0 + _k, _sb + 8192 + (tid << 3));                          \
    GLDS16(Bg + boff1 + _k, _sb + 12288 + (tid << 3));                         \
  } while (0)

  f32x4 acc[8][4];
  #pragma unroll
  for (int mi = 0; mi < 8; ++mi)
    #pragma unroll
    for (int ni = 0; ni < 4; ++ni) {
      acc[mi][ni][0] = 0.f; acc[mi][ni][1] = 0.f;
      acc[mi][ni][2] = 0.f; acc[mi][ni][3] = 0.f;
    }

  const int NT = K >> 5;
  STG256(0); STG256(1); STG256(2);
  asm volatile("s_waitcnt vmcnt(8)" ::: "memory");
  __builtin_amdgcn_s_barrier();
  asm volatile("" ::: "memory");

  for (int t = 0; t < NT; ++t) {
    if (t + 3 < NT) STG256(t + 3);

    const u16* base = smem + ((t & 3) << 14);
    bf16x8 af[8], bfr[4];
    #pragma unroll
    for (int mi = 0; mi < 8; ++mi) af[mi]  = *(const bf16x8*)(base + fAoff + mi * 512);
    #pragma unroll
    for (int ni = 0; ni < 4; ++ni) bfr[ni] = *(const bf16x8*)(base + 8192 + fBoff + ni * 512);
    __builtin_amdgcn_s_setprio(1);
    #pragma unroll
    for (int mi = 0; mi < 8; ++mi)
      #pragma unroll
      for (int ni = 0; ni < 4; ++ni)
        acc[mi][ni] = __builtin_amdgcn_mfma_f32_16x16x32_bf16(
            af[mi], bfr[ni], acc[mi][ni], 0, 0, 0);
    __builtin_amdgcn_s_setprio(0);

    if (t + 1 < NT) {
      if (t + 3 < NT)      asm volatile("s_waitcnt vmcnt(8)" ::: "memory");
      else if (t + 2 < NT) asm volatile("s_waitcnt vmcnt(4)" ::: "memory");
      else                 asm volatile("s_waitcnt vmcnt(0)" ::: "memory");
      __builtin_amdgcn_s_barrier();
      asm volatile("" ::: "memory");
    }
  }
#undef STG256

  const int cn  = lane & 15;
  const int rm4 = (lane >> 4) << 2;
  #pragma unroll
  for (int mi = 0; mi < 8; ++mi) {
    #pragma unroll
    for (int ni = 0; ni < 4; ++ni) {
      const int rb = row0r + wrow * 128 + mi * 16 + rm4;
      const int cc = col0 + wcol * 64 + ni * 16 + cn;
      float badd = BIAS ? bias[(long long)z * sBias + cc] : 0.f;
      f32x4 v = acc[mi][ni];
      #pragma unroll
      for (int j = 0; j < 4; ++j)
        Cb[(long long)z * sC + (long long)(rb + j) * ldc + cc] = f2bf(v[j] + badd);
    }
  }
}

// out = relu(p0+p1+p2+p3), partials stride 1M floats, n4 = n/4 float4s
__global__ __launch_bounds__(256) void reduce4relu_k(
    const float* __restrict__ p, float* __restrict__ out, int n4)
{
  int i = blockIdx.x * 256 + threadIdx.x;
  if (i < n4) {
    float4 a = ((const float4*)p)[i];
    float4 b = ((const float4*)(p + (1ll << 20)))[i];
    float4 c = ((const float4*)(p + (2ll << 20)))[i];
    float4 d = ((const float4*)(p + (3ll << 20)))[i];
    float4 o;
    o.x = fmaxf(a.x + b.x + c.x + d.x, 0.f);
    o.y = fmaxf(a.y + b.y + c.y + d.y, 0.f);
    o.z = fmaxf(a.z + b.z + c.z + d.z, 0.f);
    o.w = fmaxf(a.w + b.w + c.w + d.w, 0.f);
    ((float4*)out)[i] = o;
  }
}

// ---------------------------------------------------------------------------
// Fused: xT[c][r] = x[r][c] (fp32) AND x_bf[r][c] = bf16(x[r][c]).
// ---------------------------------------------------------------------------
__global__ __launch_bounds__(256) void xc_k(
    const float* __restrict__ x, float* __restrict__ xT, u16* __restrict__ xbf)
{
  __shared__ float tile[32][33];
  int c0 = blockIdx.x * 32, r0 = blockIdx.y * 32;
  int tx = threadIdx.x & 31, ty = threadIdx.x >> 5;
  #pragma unroll
  for (int rr = ty; rr < 32; rr += 8) {
    float v = x[(long long)(r0 + rr) * 1024 + c0 + tx];
    tile[rr][tx] = v;
    xbf[(long long)(r0 + rr) * 1024 + c0 + tx] = f2bf(v);
  }
  __syncthreads();
  #pragma unroll
  for (int cc = ty; cc < 32; cc += 8)
    xT[(long long)(c0 + cc) * 1024 + r0 + tx] = tile[tx][cc];
}

// fp32 [R][C] -> bf16 [C][R], batched over 4 (src,dst) pairs via blockIdx.z
__global__ __launch_bounds__(256) void wcvt4_k(
    const float* __restrict__ s0, const float* __restrict__ s1,
    const float* __restrict__ s2, const float* __restrict__ s3,
    u16* __restrict__ d0, u16* __restrict__ d1,
    u16* __restrict__ d2, u16* __restrict__ d3, int R, int Cc)
{
  const float* in = (blockIdx.z == 0) ? s0 : (blockIdx.z == 1) ? s1
                  : (blockIdx.z == 2) ? s2 : s3;
  u16* out = (blockIdx.z == 0) ? d0 : (blockIdx.z == 1) ? d1
           : (blockIdx.z == 2) ? d2 : d3;
  __shared__ float tile[32][33];
  int c0 = blockIdx.x * 32, r0 = blockIdx.y * 32;
  int tx = threadIdx.x & 31, ty = threadIdx.x >> 5;
  #pragma unroll
  for (int rr = ty; rr < 32; rr += 8)
    tile[rr][tx] = in[(long long)(r0 + rr) * Cc + c0 + tx];
  __syncthreads();
  #pragma unroll
  for (int cc = ty; cc < 32; cc += 8)
    out[(long long)(c0 + cc) * R + r0 + tx] = f2bf(tile[tx][cc]);
}

// bf16 [R][C] -> bf16 [C][R] (pure transpose; values unchanged)
__global__ __launch_bounds__(256) void btr_k(
    const u16* __restrict__ in, u16* __restrict__ out, int R, int Cc)
{
  __shared__ u16 tile[32][34];
  int c0 = blockIdx.x * 32, r0 = blockIdx.y * 32;
  int tx = threadIdx.x & 31, ty = threadIdx.x >> 5;
  #pragma unroll
  for (int rr = ty; rr < 32; rr += 8)
    tile[rr][tx] = in[(long long)(r0 + rr) * Cc + c0 + tx];
  __syncthreads();
  #pragma unroll
  for (int cc = ty; cc < 32; cc += 8)
    out[(long long)(c0 + cc) * R + r0 + tx] = tile[tx][cc];
}

// bf16 [R][C] -> bf16 [C][R] with per-source-column affine: A2[c]*v + C2[c]
__global__ __launch_bounds__(256) void tcvt_affb_k(
    const u16* __restrict__ in, u16* __restrict__ out, int R, int Cc,
    const float* __restrict__ A2, const float* __restrict__ C2)
{
  __shared__ u16 tile[32][34];
  int c0 = blockIdx.x * 32, r0 = blockIdx.y * 32;
  int tx = threadIdx.x & 31, ty = threadIdx.x >> 5;
  #pragma unroll
  for (int rr = ty; rr < 32; rr += 8)
    tile[rr][tx] = in[(long long)(r0 + rr) * Cc + c0 + tx];
  __syncthreads();
  #pragma unroll
  for (int cc = ty; cc < 32; cc += 8) {
    float v = A2[c0 + cc] * bf2f(tile[tx][cc]) + C2[c0 + cc];
    out[(long long)(c0 + cc) * R + r0 + tx] = f2bf(v);
  }
}

// pack both QK bias pairs in one launch
__global__ __launch_bounds__(256) void pack2b_k(
    const float* __restrict__ a1, const float* __restrict__ b1,
    float* __restrict__ o1, int n1,
    const float* __restrict__ a2, const float* __restrict__ b2,
    float* __restrict__ o2, int n2)
{
  int i = blockIdx.x * 256 + threadIdx.x;
  if (i < n1) { o1[i] = a1[i]; o1[n1 + i] = b1[i]; }
  int j = i - n1;
  if (j >= 0 && j < n2) { o2[j] = a2[j]; o2[n2 + j] = b2[j]; }
}

// ---------------------------------------------------------------------------
__global__ __launch_bounds__(64) void qe_k(const u16* __restrict__ Q1,
                                           const float* __restrict__ We1,
                                           float* __restrict__ qe)
{
  int h = blockIdx.x >> 10;
  int i = blockIdx.x & 1023;
  const u16* q = Q1 + (long long)i * 4096 + h * 512;
  const float* wv = We1 + h * 512;
  int l = threadIdx.x;
  float s = 0.f;
  #pragma unroll
  for (int r = 0; r < 8; ++r) s += bf2f(q[l + r * 64]) * wv[l + r * 64];
  #pragma unroll
  for (int off = 32; off > 0; off >>= 1) s += __shfl_down(s, off);
  if (l == 0) qe[blockIdx.x] = s;
}

// ---------------------------------------------------------------------------
__global__ __launch_bounds__(256) void softmax1b_k(
    u16* __restrict__ S, const float* __restrict__ xT,
    const float* __restrict__ qe, float* __restrict__ ae)
{
  int i = blockIdx.x, h = blockIdx.y;
  u16* s = S + ((long long)h * 1024 + i) * 1024;
  const float* e = xT + (long long)i * 1024;
  float q = qe[h * 1024 + i];
  int tid = threadIdx.x;
  __shared__ float red[256];

  ushort4 sv = ((const ushort4*)s)[tid];
  float4  evv = ((const float4*)e)[tid];
  float ev[4] = {evv.x, evv.y, evv.z, evv.w};
  float t[4];
  t[0] = (bf2f(sv.x) + q * ev[0]) * kInvSqrtD;
  t[1] = (bf2f(sv.y) + q * ev[1]) * kInvSqrtD;
  t[2] = (bf2f(sv.z) + q * ev[2]) * kInvSqrtD;
  t[3] = (bf2f(sv.w) + q * ev[3]) * kInvSqrtD;
  float m = fmaxf(fmaxf(t[0], t[1]), fmaxf(t[2], t[3]));
  m = blockReduceMax(m, red);
  float sum = 0.f;
  #pragma unroll
  for (int r = 0; r < 4; ++r) { t[r] = __expf(t[r] - m); sum += t[r]; }
  sum = blockReduceSum(sum, red);
  float invl = 1.f / sum;
  float aes = 0.f;
  ushort4 o;
  o.x = f2bf(t[0] * invl); o.y = f2bf(t[1] * invl);
  o.z = f2bf(t[2] * invl); o.w = f2bf(t[3] * invl);
  #pragma unroll
  for (int r = 0; r < 4; ++r) aes += (t[r] * invl) * ev[r];
  ((ushort4*)s)[tid] = o;
  aes = blockReduceSum(aes, red);
  if (tid == 0) ae[h * 1024 + i] = aes;
}

__global__ __launch_bounds__(256) void softmax2b_k(u16* __restrict__ S)
{
  u16* s = S + ((long long)blockIdx.y * 2048 + blockIdx.x) * 4096;
  int tid = threadIdx.x;
  __shared__ float red[256];
  float t[16];
  float m = -1e30f;
  #pragma unroll
  for (int r = 0; r < 4; ++r) {
    ushort4 sv = ((const ushort4*)s)[tid + r * 256];
    t[r*4+0] = bf2f(sv.x) * kInvSqrtD; t[r*4+1] = bf2f(sv.y) * kInvSqrtD;
    t[r*4+2] = bf2f(sv.z) * kInvSqrtD; t[r*4+3] = bf2f(sv.w) * kInvSqrtD;
    m = fmaxf(m, fmaxf(fmaxf(t[r*4], t[r*4+1]), fmaxf(t[r*4+2], t[r*4+3])));
  }
  m = blockReduceMax(m, red);
  float sum = 0.f;
  #pragma unroll
  for (int r = 0; r < 16; ++r) { t[r] = __expf(t[r] - m); sum += t[r]; }
  sum = blockReduceSum(sum, red);
  float invl = 1.f / sum;
  #pragma unroll
  for (int r = 0; r < 4; ++r) {
    ushort4 o;
    o.x = f2bf(t[r*4+0] * invl); o.y = f2bf(t[r*4+1] * invl);
    o.z = f2bf(t[r*4+2] * invl); o.w = f2bf(t[r*4+3] * invl);
    ((ushort4*)s)[tid + r * 256] = o;
  }
}

// ---------------------------------------------------------------------------
__global__ __launch_bounds__(256) void colpart4_k(const float* __restrict__ h,
    int N, int F, int nchunk, float* __restrict__ ps, float* __restrict__ pss)
{
  const int f4 = blockIdx.x * 256 + threadIdx.x;
  const int chunk = blockIdx.y;
  const int rows = N / nchunk;
  const int rbeg = chunk * rows;
  const int F4 = F >> 2;
  const float4* h4 = (const float4*)h;
  float4 s = {0.f, 0.f, 0.f, 0.f}, ss = {0.f, 0.f, 0.f, 0.f};
  #pragma unroll 8
  for (int i = 0; i < rows; ++i) {
    float4 v = h4[(long long)(rbeg + i) * F4 + f4];
    s.x += v.x; s.y += v.y; s.z += v.z; s.w += v.w;
    ss.x += v.x * v.x; ss.y += v.y * v.y;
    ss.z += v.z * v.z; ss.w += v.w * v.w;
  }
  ((float4*)(ps  + (long long)chunk * F))[f4] = s;
  ((float4*)(pss + (long long)chunk * F))[f4] = ss;
}

// bf16-input column partials: uint4 load = 8 bf16 cols per thread.
// grid (F/2048, nchunk); each thread owns 8 consecutive columns.
__global__ __launch_bounds__(256) void colpart8b_k(const u16* __restrict__ h,
    int N, int F, int nchunk, float* __restrict__ ps, float* __restrict__ pss)
{
  const int f8 = blockIdx.x * 256 + threadIdx.x;   // group of 8 columns
  const int chunk = blockIdx.y;
  const int rows = N / nchunk;
  const int rbeg = chunk * rows;
  const int F8 = F >> 3;
  float s[8], ss[8];
  #pragma unroll
  for (int k = 0; k < 8; ++k) { s[k] = 0.f; ss[k] = 0.f; }
  #pragma unroll 4
  for (int i = 0; i < rows; ++i) {
    uint4 v = ((const uint4*)(h + (long long)(rbeg + i) * F))[f8];
    unsigned ww[4] = {v.x, v.y, v.z, v.w};
    #pragma unroll
    for (int k = 0; k < 4; ++k) {
      float lo = bf2f((u16)(ww[k] & 0xffffu));
      float hi = bf2f((u16)(ww[k] >> 16));
      s[2*k]   += lo; ss[2*k]   += lo * lo;
      s[2*k+1] += hi; ss[2*k+1] += hi * hi;
    }
  }
  float* pd  = ps  + (long long)chunk * F + f8 * 8;
  float* psd = pss + (long long)chunk * F + f8 * 8;
  #pragma unroll
  for (int k = 0; k < 8; ++k) { pd[k] = s[k]; psd[k] = ss[k]; }
}

// Parallel finisher: one block per float4-column; 256 threads split chunks.
template<int MODE>
__global__ __launch_bounds__(256) void colfin2_k(
    const float* __restrict__ ps, const float* __restrict__ pss,
    int F, int nchunk, float Nf,
    const float* __restrict__ ms, const float* __restrict__ g,
    const float* __restrict__ beta,
    float* __restrict__ outA, float* __restrict__ outC)
{
  __shared__ float4 red4[256];
  const int f4 = blockIdx.x;
  const int tid = threadIdx.x;
  float4 s = {0.f, 0.f, 0.f, 0.f}, ss = {0.f, 0.f, 0.f, 0.f};
  for (int c = tid; c < nchunk; c += 256) {
    float4 v = ((const float4*)(ps  + (long long)c * F))[f4];
    float4 u = ((const float4*)(pss + (long long)c * F))[f4];
    s.x += v.x; s.y += v.y; s.z += v.z; s.w += v.w;
    ss.x += u.x; ss.y += u.y; ss.z += u.z; ss.w += u.w;
  }
  s  = blockReduceF4(s, red4);
  ss = blockReduceF4(ss, red4);
  if (tid < 4) {
    const int f = f4 * 4 + tid;
    float sv  = (tid == 0) ? s.x  : (tid == 1) ? s.y  : (tid == 2) ? s.z  : s.w;
    float ssv = (tid == 0) ? ss.x : (tid == 1) ? ss.y : (tid == 2) ? ss.z : ss.w;
    float Ninv = 1.f / Nf;
    float mean = sv * Ninv;
    float mm = ms[f] * mean;
    float var = ssv * Ninv - 2.f * mm * mean + mm * mm;
    float is = rsqrtf(var + 1e-5f);
    float a = g[f] * is;
    float c = beta[f] - a * mm;
    if (MODE == 1) {
      float sy2 = a * a * ssv + 2.f * a * c * sv + Nf * c * c;
      float cinv = rsqrtf(sy2);
      a *= cinv; c *= cinv;
    }
    outA[f] = a;
    outC[f] = c;
  }
}

__global__ __launch_bounds__(256) void rowl2gn_k(
    float* __restrict__ h, u16* __restrict__ hb,
    const float* __restrict__ a, const float* __restrict__ c)
{
  int i = blockIdx.x;
  float* row = h + (long long)i * 4096;
  u16* rb = hb + (long long)i * 4096;
  int tid = threadIdx.x;
  __shared__ float red[256];
  float t[16];
  float ss = 0.f;
  #pragma unroll
  for (int r = 0; r < 4; ++r) {
    int j = tid + r * 256;
    float4 hv = ((const float4*)row)[j];
    float4 av = ((const float4*)a)[j];
    float4 cv = ((const float4*)c)[j];
    t[r*4+0] = av.x * hv.x + cv.x;
    t[r*4+1] = av.y * hv.y + cv.y;
    t[r*4+2] = av.z * hv.z + cv.z;
    t[r*4+3] = av.w * hv.w + cv.w;
    ss += t[r*4+0]*t[r*4+0] + t[r*4+1]*t[r*4+1]
        + t[r*4+2]*t[r*4+2] + t[r*4+3]*t[r*4+3];
  }
  ss = blockReduceSum(ss, red);
  float inv = rsqrtf(ss);
  #pragma unroll
  for (int r = 0; r < 4; ++r) {
    int j = tid + r * 256;
    float4 o4;
    o4.x = t[r*4+0] * inv; o4.y = t[r*4+1] * inv;
    o4.z = t[r*4+2] * inv; o4.w = t[r*4+3] * inv;
    ((float4*)row)[j] = o4;
    ushort4 ob;
    ob.x = f2bf(o4.x); ob.y = f2bf(o4.y); ob.z = f2bf(o4.z); ob.w = f2bf(o4.w);
    ((ushort4*)rb)[j] = ob;
  }
}

// ---------------------------------------------------------------------------
extern "C" void kernel_launch(void* const* d_in, const int* in_sizes, int n_in,
                              void* d_out, int out_size, void* d_ws, size_t ws_size,
                              hipStream_t stream)
{
  (void)in_sizes; (void)n_in; (void)out_size; (void)ws_size;

  const float* x      = (const float*)d_in[0];
  const float* Wq1    = (const float*)d_in[1];
  const float* bq1    = (const float*)d_in[2];
  const float* Wk1    = (const float*)d_in[3];
  const float* bk1    = (const float*)d_in[4];
  const float* Wv1    = (const float*)d_in[5];
  const float* bv1    = (const float*)d_in[6];
  const float* We1    = (const float*)d_in[7];
  const float* Wskip1 = (const float*)d_in[8];
  const float* bskip1 = (const float*)d_in[9];
  const float* g1     = (const float*)d_in[10];
  const float* bb1    = (const float*)d_in[11];
  const float* ms1    = (const float*)d_in[12];
  const float* Wq2    = (const float*)d_in[13];
  const float* bq2    = (const float*)d_in[14];
  const float* Wk2    = (const float*)d_in[15];
  const float* bk2    = (const float*)d_in[16];
  const float* Wv2    = (const float*)d_in[17];
  const float* bv2    = (const float*)d_in[18];
  const float* Wskip2 = (const float*)d_in[19];
  const float* bskip2 = (const float*)d_in[20];
  const float* g2     = (const float*)d_in[21];
  const float* bb2    = (const float*)d_in[22];
  const float* ms2    = (const float*)d_in[23];

  // ---- workspace arena (~209 MB) ----
  char* base = (char*)d_ws;
  float* lrx_f   = (float*)(base);                 // 16MB [1024][4096]
  u16*   lrx_bf  = (u16*)  (base + (16ll << 20));  // 8MB
  u16*   lrxT_bf = (u16*)  (base + (24ll << 20));  // 8MB [4096][1024]
  u16*   hrx_bf  = (u16*)  (base + (32ll << 20));  // 16MB [2048][4096]
  char* sh = base + (48ll << 20);                  // shared region, 160MB
  // stage A
  u16* x_bf  = (u16*)(sh);                         // 2MB
  float* xT  = (float*)(sh + (2ll << 20));         // 4MB
  u16* Wq1T  = (u16*)(sh + (6ll << 20));           // 8MB each (Wk1T follows Wq1T)
  u16* Wk1T  = (u16*)(sh + (14ll << 20));
  u16* Wv1T  = (u16*)(sh + (22ll << 20));
  u16* Ws1T  = (u16*)(sh + (30ll << 20));
  u16* Q1bf  = (u16*)(sh + (38ll << 20));          // 8MB [1024][4096] (K1bf follows)
  u16* K1bf  = (u16*)(sh + (46ll << 20));          // 8MB
  u16* V1T   = (u16*)(sh + (54ll << 20));          // 8MB [4096][1024]
  u16* S1bf  = (u16*)(sh + (62ll << 20));          // 16MB [8][1024][1024]
  // GN1 partials in dead S1bf space (consumed before V2T/H2 writes)
  float* ps1  = (float*)(sh + (66ll << 20));       // 2MB [128][4096]
  float* pss1 = (float*)(sh + (68ll << 20));       // 2MB
  // stage B (aliases stage A)
  u16* Wq2T  = (u16*)(sh);                         // 4MB each (Wk2T follows)
  u16* Wk2T  = (u16*)(sh + (4ll << 20));
  u16* Wv2T  = (u16*)(sh + (8ll << 20));
  u16* Ws2T  = (u16*)(sh + (12ll << 20));
  u16* Q2bf  = (u16*)(sh + (16ll << 20));          // 16MB [4096][2048] (K2bf follows)
  u16* K2bf  = (u16*)(sh + (32ll << 20));          // 16MB
  u16* V2T   = (u16*)(sh + (48ll << 20));          // 16MB [2048][4096]
  u16* H2b   = (u16*)(sh + (64ll << 20));          // 16MB [4096][2048] bf16
  u16* S2bf  = (u16*)(sh + (96ll << 20));          // 64MB [4][2048][4096]
  float* gpart = (float*)(sh + (96ll << 20));      // 16MB lr-gram partials (S2 dead)
  // GN2 partials in dead S2bf space (consumed before gpart written)
  float* ps2  = (float*)(sh + (120ll << 20));      // 2MB [256][2048]
  float* pss2 = (float*)(sh + (122ll << 20));      // 2MB
  // small tail
  float* tail    = (float*)(base + (208ll << 20));
  float* qe      = tail;             // 8192
  float* ae      = qe + 8192;        // 8192
  float* af1     = ae + 8192;        // 4096
  float* cf1     = af1 + 4096;       // 4096
  float* A2v     = cf1 + 4096;       // 2048
  float* C2v     = A2v + 2048;       // 2048
  float* biasQK1 = C2v + 2048;       // 8192
  float* biasQK2 = biasQK1 + 8192;   // 4096

  float* out0 = (float*)d_out;                   // hr [2048][2048]
  float* out1 = out0 + (long long)2048 * 2048;   // lr gram [1024][1024]

  // ---- stage 0: fused conversions ----
  xc_k<<<dim3(32, 32), 256, 0, stream>>>(x, xT, x_bf);
  wcvt4_k<<<dim3(128, 32, 4), 256, 0, stream>>>(
      Wq1, Wk1, Wv1, Wskip1, Wq1T, Wk1T, Wv1T, Ws1T, 1024, 4096);
  pack2b_k<<<dim3(24), 256, 0, stream>>>(bq1, bk1, biasQK1, 4096,
                                         bq2, bk2, biasQK2, 2048);

  // ---- conv1 Q+K batched (z=2, 512 blocks -> ring-4), V + skip (ring-8) ----
  mgemm8d_k<1,false,false,false,true><<<dim3(32, 8, 2), 512, 0, stream>>>(
      x_bf, 1024, 0, Wq1T, 1024, (long long)4096 * 1024, biasQK1, 4096,
      nullptr, Q1bf, 4096, (long long)1024 * 4096, 1024, nullptr, 0, nullptr, 0);
  mgemm8_k<2,false,false,false,true><<<dim3(32, 8, 1), 512, 0, stream>>>(
      x_bf, 1024, 0, Wv1T, 1024, 0, bv1, 0, nullptr, V1T, 1024, 0, 1024,
      nullptr, 0, nullptr, 0);
  mgemm8_k<0,false,false,false,true><<<dim3(32, 8, 1), 512, 0, stream>>>(
      x_bf, 1024, 0, Ws1T, 1024, 0, bskip1, 0, lrx_f, nullptr, 4096, 0, 1024,
      nullptr, 0, nullptr, 0);

  qe_k<<<dim3(8192), 64, 0, stream>>>(Q1bf, We1, qe);

  // ---- scores1[h] (512 blocks -> ring-4) ----
  mgemm8d_k<1,false,false,false,false><<<dim3(8, 8, 8), 512, 0, stream>>>(
      Q1bf, 4096, 512, K1bf, 4096, 512, nullptr, 0, nullptr, S1bf, 1024, 1048576,
      512, nullptr, 0, nullptr, 0);

  softmax1b_k<<<dim3(1024, 8), 256, 0, stream>>>(S1bf, xT, qe, ae);

  // ---- PV1 (256 blocks -> ring-8, fp32 accum into lrx_f) ----
  mgemm8_k<0,true,false,true,false><<<dim3(4, 8, 8), 512, 0, stream>>>(
      S1bf, 1024, 1048576, V1T, 1024, 512 * 1024, nullptr, 0, lrx_f, nullptr,
      4096, 512, 1024, ae, 1024, We1, 512);

  // ---- GraphNorm1 (affine) + row L2, fused ----
  colpart4_k<<<dim3(4, 128), 256, 0, stream>>>(lrx_f, 1024, 4096, 128, ps1, pss1);
  colfin2_k<0><<<dim3(1024), 256, 0, stream>>>(ps1, pss1, 4096, 128, 1024.f,
                                               ms1, g1, bb1, af1, cf1);
  rowl2gn_k<<<dim3(1024), 256, 0, stream>>>(lrx_f, lrx_bf, af1, cf1);
  btr_k<<<dim3(128, 32), 256, 0, stream>>>(lrx_bf, lrxT_bf, 1024, 4096);

  // ---- conv2 weights (batched; region aliases stage A) ----
  wcvt4_k<<<dim3(64, 32, 4), 256, 0, stream>>>(
      Wq2, Wk2, Wv2, Wskip2, Wq2T, Wk2T, Wv2T, Ws2T, 1024, 2048);

  // ---- conv2 Q+K on 256^2 kernel; V + skip (512 blocks -> ring-4) ----
  mgemm256_k<true><<<dim3(8, 16, 2), 512, 0, stream>>>(
      lrxT_bf, 1024, 0, Wq2T, 1024, (long long)2048 * 1024, biasQK2, 2048,
      Q2bf, 2048, (long long)4096 * 2048, 1024);
  mgemm8d_k<2,false,false,false,true><<<dim3(16, 32, 1), 512, 0, stream>>>(
      lrxT_bf, 1024, 0, Wv2T, 1024, 0, bv2, 0, nullptr, V2T, 4096, 0, 1024,
      nullptr, 0, nullptr, 0);
  // skip2 -> bf16 H2b
  mgemm8d_k<1,false,false,false,true><<<dim3(16, 32, 1), 512, 0, stream>>>(
      lrxT_bf, 1024, 0, Ws2T, 1024, 0, bskip2, 0, nullptr, H2b, 2048, 0, 1024,
      nullptr, 0, nullptr, 0);

  // ---- conv2 attention in 2 chunks of 2048 rows (bf16 accum into H2b) ----
  for (int c = 0; c < 2; ++c) {
    const u16* Qc = Q2bf + (long long)c * 2048 * 2048;
    u16* Hc = H2b + (long long)c * 2048 * 2048;
    mgemm256_k<false><<<dim3(16, 8, 4), 512, 0, stream>>>(
        Qc, 2048, 512, K2bf, 2048, 512, nullptr, 0,
        S2bf, 4096, (long long)2048 * 4096, 512);
    softmax2b_k<<<dim3(2048, 4), 256, 0, stream>>>(S2bf);
    mgemm8_k<1,true,false,false,false><<<dim3(4, 16, 4), 512, 0, stream>>>(
        S2bf, 4096, (long long)2048 * 4096, V2T, 4096, (long long)512 * 4096,
        nullptr, 0, nullptr, Hc, 2048, 512, 4096, nullptr, 0, nullptr, 0);
  }

  // ---- GraphNorm2 + column L2 fused into one affine transpose-convert ----
  colpart8b_k<<<dim3(1, 256), 256, 0, stream>>>(H2b, 4096, 2048, 256, ps2, pss2);
  colfin2_k<1><<<dim3(512), 256, 0, stream>>>(ps2, pss2, 2048, 256, 4096.f,
                                              ms2, g2, bb2, A2v, C2v);
  tcvt_affb_k<<<dim3(64, 128), 256, 0, stream>>>(H2b, hrx_bf, 4096, 2048, A2v, C2v);

  // ---- outputs: relu Grams ----
  mgemm8_k<0,false,true,false,false><<<dim3(16, 16, 1), 512, 0, stream>>>(
      hrx_bf, 4096, 0, hrx_bf, 4096, 0, nullptr, 0, out0, nullptr, 2048, 0, 4096,
      nullptr, 0, nullptr, 0);
  // lr-gram: grid-split K 4-way (z) into partials, then reduce+relu
  mgemm8_k<0,false,false,false,false><<<dim3(8, 8, 4), 512, 0, stream>>>(
      lrx_bf, 4096, 1024, lrx_bf, 4096, 1024, nullptr, 0, gpart, nullptr, 1024,
      (long long)1 << 20, 1024, nullptr, 0, nullptr, 0);
  reduce4relu_k<<<dim3(1024), 256, 0, stream>>>(gpart, out1, 262144);
}